// Round 16
// baseline (192.573 us; speedup 1.0000x reference)
//
#include <hip/hip_runtime.h>
#include <hip/hip_bf16.h>

#define NJ 24
#define NV 6890
#define NVP 6912         // padded vertex count (multiple of 256)
#define NR (NV*3)        // 20670 output rows per batch
#define NPF 207
#define KB 217           // 207 pf + 10 beta
#define KP 256           // padded K (8 x 32)
#define NT 162           // n-tiles (162*128 = 20736 >= NR)
#define NSPLIT 512       // jdirs v-splits
#define VPB 14           // ceil(6890/512)
#define FTILE 32768      // shorts per fragment tile: 8 ks * 8 frag * 64 lane * 8
#define NB 8             // skin batches per block

typedef short s16x8 __attribute__((ext_vector_type(8)));
typedef short s16x8a __attribute__((ext_vector_type(8), aligned(4)));
typedef float f32x4 __attribute__((ext_vector_type(4)));
typedef float f4u   __attribute__((ext_vector_type(4), aligned(4)));
typedef unsigned int u32x2 __attribute__((ext_vector_type(2)));

__device__ constexpr int PAR[24] = {-1,0,0,0,1,2,3,4,5,6,7,8,9,9,9,12,13,14,16,17,18,19,20,21};

__device__ __forceinline__ short f2bf(float f) {
    __hip_bfloat16 h = __float2bfloat16(f);
    return *reinterpret_cast<short*>(&h);
}
__device__ __forceinline__ float bf2f(unsigned int u) {
    unsigned int x = u << 16;
    return __uint_as_float(x);
}

// fragment address for matrix element (row_in_tile, k)
__device__ __forceinline__ size_t frag_addr(int row128, int k) {
    int ks = k >> 5, q = (k >> 3) & 3, e = k & 7;
    int mf = row128 >> 4, r16 = row128 & 15;
    return ((size_t)(ks*8 + mf) * 64 + q*16 + r16) * 8 + e;
}

// ============ K1: Rodrigues -> Rws(f32), pfA(f32), Afrag(bf16 fragment layout) ============
__global__ __launch_bounds__(256) void k_rodrigues(const float* __restrict__ theta,
        const float* __restrict__ beta, float* __restrict__ Rws,
        float* __restrict__ pfA, short* __restrict__ Afrag, int B) {
    int idx = blockIdx.x * blockDim.x + threadIdx.x;   // b*24 + j
    if (idx >= B * NJ) return;
    int b = idx / NJ, j = idx % NJ;
    float x = theta[b*72 + j*3 + 0];
    float y = theta[b*72 + j*3 + 1];
    float z = theta[b*72 + j*3 + 2];
    float n = sqrtf(x*x + y*y + z*z);
    float a = fmaxf(n, 1e-8f);
    float inv = 1.0f / a;
    float ix = x*inv, iy = y*inv, iz = z*inv;
    float c = cosf(a), s = sinf(a), t = 1.0f - c;
    float r[9];
    r[0] = t*ix*ix + c;     r[1] = t*ix*iy - s*iz;  r[2] = t*ix*iz + s*iy;
    r[3] = t*ix*iy + s*iz;  r[4] = t*iy*iy + c;     r[5] = t*iy*iz - s*ix;
    r[6] = t*ix*iz - s*iy;  r[7] = t*iy*iz + s*ix;  r[8] = t*iz*iz + c;
    float* Rp = Rws + (size_t)idx * 9;
    #pragma unroll
    for (int k = 0; k < 9; ++k) Rp[k] = r[k];

    int rb = b & 127;
    short* At = Afrag + (size_t)(b >> 7) * FTILE;
    float* pa = pfA + (size_t)b * 224;
    if (j >= 1) {
        #pragma unroll
        for (int kk = 0; kk < 9; ++kk) {
            int k = (j-1)*9 + kk;
            float f = r[kk] - ((kk == 0 || kk == 4 || kk == 8) ? 1.0f : 0.0f);
            At[frag_addr(rb, k)] = f2bf(f);
            pa[k] = f;
        }
    } else {
        #pragma unroll
        for (int kk = 0; kk < 10; ++kk) {
            int k = NPF + kk;
            float f = beta[b*10 + kk];
            At[frag_addr(rb, k)] = f2bf(f);
            pa[k] = f;
        }
        for (int k = KB; k < KP; ++k)
            At[frag_addr(rb, k)] = 0;
    }
}

// ============ K2: build Bfrag (bf16, fragment layout, coalesced writes) ============
__global__ __launch_bounds__(256) void k_convB(const float* __restrict__ pd,
        const float* __restrict__ sd, short* __restrict__ Bf) {
    int cid = blockIdx.x * 256 + threadIdx.x;      // chunk id: [nt][ks][nf][lane]
    int lane_ = cid & 63;
    int nf = (cid >> 6) & 7;
    int ks = (cid >> 9) & 7;
    int nt = cid >> 12;
    int q = lane_ >> 4, r16 = lane_ & 15;
    int rg = nt*128 + nf*16 + r16;
    int k0 = ks*32 + q*8;
    s16x8 v;
    if (rg < NR) {
        if (k0 + 7 < NPF) {
            const float* p = pd + (size_t)rg * NPF + k0;
            #pragma unroll
            for (int k = 0; k < 8; ++k) v[k] = f2bf(p[k]);
        } else {
            #pragma unroll
            for (int k = 0; k < 8; ++k) {
                int col = k0 + k;
                float f = 0.0f;
                if (col < NPF)     f = pd[(size_t)rg * NPF + col];
                else if (col < KB) f = sd[(size_t)rg * 10 + (col - NPF)];
                v[k] = f2bf(f);
            }
        }
    } else {
        #pragma unroll
        for (int k = 0; k < 8; ++k) v[k] = 0;
    }
    *(s16x8*)&Bf[(size_t)cid * 8] = v;
}

// ============ K3: JD partials, part layout [bi][i(72)][k(224)] ============
__global__ __launch_bounds__(256) void k_jdirs(const float* __restrict__ pd,
        const float* __restrict__ sd, const float* __restrict__ vt,
        const float* __restrict__ Jreg, float* __restrict__ part) {
    __shared__ float wjs[24][VPB];
    int bi = blockIdx.x;
    int v0 = bi * VPB;
    int nv = NV - v0; if (nv > VPB) nv = VPB; if (nv < 0) nv = 0;
    for (int i = threadIdx.x; i < 24*VPB; i += 256) {
        int j = i / VPB, vv = i - j*VPB;
        wjs[j][vv] = (vv < nv) ? Jreg[(size_t)j * NV + v0 + vv] : 0.0f;
    }
    __syncthreads();
    int k = threadIdx.x;
    float acc[72];
    #pragma unroll
    for (int i = 0; i < 72; ++i) acc[i] = 0.0f;
    for (int vv = 0; vv < VPB; ++vv) {
        int v = v0 + vv;
        if (v >= NV) break;
        #pragma unroll
        for (int c = 0; c < 3; ++c) {
            int row = v*3 + c;
            float val = 0.0f;
            if (k < NPF)      val = pd[(size_t)row * NPF + k];
            else if (k < KB)  val = sd[(size_t)row * 10 + (k - NPF)];
            else if (k == KB) val = vt[row];
            #pragma unroll
            for (int j = 0; j < 24; ++j) acc[j*3 + c] += wjs[j][vv] * val;
        }
    }
    if (k < 224) {
        float* p = part + (size_t)bi * (72*224);
        #pragma unroll
        for (int i = 0; i < 72; ++i) p[i*224 + k] = acc[i];
    }
}

// ============ K4a: reduce 512 -> 8 partials, coalesced ============
__global__ __launch_bounds__(256) void k_jreduce1(const float* __restrict__ part,
        float* __restrict__ part2) {
    int i = blockIdx.x;            // 0..71
    int s = blockIdx.y;            // 0..7
    int k = threadIdx.x;
    if (k >= 224) return;
    float acc = 0.0f;
    #pragma unroll 4
    for (int bi = s*64; bi < s*64 + 64; ++bi)
        acc += part[(size_t)bi * (72*224) + i*224 + k];
    part2[((size_t)s * 72 + i) * 224 + k] = acc;
}

// ============ K4b: reduce 8 -> JDt[k][72] ============
__global__ __launch_bounds__(256) void k_jreduce2(const float* __restrict__ part2,
        float* __restrict__ JDt) {
    int e = blockIdx.x * 256 + threadIdx.x;    // e = i*224 + k
    if (e >= 72*224) return;
    int i = e / 224, k = e - i*224;
    float s = 0.0f;
    #pragma unroll
    for (int ss = 0; ss < 8; ++ss)
        s += part2[((size_t)ss * 72 + i) * 224 + k];
    if (k < 218) JDt[k*72 + i] = s;
}

// ============ K5: J[b][jc] = JDt[217][jc] + sum_k pfA[b][k]*JDt[k][jc] ============
__global__ __launch_bounds__(128) void k_J(const float* __restrict__ pfA,
        const float* __restrict__ JDt, float* __restrict__ Jout, int B) {
    int b = blockIdx.x, t = threadIdx.x;
    if (t >= 72) return;
    const float* pa = pfA + (size_t)b * 224;
    float acc = JDt[217*72 + t];
    #pragma unroll 7
    for (int k = 0; k < KB; ++k) acc += pa[k] * JDt[k*72 + t];
    Jout[(size_t)b * 72 + t] = acc;
}

// ============ K6: kinematic chain -> G_corr (B,24,12) ============
__global__ __launch_bounds__(32) void k_chain(const float* __restrict__ Rg,
        const float* __restrict__ Jg, float* __restrict__ Gc, int B) {
    __shared__ float Gs[32 * 289];
    int b = blockIdx.x * 32 + threadIdx.x;
    if (b >= B) return;
    float* G = &Gs[threadIdx.x * 289];
    float Jl[72];
    const float* Jb = Jg + (size_t)b * 72;
    #pragma unroll
    for (int i = 0; i < 72; ++i) Jl[i] = Jb[i];
    const float* Rb = Rg + (size_t)b * 216;
    G[0]=Rb[0]; G[1]=Rb[1]; G[2]=Rb[2];  G[3]=Jl[0];
    G[4]=Rb[3]; G[5]=Rb[4]; G[6]=Rb[5];  G[7]=Jl[1];
    G[8]=Rb[6]; G[9]=Rb[7]; G[10]=Rb[8]; G[11]=Jl[2];
    #pragma unroll
    for (int i = 1; i < NJ; ++i) {
        const int p = PAR[i];
        const float* Ri = Rb + i*9;
        float r00=Ri[0],r01=Ri[1],r02=Ri[2];
        float r10=Ri[3],r11=Ri[4],r12=Ri[5];
        float r20=Ri[6],r21=Ri[7],r22=Ri[8];
        float px=Jl[p*3+0], py=Jl[p*3+1], pz=Jl[p*3+2];
        float tx = Jl[i*3+0] - (r00*px + r01*py + r02*pz);
        float ty = Jl[i*3+1] - (r10*px + r11*py + r12*pz);
        float tz = Jl[i*3+2] - (r20*px + r21*py + r22*pz);
        const float* gp = &G[p*12];
        float* gi = &G[i*12];
        #pragma unroll
        for (int rr = 0; rr < 3; ++rr) {
            float a0=gp[rr*4+0], a1=gp[rr*4+1], a2=gp[rr*4+2], a3=gp[rr*4+3];
            gi[rr*4+0] = a0*r00 + a1*r10 + a2*r20;
            gi[rr*4+1] = a0*r01 + a1*r11 + a2*r21;
            gi[rr*4+2] = a0*r02 + a1*r12 + a2*r22;
            gi[rr*4+3] = a0*tx + a1*ty + a2*tz + a3;
        }
    }
    float* out = Gc + (size_t)b * 288;
    #pragma unroll
    for (int i = 0; i < NJ; ++i) {
        const float* gi = &G[i*12];
        float jx=Jl[i*3+0], jy=Jl[i*3+1], jz=Jl[i*3+2];
        #pragma unroll
        for (int rr = 0; rr < 3; ++rr) {
            out[i*12+rr*4+0] = gi[rr*4+0];
            out[i*12+rr*4+1] = gi[rr*4+1];
            out[i*12+rr*4+2] = gi[rr*4+2];
            out[i*12+rr*4+3] = gi[rr*4+3] - (gi[rr*4+0]*jx + gi[rr*4+1]*jy + gi[rr*4+2]*jz);
        }
    }
}

// ============ K6b: Gmf[b][lane][8] bf16 skin-A-fragments from G_corr (R9-proven layout) ============
__global__ __launch_bounds__(256) void k_gmf(const float* __restrict__ Gc,
        short* __restrict__ Gmf, int B) {
    int idx = blockIdx.x * 256 + threadIdx.x;      // b*64 + lane
    if (idx >= B * 64) return;
    int lane_ = idx & 63, b = idx >> 6;
    int q = lane_ >> 4, c = lane_ & 15;
    s16x8 v;
    if (c < 12 && q < 3) {
        #pragma unroll
        for (int e = 0; e < 8; ++e)
            v[e] = f2bf(Gc[(size_t)b * 288 + (q*8 + e)*12 + c]);
    } else {
        #pragma unroll
        for (int e = 0; e < 8; ++e) v[e] = 0;
    }
    *(s16x8*)&Gmf[(size_t)idx * 8] = v;
}

// ============ K7: streaming-fragment MFMA GEMM, f32 out (fallback path) ============
__global__ __launch_bounds__(256, 2) void k_gemm(const short* __restrict__ Af,
        const short* __restrict__ Bf, const float* __restrict__ vt,
        float* __restrict__ vout, int B) {
    __shared__ float eld[64 * 128];
    const int t = threadIdx.x;
    const int wgid = blockIdx.x;
    const int bt = wgid & 7, nt = wgid >> 3;
    const int wave = t >> 6, lane = t & 63;
    const int wn = (wave & 1) * 64;
    const int q = lane >> 4, r16 = lane & 15;
    const int mfb = (wave >> 1) * 4, nfb = (wave & 1) * 4;

    const s16x8* Ab = (const s16x8*)(Af + (size_t)bt * FTILE);
    const s16x8* Bb = (const s16x8*)(Bf + (size_t)nt * FTILE);

    f32x4 acc[4][4];
    #pragma unroll
    for (int m = 0; m < 4; ++m)
        #pragma unroll
        for (int n = 0; n < 4; ++n)
            #pragma unroll
            for (int i = 0; i < 4; ++i) acc[m][n][i] = 0.0f;

    #pragma unroll
    for (int ks = 0; ks < 8; ++ks) {
        s16x8 a[4], b[4];
        #pragma unroll
        for (int m = 0; m < 4; ++m) a[m] = Ab[(ks*8 + mfb + m)*64 + lane];
        #pragma unroll
        for (int n = 0; n < 4; ++n) b[n] = Bb[(ks*8 + nfb + n)*64 + lane];
        #pragma unroll
        for (int m = 0; m < 4; ++m)
            #pragma unroll
            for (int n = 0; n < 4; ++n)
                acc[m][n] = __builtin_amdgcn_mfma_f32_16x16x32_bf16(a[m], b[n], acc[m][n], 0, 0, 0);
    }

    #pragma unroll
    for (int half = 0; half < 2; ++half) {
        if ((wave >> 1) == half) {
            #pragma unroll
            for (int m = 0; m < 4; ++m)
                #pragma unroll
                for (int n = 0; n < 4; ++n)
                    #pragma unroll
                    for (int i = 0; i < 4; ++i) {
                        int row_l = m*16 + q*4 + i;
                        int col = wn + n*16 + r16;
                        eld[row_l * 128 + (col ^ ((row_l & 7) << 2))] = acc[m][n][i];
                    }
        }
        __syncthreads();
        {
            const int c32 = t & 31;
            const int col = c32 * 4;
            const int rsub = (t >> 5) & 1;
            #pragma unroll
            for (int it = 0; it < 8; ++it) {
                int row_l = it * 8 + wave * 2 + rsub;
                int bg = bt * 128 + half * 64 + row_l;
                int rg = nt * 128 + col;
                f32x4 v = *(const f32x4*)&eld[row_l * 128 + (col ^ ((row_l & 7) << 2))];
                if (bg < B) {
                    float* dst = vout + (size_t)bg * NR + rg;
                    if (rg + 3 < NR) {
                        float4 tv = *(const float4*)(vt + rg);
                        v[0] += tv.x; v[1] += tv.y; v[2] += tv.z; v[3] += tv.w;
                        *(f4u*)dst = v;
                    } else {
                        #pragma unroll
                        for (int e = 0; e < 4; ++e)
                            if (rg + e < NR) dst[e] = v[e] + vt[rg + e];
                    }
                }
            }
        }
        __syncthreads();
    }
}

// ============ K7b: GEMM, padded bf16 v_posed out ([b][vert(6912)][4] bf16) ============
__global__ __launch_bounds__(256, 2) void k_gemm_bf(const short* __restrict__ Af,
        const short* __restrict__ Bf, const float* __restrict__ vt,
        short* __restrict__ vpbf, int B) {
    __shared__ float eld[64 * 128];
    const int t = threadIdx.x;
    const int wgid = blockIdx.x;
    const int bt = wgid & 7, nt = wgid >> 3;
    const int wave = t >> 6, lane = t & 63;
    const int wn = (wave & 1) * 64;
    const int q = lane >> 4, r16 = lane & 15;
    const int mfb = (wave >> 1) * 4, nfb = (wave & 1) * 4;

    const s16x8* Ab = (const s16x8*)(Af + (size_t)bt * FTILE);
    const s16x8* Bb = (const s16x8*)(Bf + (size_t)nt * FTILE);

    f32x4 acc[4][4];
    #pragma unroll
    for (int m = 0; m < 4; ++m)
        #pragma unroll
        for (int n = 0; n < 4; ++n)
            #pragma unroll
            for (int i = 0; i < 4; ++i) acc[m][n][i] = 0.0f;

    #pragma unroll
    for (int ks = 0; ks < 8; ++ks) {
        s16x8 a[4], b[4];
        #pragma unroll
        for (int m = 0; m < 4; ++m) a[m] = Ab[(ks*8 + mfb + m)*64 + lane];
        #pragma unroll
        for (int n = 0; n < 4; ++n) b[n] = Bb[(ks*8 + nfb + n)*64 + lane];
        #pragma unroll
        for (int m = 0; m < 4; ++m)
            #pragma unroll
            for (int n = 0; n < 4; ++n)
                acc[m][n] = __builtin_amdgcn_mfma_f32_16x16x32_bf16(a[m], b[n], acc[m][n], 0, 0, 0);
    }

    #pragma unroll
    for (int half = 0; half < 2; ++half) {
        if ((wave >> 1) == half) {
            #pragma unroll
            for (int m = 0; m < 4; ++m)
                #pragma unroll
                for (int n = 0; n < 4; ++n)
                    #pragma unroll
                    for (int i = 0; i < 4; ++i) {
                        int row_l = m*16 + q*4 + i;
                        int col = wn + n*16 + r16;
                        eld[row_l * 128 + (col ^ ((row_l & 7) << 2))] = acc[m][n][i];
                    }
        }
        __syncthreads();
        {
            const int col0 = (t & 15) * 8;
            const int rsub = t >> 4;               // 0..15
            #pragma unroll
            for (int it = 0; it < 4; ++it) {
                int row_l = it * 16 + rsub;        // 0..63
                int bg = bt * 128 + half * 64 + row_l;
                int rg0 = nt * 128 + col0;
                int sw = (row_l & 7) << 2;
                f32x4 v0 = *(const f32x4*)&eld[row_l * 128 + (col0 ^ sw)];
                f32x4 v1 = *(const f32x4*)&eld[row_l * 128 + ((col0 + 4) ^ sw)];
                if (bg < B) {
                    short* dstb = vpbf + (size_t)bg * (NVP*4);
                    #pragma unroll
                    for (int e = 0; e < 8; ++e) {
                        int rg = rg0 + e;
                        if (rg < NR) {
                            float f = (e < 4 ? v0[e] : v1[e-4]) + vt[rg];
                            int vert = rg / 3;
                            int comp = rg - vert*3;
                            dstb[vert*4 + comp] = f2bf(f);
                        }
                    }
                }
            }
        }
        __syncthreads();
    }
}

// ============ K8: MFMA skinning, f32 in-place (fallback) ============
__global__ __launch_bounds__(256) void k_skin(float* __restrict__ vio,
        const float* __restrict__ W, const float* __restrict__ Gc, int B) {
    __shared__ short Gm[16 * 40];
    const int t = threadIdx.x;
    const int wave = t >> 6, lane = t & 63;
    const int q = lane >> 4, c = lane & 15;
    const int vb = blockIdx.x * 256 + wave * 64;
    const int b0 = blockIdx.y * 16;

    if (t < 320) ((int*)Gm)[t] = 0;

    s16x8 wf[4];
    #pragma unroll
    for (int m = 0; m < 4; ++m) {
        int vert = vb + m*16 + c;
        if (q < 3 && vert < NV) {
            const float* wp = W + (size_t)vert * NJ + q*8;
            float4 f0 = *(const float4*)(wp);
            float4 f1 = *(const float4*)(wp + 4);
            wf[m][0]=f2bf(f0.x); wf[m][1]=f2bf(f0.y); wf[m][2]=f2bf(f0.z); wf[m][3]=f2bf(f0.w);
            wf[m][4]=f2bf(f1.x); wf[m][5]=f2bf(f1.y); wf[m][6]=f2bf(f1.z); wf[m][7]=f2bf(f1.w);
        } else {
            #pragma unroll
            for (int e = 0; e < 8; ++e) wf[m][e] = 0;
        }
    }
    __syncthreads();

    for (int bb = 0; bb < 16; ++bb) {
        int b = b0 + bb;
        if (b >= B) break;
        {
            int i0 = t;
            int j0 = i0 / 12, c0 = i0 - j0*12;
            if (i0 < 288) Gm[c0*40 + j0] = f2bf(Gc[(size_t)b*288 + i0]);
            int i1 = t + 256;
            if (i1 < 288) {
                int j1 = i1 / 12, c1 = i1 - j1*12;
                Gm[c1*40 + j1] = f2bf(Gc[(size_t)b*288 + i1]);
            }
        }
        __syncthreads();

        s16x8 af = *(const s16x8*)&Gm[c*40 + q*8];
        #pragma unroll
        for (int m = 0; m < 4; ++m) {
            f32x4 zz = {0.0f, 0.0f, 0.0f, 0.0f};
            f32x4 acc = __builtin_amdgcn_mfma_f32_16x16x32_bf16(af, wf[m], zz, 0, 0, 0);
            int vert = vb + m*16 + c;
            bool ok = (q < 3) && (vert < NV);
            if (ok) {
                float* vp = vio + (size_t)b * NR + (size_t)vert * 3;
                float x = vp[0], y = vp[1], z = vp[2];
                float o = acc[0]*x + acc[1]*y + acc[2]*z + acc[3];
                vp[q] = o;
            }
        }
        __syncthreads();
    }
}

// ============ K8b: pipelined barrier-free skinning, padded bf16 in (1 dwordx2/vert) ============
__global__ __launch_bounds__(256) void k_skin_bf(const short* __restrict__ vpbf,
        float* __restrict__ vout, const float* __restrict__ W,
        const short* __restrict__ Gmf, int B) {
    const int t = threadIdx.x;
    const int wave = t >> 6, lane = t & 63;
    const int q = lane >> 4, c = lane & 15;
    const int vb = blockIdx.x * 256 + wave * 64;
    const int b0 = blockIdx.y * NB;

    s16x8 wf[4];
    int vert[4];
    bool vok[4];
    #pragma unroll
    for (int m = 0; m < 4; ++m) {
        vert[m] = vb + m*16 + c;
        vok[m] = (q < 3) && (vert[m] < NV);
        if (vok[m]) {
            const float* wp = W + (size_t)vert[m] * NJ + q*8;
        float4 f0 = *(const float4*)(wp);
            float4 f1 = *(const float4*)(wp + 4);
            wf[m][0]=f2bf(f0.x); wf[m][1]=f2bf(f0.y); wf[m][2]=f2bf(f0.z); wf[m][3]=f2bf(f0.w);
            wf[m][4]=f2bf(f1.x); wf[m][5]=f2bf(f1.y); wf[m][6]=f2bf(f1.z); wf[m][7]=f2bf(f1.w);
        } else {
            #pragma unroll
            for (int e = 0; e < 8; ++e) wf[m][e] = 0;
        }
    }

    // unconditional loads (vpbf padded to NVP verts; vert[m] < NVP always)
#define LOADTO(bx, af_, v_)                                                        \
    {                                                                              \
        af_ = *(const s16x8*)&Gmf[((size_t)(bx) * 64 + lane) * 8];                 \
        const short* vbase_ = vpbf + (size_t)(bx) * (NVP*4);                       \
        _Pragma("unroll")                                                          \
        for (int m = 0; m < 4; ++m)                                                \
            v_[m] = *(const u32x2*)&vbase_[vert[m] * 4];                           \
    }

#define COMPUTE(bx, af_, v_)                                                       \
    {                                                                              \
        _Pragma("unroll")                                                          \
        for (int m = 0; m < 4; ++m) {                                              \
            f32x4 zz = {0.0f, 0.0f, 0.0f, 0.0f};                                   \
            f32x4 acc = __builtin_amdgcn_mfma_f32_16x16x32_bf16(af_, wf[m], zz, 0, 0, 0); \
            if (vok[m]) {                                                          \
                float x = bf2f(v_[m][0] & 0xffffu);                                \
                float y = bf2f(v_[m][0] >> 16);                                    \
                float z = bf2f(v_[m][1] & 0xffffu);                                \
                float o = acc[0]*x + acc[1]*y + acc[2]*z + acc[3];                 \
                vout[(size_t)(bx) * NR + (size_t)vert[m] * 3 + q] = o;             \
            }                                                                      \
        }                                                                          \
    }

    s16x8 afA, afB;
    u32x2 vA[4], vB[4];

    LOADTO(b0, afA, vA);
    #pragma unroll
    for (int bb = 0; bb < NB; bb += 2) {
        if (bb + 1 < NB) LOADTO(b0 + bb + 1, afB, vB);
        COMPUTE(b0 + bb, afA, vA);
        if (bb + 2 < NB) LOADTO(b0 + bb + 2, afA, vA);
        if (bb + 1 < NB) COMPUTE(b0 + bb + 1, afB, vB);
    }
#undef LOADTO
#undef COMPUTE
}

extern "C" void kernel_launch(void* const* d_in, const int* in_sizes, int n_in,
                              void* d_out, int out_size, void* d_ws, size_t ws_size,
                              hipStream_t stream) {
    const float* theta = (const float*)d_in[0];
    const float* beta  = (const float*)d_in[1];
    const float* sd    = (const float*)d_in[2];
    const float* pd    = (const float*)d_in[3];
    const float* Jreg  = (const float*)d_in[4];
    const float* vt    = (const float*)d_in[5];
    const float* W     = (const float*)d_in[6];
    float* out = (float*)d_out;

    const int B = in_sizes[0] / 72;

    float* vregion = out;
    float* Jout    = out + (size_t)B * NR;

    float* Rws   = (float*)d_ws;                          // B*216 f32
    float* Gcws  = Rws + (size_t)B * 216;                 // B*288 f32
    float* pfA   = Gcws + (size_t)B * 288;                // B*224 f32
    short* Afrag = (short*)(pfA + (size_t)B * 224);       // 8*FTILE bf16 (512 KB)
    short* Bfrag = Afrag + (size_t)(B/128) * FTILE;       // 162*FTILE bf16 (10.6 MB)
    short* vpbf  = Bfrag + (size_t)NT * FTILE;            // B*NVP*4 bf16 (56.6 MB, optional)
    short* Gmf   = vpbf + (size_t)B * NVP * 4;            // B*512 bf16 (1 MB, optional)

    size_t base_bytes = (size_t)B * 2912 + (size_t)(B/128) * FTILE * 2 + (size_t)NT * FTILE * 2;
    size_t need_bf    = base_bytes + (size_t)B * NVP * 4 * 2 + (size_t)B * 512 * 2;
    const bool use_bf = (ws_size >= need_bf);

    float* part  = vregion;                               // d_out scratch pre-GEMM
    float* part2 = vregion + (size_t)NSPLIT * 72 * 224;
    float* JDt   = part2 + (size_t)8 * 72 * 224;

    k_rodrigues<<<(B*NJ + 255)/256, 256, 0, stream>>>(theta, beta, Rws, pfA, Afrag, B);
    k_convB<<<(NT*8*8*64)/256, 256, 0, stream>>>(pd, sd, Bfrag);
    k_jdirs<<<NSPLIT, 256, 0, stream>>>(pd, sd, vt, Jreg, part);
    {
        dim3 grid(72, 8);
        k_jreduce1<<<grid, 256, 0, stream>>>(part, part2);
    }
    k_jreduce2<<<(72*224 + 255)/256, 256, 0, stream>>>(part2, JDt);
    k_J<<<B, 128, 0, stream>>>(pfA, JDt, Jout, B);
    k_chain<<<(B + 31)/32, 32, 0, stream>>>(Rws, Jout, Gcws, B);

    if (use_bf) {
        k_gmf<<<(B*64 + 255)/256, 256, 0, stream>>>(Gcws, Gmf, B);
        k_gemm_bf<<<NT * (B/128), 256, 0, stream>>>(Afrag, Bfrag, vt, vpbf, B);
        dim3 grid((NV + 255)/256, (B + NB - 1)/NB);
        k_skin_bf<<<grid, 256, 0, stream>>>(vpbf, vregion, W, Gmf, B);
    } else {
        k_gemm<<<NT * (B/128), 256, 0, stream>>>(Afrag, Bfrag, vt, vregion, B);
        dim3 grid((NV + 255)/256, (B + 15)/16);
        k_skin<<<grid, 256, 0, stream>>>(vregion, W, Gcws, B);
    }
}

// Round 17
// 141.597 us; speedup vs baseline: 1.3600x; 1.3600x over previous
//
#include <hip/hip_runtime.h>
#include <hip/hip_bf16.h>

#define NJ 24
#define NV 6890
#define NVP 6912         // padded vertex count
#define NR (NV*3)        // 20670 output rows per batch
#define NPF 207
#define KB 217           // 207 pf + 10 beta
#define KP 256           // padded K (8 x 32)
#define NT 162           // 128-col tiles (fallback path)
#define NT2 108          // 192-col tiles (64 whole verts each)
#define NSPLIT 512       // jdirs v-splits
#define VPB 14           // ceil(6890/512)
#define FTILE 32768      // A-tile shorts: 8 ks * 8 frag * 64 lane * 8
#define FT2   49152      // B-tile shorts (192-col): 8 ks * 12 frag * 64 lane * 8
#define NB 8             // skin batches per block

typedef short s16x8 __attribute__((ext_vector_type(8)));
typedef short s16x4 __attribute__((ext_vector_type(4)));
typedef float f32x4 __attribute__((ext_vector_type(4)));
typedef float f4u   __attribute__((ext_vector_type(4), aligned(4)));
typedef unsigned int u32x2 __attribute__((ext_vector_type(2)));

__device__ constexpr int PAR[24] = {-1,0,0,0,1,2,3,4,5,6,7,8,9,9,9,12,13,14,16,17,18,19,20,21};

__device__ __forceinline__ short f2bf(float f) {
    __hip_bfloat16 h = __float2bfloat16(f);
    return *reinterpret_cast<short*>(&h);
}
__device__ __forceinline__ float bf2f(unsigned int u) {
    unsigned int x = u << 16;
    return __uint_as_float(x);
}

// A-fragment address for (row_in_tile, k)
__device__ __forceinline__ size_t frag_addr(int row128, int k) {
    int ks = k >> 5, q = (k >> 3) & 3, e = k & 7;
    int mf = row128 >> 4, r16 = row128 & 15;
    return ((size_t)(ks*8 + mf) * 64 + q*16 + r16) * 8 + e;
}

// swizzled index into eld[64][192] f32
__device__ __forceinline__ int eswz(int row, int col) {
    return row * 192 + ((col & ~3) ^ ((row & 7) << 2)) + (col & 3);
}

// ============ K1: Rodrigues -> Rws(f32), pfA(f32), Afrag(bf16 fragment layout) ============
__global__ __launch_bounds__(256) void k_rodrigues(const float* __restrict__ theta,
        const float* __restrict__ beta, float* __restrict__ Rws,
        float* __restrict__ pfA, short* __restrict__ Afrag, int B) {
    int idx = blockIdx.x * blockDim.x + threadIdx.x;   // b*24 + j
    if (idx >= B * NJ) return;
    int b = idx / NJ, j = idx % NJ;
    float x = theta[b*72 + j*3 + 0];
    float y = theta[b*72 + j*3 + 1];
    float z = theta[b*72 + j*3 + 2];
    float n = sqrtf(x*x + y*y + z*z);
    float a = fmaxf(n, 1e-8f);
    float inv = 1.0f / a;
    float ix = x*inv, iy = y*inv, iz = z*inv;
    float c = cosf(a), s = sinf(a), t = 1.0f - c;
    float r[9];
    r[0] = t*ix*ix + c;     r[1] = t*ix*iy - s*iz;  r[2] = t*ix*iz + s*iy;
    r[3] = t*ix*iy + s*iz;  r[4] = t*iy*iy + c;     r[5] = t*iy*iz - s*ix;
    r[6] = t*ix*iz - s*iy;  r[7] = t*iy*iz + s*ix;  r[8] = t*iz*iz + c;
    float* Rp = Rws + (size_t)idx * 9;
    #pragma unroll
    for (int k = 0; k < 9; ++k) Rp[k] = r[k];

    int rb = b & 127;
    short* At = Afrag + (size_t)(b >> 7) * FTILE;
    float* pa = pfA + (size_t)b * 224;
    if (j >= 1) {
        #pragma unroll
        for (int kk = 0; kk < 9; ++kk) {
            int k = (j-1)*9 + kk;
            float f = r[kk] - ((kk == 0 || kk == 4 || kk == 8) ? 1.0f : 0.0f);
            At[frag_addr(rb, k)] = f2bf(f);
            pa[k] = f;
        }
    } else {
        #pragma unroll
        for (int kk = 0; kk < 10; ++kk) {
            int k = NPF + kk;
            float f = beta[b*10 + kk];
            At[frag_addr(rb, k)] = f2bf(f);
            pa[k] = f;
        }
        for (int k = KB; k < KP; ++k)
            At[frag_addr(rb, k)] = 0;
    }
}

// ============ K2a: Bfrag for 192-col tiles (R9-proven mapping) ============
__global__ __launch_bounds__(256) void k_convB192(const float* __restrict__ pd,
        const float* __restrict__ sd, short* __restrict__ Bf) {
    int nt = blockIdx.y;
    int id = blockIdx.x * 256 + threadIdx.x;       // (ks*12 + nf)*64 + lane
    int lane_ = id & 63;
    int fi = id >> 6;                              // 0..95
    int nf = fi % 12, ks = fi / 12;
    int q = lane_ >> 4, r16 = lane_ & 15;
    int rg = nt*192 + nf*16 + r16;
    int k0 = ks*32 + q*8;
    s16x8 v;
    if (rg < NR) {
        if (k0 + 7 < NPF) {
            const float* p = pd + (size_t)rg * NPF + k0;
            #pragma unroll
            for (int k = 0; k < 8; ++k) v[k] = f2bf(p[k]);
        } else {
            #pragma unroll
            for (int k = 0; k < 8; ++k) {
                int col = k0 + k;
                float f = 0.0f;
                if (col < NPF)     f = pd[(size_t)rg * NPF + col];
                else if (col < KB) f = sd[(size_t)rg * 10 + (col - NPF)];
                v[k] = f2bf(f);
            }
        }
    } else {
        #pragma unroll
        for (int k = 0; k < 8; ++k) v[k] = 0;
    }
    *(s16x8*)&Bf[((size_t)nt * FT2) + (size_t)id * 8] = v;
}

// ============ K2b: Bfrag for 128-col tiles (fallback) ============
__global__ __launch_bounds__(256) void k_convB128(const float* __restrict__ pd,
        const float* __restrict__ sd, short* __restrict__ Bf) {
    int cid = blockIdx.x * 256 + threadIdx.x;
    int lane_ = cid & 63;
    int nf = (cid >> 6) & 7;
    int ks = (cid >> 9) & 7;
    int nt = cid >> 12;
    int q = lane_ >> 4, r16 = lane_ & 15;
    int rg = nt*128 + nf*16 + r16;
    int k0 = ks*32 + q*8;
    s16x8 v;
    if (rg < NR) {
        if (k0 + 7 < NPF) {
            const float* p = pd + (size_t)rg * NPF + k0;
            #pragma unroll
            for (int k = 0; k < 8; ++k) v[k] = f2bf(p[k]);
        } else {
            #pragma unroll
            for (int k = 0; k < 8; ++k) {
                int col = k0 + k;
                float f = 0.0f;
                if (col < NPF)     f = pd[(size_t)rg * NPF + col];
                else if (col < KB) f = sd[(size_t)rg * 10 + (col - NPF)];
                v[k] = f2bf(f);
            }
        }
    } else {
        #pragma unroll
        for (int k = 0; k < 8; ++k) v[k] = 0;
    }
    *(s16x8*)&Bf[(size_t)cid * 8] = v;
}

// ============ K3: JD partials, part layout [bi][i(72)][k(224)] ============
__global__ __launch_bounds__(256) void k_jdirs(const float* __restrict__ pd,
        const float* __restrict__ sd, const float* __restrict__ vt,
        const float* __restrict__ Jreg, float* __restrict__ part) {
    __shared__ float wjs[24][VPB];
    int bi = blockIdx.x;
    int v0 = bi * VPB;
    int nv = NV - v0; if (nv > VPB) nv = VPB; if (nv < 0) nv = 0;
    for (int i = threadIdx.x; i < 24*VPB; i += 256) {
        int j = i / VPB, vv = i - j*VPB;
        wjs[j][vv] = (vv < nv) ? Jreg[(size_t)j * NV + v0 + vv] : 0.0f;
    }
    __syncthreads();
    int k = threadIdx.x;
    float acc[72];
    #pragma unroll
    for (int i = 0; i < 72; ++i) acc[i] = 0.0f;
    for (int vv = 0; vv < VPB; ++vv) {
        int v = v0 + vv;
        if (v >= NV) break;
        #pragma unroll
        for (int c = 0; c < 3; ++c) {
            int row = v*3 + c;
            float val = 0.0f;
            if (k < NPF)      val = pd[(size_t)row * NPF + k];
            else if (k < KB)  val = sd[(size_t)row * 10 + (k - NPF)];
            else if (k == KB) val = vt[row];
            #pragma unroll
            for (int j = 0; j < 24; ++j) acc[j*3 + c] += wjs[j][vv] * val;
        }
    }
    if (k < 224) {
        float* p = part + (size_t)bi * (72*224);
        #pragma unroll
        for (int i = 0; i < 72; ++i) p[i*224 + k] = acc[i];
    }
}

// ============ K4a: reduce 512 -> 8 partials, coalesced ============
__global__ __launch_bounds__(256) void k_jreduce1(const float* __restrict__ part,
        float* __restrict__ part2) {
    int i = blockIdx.x;            // 0..71
    int s = blockIdx.y;            // 0..7
    int k = threadIdx.x;
    if (k >= 224) return;
    float acc = 0.0f;
    #pragma unroll 4
    for (int bi = s*64; bi < s*64 + 64; ++bi)
        acc += part[(size_t)bi * (72*224) + i*224 + k];
    part2[((size_t)s * 72 + i) * 224 + k] = acc;
}

// ============ K4b: reduce 8 -> JDt[k][72] ============
__global__ __launch_bounds__(256) void k_jreduce2(const float* __restrict__ part2,
        float* __restrict__ JDt) {
    int e = blockIdx.x * 256 + threadIdx.x;    // e = i*224 + k
    if (e >= 72*224) return;
    int i = e / 224, k = e - i*224;
    float s = 0.0f;
    #pragma unroll
    for (int ss = 0; ss < 8; ++ss)
        s += part2[((size_t)ss * 72 + i) * 224 + k];
    if (k < 218) JDt[k*72 + i] = s;
}

// ============ K5: J[b][jc] = JDt[217][jc] + sum_k pfA[b][k]*JDt[k][jc] ============
__global__ __launch_bounds__(128) void k_J(const float* __restrict__ pfA,
        const float* __restrict__ JDt, float* __restrict__ Jout, int B) {
    int b = blockIdx.x, t = threadIdx.x;
    if (t >= 72) return;
    const float* pa = pfA + (size_t)b * 224;
    float acc = JDt[217*72 + t];
    #pragma unroll 7
    for (int k = 0; k < KB; ++k) acc += pa[k] * JDt[k*72 + t];
    Jout[(size_t)b * 72 + t] = acc;
}

// ============ K6: kinematic chain -> G_corr (B,24,12) ============
__global__ __launch_bounds__(32) void k_chain(const float* __restrict__ Rg,
        const float* __restrict__ Jg, float* __restrict__ Gc, int B) {
    __shared__ float Gs[32 * 289];
    int b = blockIdx.x * 32 + threadIdx.x;
    if (b >= B) return;
    float* G = &Gs[threadIdx.x * 289];
    float Jl[72];
    const float* Jb = Jg + (size_t)b * 72;
    #pragma unroll
    for (int i = 0; i < 72; ++i) Jl[i] = Jb[i];
    const float* Rb = Rg + (size_t)b * 216;
    G[0]=Rb[0]; G[1]=Rb[1]; G[2]=Rb[2];  G[3]=Jl[0];
    G[4]=Rb[3]; G[5]=Rb[4]; G[6]=Rb[5];  G[7]=Jl[1];
    G[8]=Rb[6]; G[9]=Rb[7]; G[10]=Rb[8]; G[11]=Jl[2];
    #pragma unroll
    for (int i = 1; i < NJ; ++i) {
        const int p = PAR[i];
        const float* Ri = Rb + i*9;
        float r00=Ri[0],r01=Ri[1],r02=Ri[2];
        float r10=Ri[3],r11=Ri[4],r12=Ri[5];
        float r20=Ri[6],r21=Ri[7],r22=Ri[8];
        float px=Jl[p*3+0], py=Jl[p*3+1], pz=Jl[p*3+2];
        float tx = Jl[i*3+0] - (r00*px + r01*py + r02*pz);
        float ty = Jl[i*3+1] - (r10*px + r11*py + r12*pz);
        float tz = Jl[i*3+2] - (r20*px + r21*py + r22*pz);
        const float* gp = &G[p*12];
        float* gi = &G[i*12];
        #pragma unroll
        for (int rr = 0; rr < 3; ++rr) {
            float a0=gp[rr*4+0], a1=gp[rr*4+1], a2=gp[rr*4+2], a3=gp[rr*4+3];
            gi[rr*4+0] = a0*r00 + a1*r10 + a2*r20;
            gi[rr*4+1] = a0*r01 + a1*r11 + a2*r21;
            gi[rr*4+2] = a0*r02 + a1*r12 + a2*r22;
            gi[rr*4+3] = a0*tx + a1*ty + a2*tz + a3;
        }
    }
    float* out = Gc + (size_t)b * 288;
    #pragma unroll
    for (int i = 0; i < NJ; ++i) {
        const float* gi = &G[i*12];
        float jx=Jl[i*3+0], jy=Jl[i*3+1], jz=Jl[i*3+2];
        #pragma unroll
        for (int rr = 0; rr < 3; ++rr) {
            out[i*12+rr*4+0] = gi[rr*4+0];
            out[i*12+rr*4+1] = gi[rr*4+1];
            out[i*12+rr*4+2] = gi[rr*4+2];
            out[i*12+rr*4+3] = gi[rr*4+3] - (gi[rr*4+0]*jx + gi[rr*4+1]*jy + gi[rr*4+2]*jz);
        }
    }
}

// ============ K6b: Gmf[b][lane][8] bf16 skin-A-fragments from G_corr ============
__global__ __launch_bounds__(256) void k_gmf(const float* __restrict__ Gc,
        short* __restrict__ Gmf, int B) {
    int idx = blockIdx.x * 256 + threadIdx.x;      // b*64 + lane
    if (idx >= B * 64) return;
    int lane_ = idx & 63, b = idx >> 6;
    int q = lane_ >> 4, c = lane_ & 15;
    s16x8 v;
    if (c < 12 && q < 3) {
        #pragma unroll
        for (int e = 0; e < 8; ++e)
            v[e] = f2bf(Gc[(size_t)b * 288 + (q*8 + e)*12 + c]);
    } else {
        #pragma unroll
        for (int e = 0; e < 8; ++e) v[e] = 0;
    }
    *(s16x8*)&Gmf[(size_t)idx * 8] = v;
}

// ============ K7: 128-col streaming GEMM, f32 out (fallback) ============
__global__ __launch_bounds__(256, 2) void k_gemm(const short* __restrict__ Af,
        const short* __restrict__ Bf, const float* __restrict__ vt,
        float* __restrict__ vout, int B) {
    __shared__ float eld[64 * 128];
    const int t = threadIdx.x;
    const int wgid = blockIdx.x;
    const int bt = wgid & 7, nt = wgid >> 3;
    const int wave = t >> 6, lane = t & 63;
    const int wn = (wave & 1) * 64;
    const int q = lane >> 4, r16 = lane & 15;
    const int mfb = (wave >> 1) * 4, nfb = (wave & 1) * 4;

    const s16x8* Ab = (const s16x8*)(Af + (size_t)bt * FTILE);
    const s16x8* Bb = (const s16x8*)(Bf + (size_t)nt * FTILE);

    f32x4 acc[4][4];
    #pragma unroll
    for (int m = 0; m < 4; ++m)
        #pragma unroll
        for (int n = 0; n < 4; ++n)
            #pragma unroll
            for (int i = 0; i < 4; ++i) acc[m][n][i] = 0.0f;

    #pragma unroll
    for (int ks = 0; ks < 8; ++ks) {
        s16x8 a[4], b[4];
        #pragma unroll
        for (int m = 0; m < 4; ++m) a[m] = Ab[(ks*8 + mfb + m)*64 + lane];
        #pragma unroll
        for (int n = 0; n < 4; ++n) b[n] = Bb[(ks*8 + nfb + n)*64 + lane];
        #pragma unroll
        for (int m = 0; m < 4; ++m)
            #pragma unroll
            for (int n = 0; n < 4; ++n)
                acc[m][n] = __builtin_amdgcn_mfma_f32_16x16x32_bf16(a[m], b[n], acc[m][n], 0, 0, 0);
    }

    #pragma unroll
    for (int half = 0; half < 2; ++half) {
        if ((wave >> 1) == half) {
            #pragma unroll
            for (int m = 0; m < 4; ++m)
                #pragma unroll
                for (int n = 0; n < 4; ++n)
                    #pragma unroll
                    for (int i = 0; i < 4; ++i) {
                        int row_l = m*16 + q*4 + i;
                        int col = wn + n*16 + r16;
                        eld[row_l * 128 + (col ^ ((row_l & 7) << 2))] = acc[m][n][i];
                    }
        }
        __syncthreads();
        {
            const int c32 = t & 31;
            const int col = c32 * 4;
            const int rsub = (t >> 5) & 1;
            #pragma unroll
            for (int it = 0; it < 8; ++it) {
                int row_l = it * 8 + wave * 2 + rsub;
                int bg = bt * 128 + half * 64 + row_l;
                int rg = nt * 128 + col;
                f32x4 v = *(const f32x4*)&eld[row_l * 128 + (col ^ ((row_l & 7) << 2))];
                if (bg < B) {
                    float* dst = vout + (size_t)bg * NR + rg;
                    if (rg + 3 < NR) {
                        float4 tv = *(const float4*)(vt + rg);
                        v[0] += tv.x; v[1] += tv.y; v[2] += tv.z; v[3] += tv.w;
                        *(f4u*)dst = v;
                    } else {
                        #pragma unroll
                        for (int e = 0; e < 4; ++e)
                            if (rg + e < NR) dst[e] = v[e] + vt[rg + e];
                    }
                }
            }
        }
        __syncthreads();
    }
}

// ============ K7b: 192-col streaming GEMM -> padded bf16 vpbf, vectorized vertex stores ============
__global__ __launch_bounds__(256, 2) void k_gemm_bf(const short* __restrict__ Af,
        const short* __restrict__ Bf, const float* __restrict__ vt,
        short* __restrict__ vpbf, int B) {
    __shared__ float eld[64 * 192];                // 48 KB
    const int t = threadIdx.x;
    const int wgid = blockIdx.x;
    const int bt = wgid & 7, nt = wgid >> 3;       // nt 0..107
    const int wave = t >> 6, lane = t & 63;
    const int wn = (wave & 1) * 96;
    const int q = lane >> 4, r16 = lane & 15;
    const int mfb = (wave >> 1) * 4, nfb = (wave & 1) * 6;

    const s16x8* Ab = (const s16x8*)(Af + (size_t)bt * FTILE);
    const s16x8* Bb = (const s16x8*)(Bf + (size_t)nt * FT2);

    f32x4 acc[4][6];
    #pragma unroll
    for (int m = 0; m < 4; ++m)
        #pragma unroll
        for (int n = 0; n < 6; ++n)
            #pragma unroll
            for (int i = 0; i < 4; ++i) acc[m][n][i] = 0.0f;

    #pragma unroll
    for (int ks = 0; ks < 8; ++ks) {
        s16x8 a[4], b[6];
        #pragma unroll
        for (int m = 0; m < 4; ++m) a[m] = Ab[(ks*8 + mfb + m)*64 + lane];
        #pragma unroll
        for (int n = 0; n < 6; ++n) b[n] = Bb[(ks*12 + nfb + n)*64 + lane];
        #pragma unroll
        for (int m = 0; m < 4; ++m)
            #pragma unroll
            for (int n = 0; n < 6; ++n)
                acc[m][n] = __builtin_amdgcn_mfma_f32_16x16x32_bf16(a[m], b[n], acc[m][n], 0, 0, 0);
    }

    // vt values for this wave's columns (cached once; reused both halves)
    float vtv[6];
    #pragma unroll
    for (int n = 0; n < 6; ++n) {
        int rg = nt*192 + wn + n*16 + r16;
        vtv[n] = (rg < NR) ? vt[rg] : 0.0f;
    }

    #pragma unroll
    for (int half = 0; half < 2; ++half) {
        // (a) owning wave-pair writes acc+vt into swizzled eld
        if ((wave >> 1) == half) {
            #pragma unroll
            for (int m = 0; m < 4; ++m)
                #pragma unroll
                for (int n = 0; n < 6; ++n)
                    #pragma unroll
                    for (int i = 0; i < 4; ++i) {
                        int row_l = m*16 + q*4 + i;              // 0..63
                        int col = wn + n*16 + r16;               // 0..191
                        eld[eswz(row_l, col)] = acc[m][n][i] + vtv[n];
                    }
        }
        __syncthreads();
        // (b) vertex stores: wave instr = one row, 64 lanes = 64 verts, 512B contiguous
        {
            #pragma unroll
            for (int it = 0; it < 16; ++it) {
                int r = it * 4 + wave;                           // 0..63
                int bg = bt * 128 + half * 64 + r;
                float x = eld[eswz(r, 3*lane + 0)];
                float y = eld[eswz(r, 3*lane + 1)];
                float z = eld[eswz(r, 3*lane + 2)];
                if (bg < B) {
                    s16x4 s;
                    s[0] = f2bf(x); s[1] = f2bf(y); s[2] = f2bf(z); s[3] = 0;
                    *(s16x4*)&vpbf[(size_t)bg * (NVP*4) + (size_t)(nt*64 + lane) * 4] = s;
                }
            }
        }
        __syncthreads();
    }
}

// ============ K8: MFMA skinning, f32 in-place (fallback) ============
__global__ __launch_bounds__(256) void k_skin(float* __restrict__ vio,
        const float* __restrict__ W, const float* __restrict__ Gc, int B) {
    __shared__ short Gm[16 * 40];
    const int t = threadIdx.x;
    const int wave = t >> 6, lane = t & 63;
    const int q = lane >> 4, c = lane & 15;
    const int vb = blockIdx.x * 256 + wave * 64;
    const int b0 = blockIdx.y * 16;

    if (t < 320) ((int*)Gm)[t] = 0;

    s16x8 wf[4];
    #pragma unroll
    for (int m = 0; m < 4; ++m) {
        int vert = vb + m*16 + c;
        if (q < 3 && vert < NV) {
            const float* wp = W + (size_t)vert * NJ + q*8;
            float4 f0 = *(const float4*)(wp);
            float4 f1 = *(const float4*)(wp + 4);
            wf[m][0]=f2bf(f0.x); wf[m][1]=f2bf(f0.y); wf[m][2]=f2bf(f0.z); wf[m][3]=f2bf(f0.w);
            wf[m][4]=f2bf(f1.x); wf[m][5]=f2bf(f1.y); wf[m][6]=f2bf(f1.z); wf[m][7]=f2bf(f1.w);
        } else {
            #pragma unroll
            for (int e = 0; e < 8; ++e) wf[m][e] = 0;
        }
    }
    __syncthreads();

    for (int bb = 0; bb < 16; ++bb) {
        int b = b0 + bb;
        if (b >= B) break;
        {
            int i0 = t;
            int j0 = i0 / 12, c0 = i0 - j0*12;
            if (i0 < 288) Gm[c0*40 + j0] = f2bf(Gc[(size_t)b*288 + i0]);
            int i1 = t + 256;
            if (i1 < 288) {
                int j1 = i1 / 12, c1 = i1 - j1*12;
                Gm[c1*40 + j1] = f2bf(Gc[(size_t)b*288 + i1]);
            }
        }
        __syncthreads();

        s16x8 af = *(const s16x8*)&Gm[c*40 + q*8];
        #pragma unroll
        for (int m = 0; m < 4; ++m) {
            f32x4 zz = {0.0f, 0.0f, 0.0f, 0.0f};
            f32x4 acc = __builtin_amdgcn_mfma_f32_16x16x32_bf16(af, wf[m], zz, 0, 0, 0);
            int vert = vb + m*16 + c;
            bool ok = (q < 3) && (vert < NV);
            if (ok) {
                float* vp = vio + (size_t)b * NR + (size_t)vert * 3;
                float x = vp[0], y = vp[1], z = vp[2];
                float o = acc[0]*x + acc[1]*y + acc[2]*z + acc[3];
                vp[q] = o;
            }
        }
        __syncthreads();
    }
}

// ============ K8b: pipelined barrier-free skinning, padded bf16 in (dwordx2/vert) ============
__global__ __launch_bounds__(256) void k_skin_bf(const short* __restrict__ vpbf,
        float* __restrict__ vout, const float* __restrict__ W,
        const short* __restrict__ Gmf, int B) {
    const int t = threadIdx.x;
    const int wave = t >> 6, lane = t & 63;
    const int q = lane >> 4, c = lane & 15;
    const int vb = blockIdx.x * 256 + wave * 64;
    const int b0 = blockIdx.y * NB;

    s16x8 wf[4];
    int vert[4];
    bool vok[4];
    #pragma unroll
    for (int m = 0; m < 4; ++m) {
        vert[m] = vb + m*16 + c;
        vok[m] = (q < 3) && (vert[m] < NV);
        if (vok[m]) {
            const float* wp = W + (size_t)vert[m] * NJ + q*8;
            float4 f0 = *(const float4*)(wp);
            float4 f1 = *(const float4*)(wp + 4);
            wf[m][0]=f2bf(f0.x); wf[m][1]=f2bf(f0.y); wf[m][2]=f2bf(f0.z); wf[m][3]=f2bf(f0.w);
            wf[m][4]=f2bf(f1.x); wf[m][5]=f2bf(f1.y); wf[m][6]=f2bf(f1.z); wf[m][7]=f2bf(f1.w);
        } else {
            #pragma unroll
            for (int e = 0; e < 8; ++e) wf[m][e] = 0;
        }
    }

#define LOADTO(bx, af_, v_)                                                        \
    {                                                                              \
        af_ = *(const s16x8*)&Gmf[((size_t)(bx) * 64 + lane) * 8];                 \
        const short* vbase_ = vpbf + (size_t)(bx) * (NVP*4);                       \
        _Pragma("unroll")                                                          \
        for (int m = 0; m < 4; ++m)                                                \
            v_[m] = *(const u32x2*)&vbase_[vert[m] * 4];                           \
    }

#define COMPUTE(bx, af_, v_)                                                       \
    {                                                                              \
        _Pragma("unroll")                                                          \
        for (int m = 0; m < 4; ++m) {                                              \
            f32x4 zz = {0.0f, 0.0f, 0.0f, 0.0f};                                   \
            f32x4 acc = __builtin_amdgcn_mfma_f32_16x16x32_bf16(af_, wf[m], zz, 0, 0, 0); \
            if (vok[m]) {                                                          \
                float x = bf2f(v_[m][0] & 0xffffu);                                \
                float y = bf2f(v_[m][0] >> 16);                                    \
                float z = bf2f(v_[m][1] & 0xffffu);                                \
                float o = acc[0]*x + acc[1]*y + acc[2]*z + acc[3];                 \
                vout[(size_t)(bx) * NR + (size_t)vert[m] * 3 + q] = o;             \
            }                                                                      \
        }                                                                          \
    }

    s16x8 afA, afB;
    u32x2 vA[4], vB[4];

    LOADTO(b0, afA, vA);
    #pragma unroll
    for (int bb = 0; bb < NB; bb += 2) {
        if (bb + 1 < NB) LOADTO(b0 + bb + 1, afB, vB);
        COMPUTE(b0 + bb, afA, vA);
        if (bb + 2 < NB) LOADTO(b0 + bb + 2, afA, vA);
        if (bb + 1 < NB) COMPUTE(b0 + bb + 1, afB, vB);
    }
#undef LOADTO
#undef COMPUTE
}

extern "C" void kernel_launch(void* const* d_in, const int* in_sizes, int n_in,
                              void* d_out, int out_size, void* d_ws, size_t ws_size,
                              hipStream_t stream) {
    const float* theta = (const float*)d_in[0];
    const float* beta  = (const float*)d_in[1];
    const float* sd    = (const float*)d_in[2];
    const float* pd    = (const float*)d_in[3];
    const float* Jreg  = (const float*)d_in[4];
    const float* vt    = (const float*)d_in[5];
    const float* W     = (const float*)d_in[6];
    float* out = (float*)d_out;

    const int B = in_sizes[0] / 72;

    float* vregion = out;
    float* Jout    = out + (size_t)B * NR;

    float* Rws   = (float*)d_ws;                          // B*216 f32
    float* Gcws  = Rws + (size_t)B * 216;                 // B*288 f32
    float* pfA   = Gcws + (size_t)B * 288;                // B*224 f32
    short* Afrag = (short*)(pfA + (size_t)B * 224);       // 8*FTILE bf16
    short* Bfrag = Afrag + (size_t)(B/128) * FTILE;       // NT2*FT2 == NT*FTILE shorts (10.6 MB)
    short* vpbf  = Bfrag + (size_t)NT2 * FT2;             // B*NVP*4 bf16 (56.6 MB, optional)
    short* Gmf   = vpbf + (size_t)B * NVP * 4;            // B*512 bf16 (1 MB, optional)

    size_t base_bytes = (size_t)B * 2912 + (size_t)(B/128) * FTILE * 2 + (size_t)NT2 * FT2 * 2;
    size_t need_bf    = base_bytes + (size_t)B * NVP * 4 * 2 + (size_t)B * 512 * 2;
    const bool use_bf = (ws_size >= need_bf);

    float* part  = vregion;                               // d_out scratch pre-GEMM
    float* part2 = vregion + (size_t)NSPLIT * 72 * 224;
    float* JDt   = part2 + (size_t)8 * 72 * 224;

    k_rodrigues<<<(B*NJ + 255)/256, 256, 0, stream>>>(theta, beta, Rws, pfA, Afrag, B);
    if (use_bf) {
        dim3 grid(24, NT2);
        k_convB192<<<grid, 256, 0, stream>>>(pd, sd, Bfrag);
    } else {
        k_convB128<<<(NT*8*8*64)/256, 256, 0, stream>>>(pd, sd, Bfrag);
    }
    k_jdirs<<<NSPLIT, 256, 0, stream>>>(pd, sd, vt, Jreg, part);
    {
        dim3 grid(72, 8);
        k_jreduce1<<<grid, 256, 0, stream>>>(part, part2);
    }
    k_jreduce2<<<(72*224 + 255)/256, 256, 0, stream>>>(part2, JDt);
    k_J<<<B, 128, 0, stream>>>(pfA, JDt, Jout, B);
    k_chain<<<(B + 31)/32, 32, 0, stream>>>(Rws, Jout, Gcws, B);

    if (use_bf) {
        k_gmf<<<(B*64 + 255)/256, 256, 0, stream>>>(Gcws, Gmf, B);
        k_gemm_bf<<<NT2 * (B/128), 256, 0, stream>>>(Afrag, Bfrag, vt, vpbf, B);
        dim3 grid((NV + 255)/256, (B + NB - 1)/NB);
        k_skin_bf<<<grid, 256, 0, stream>>>(vpbf, vregion, W, Gmf, B);
    } else {
        k_gemm<<<NT * (B/128), 256, 0, stream>>>(Afrag, Bfrag, vt, vregion, B);
        dim3 grid((NV + 255)/256, (B + 15)/16);
        k_skin<<<grid, 256, 0, stream>>>(vregion, W, Gcws, B);
    }
}

// Round 18
// 136.762 us; speedup vs baseline: 1.4081x; 1.0354x over previous
//
#include <hip/hip_runtime.h>
#include <hip/hip_bf16.h>

#define NJ 24
#define NV 6890
#define NVP 6912         // padded vertex count
#define NR (NV*3)        // 20670 output rows per batch
#define NPF 207
#define KB 217           // 207 pf + 10 beta
#define KP 256           // padded K (8 x 32)
#define NT 162           // 128-col tiles (fallback path)
#define NT2 108          // 192-col tiles (64 whole verts each)
#define NSPLIT 512       // jdirs v-splits
#define VPB 14           // ceil(6890/512)
#define FTILE 32768      // A-tile shorts: 8 ks * 8 frag * 64 lane * 8
#define FT2   49152      // B-tile shorts (192-col): 8 ks * 12 frag * 64 lane * 8
#define NB 8             // skin batches per block
#define ELDW 264         // elds row stride in shorts (64 verts*4 + 8 pad; 528B = 33x16B)

typedef short s16x8 __attribute__((ext_vector_type(8)));
typedef short s16x4 __attribute__((ext_vector_type(4)));
typedef float f32x4 __attribute__((ext_vector_type(4)));
typedef float f4u   __attribute__((ext_vector_type(4), aligned(4)));
typedef unsigned int u32x2 __attribute__((ext_vector_type(2)));

__device__ constexpr int PAR[24] = {-1,0,0,0,1,2,3,4,5,6,7,8,9,9,9,12,13,14,16,17,18,19,20,21};

__device__ __forceinline__ short f2bf(float f) {
    __hip_bfloat16 h = __float2bfloat16(f);
    return *reinterpret_cast<short*>(&h);
}
__device__ __forceinline__ float bf2f(unsigned int u) {
    unsigned int x = u << 16;
    return __uint_as_float(x);
}

// A-fragment address for (row_in_tile, k)
__device__ __forceinline__ size_t frag_addr(int row128, int k) {
    int ks = k >> 5, q = (k >> 3) & 3, e = k & 7;
    int mf = row128 >> 4, r16 = row128 & 15;
    return ((size_t)(ks*8 + mf) * 64 + q*16 + r16) * 8 + e;
}

// ============ K1: Rodrigues -> Rws(f32), pfA(f32), Afrag(bf16 fragment layout) ============
__global__ __launch_bounds__(256) void k_rodrigues(const float* __restrict__ theta,
        const float* __restrict__ beta, float* __restrict__ Rws,
        float* __restrict__ pfA, short* __restrict__ Afrag, int B) {
    int idx = blockIdx.x * blockDim.x + threadIdx.x;   // b*24 + j
    if (idx >= B * NJ) return;
    int b = idx / NJ, j = idx % NJ;
    float x = theta[b*72 + j*3 + 0];
    float y = theta[b*72 + j*3 + 1];
    float z = theta[b*72 + j*3 + 2];
    float n = sqrtf(x*x + y*y + z*z);
    float a = fmaxf(n, 1e-8f);
    float inv = 1.0f / a;
    float ix = x*inv, iy = y*inv, iz = z*inv;
    float c = cosf(a), s = sinf(a), t = 1.0f - c;
    float r[9];
    r[0] = t*ix*ix + c;     r[1] = t*ix*iy - s*iz;  r[2] = t*ix*iz + s*iy;
    r[3] = t*ix*iy + s*iz;  r[4] = t*iy*iy + c;     r[5] = t*iy*iz - s*ix;
    r[6] = t*ix*iz - s*iy;  r[7] = t*iy*iz + s*ix;  r[8] = t*iz*iz + c;
    float* Rp = Rws + (size_t)idx * 9;
    #pragma unroll
    for (int k = 0; k < 9; ++k) Rp[k] = r[k];

    int rb = b & 127;
    short* At = Afrag + (size_t)(b >> 7) * FTILE;
    float* pa = pfA + (size_t)b * 224;
    if (j >= 1) {
        #pragma unroll
        for (int kk = 0; kk < 9; ++kk) {
            int k = (j-1)*9 + kk;
            float f = r[kk] - ((kk == 0 || kk == 4 || kk == 8) ? 1.0f : 0.0f);
            At[frag_addr(rb, k)] = f2bf(f);
            pa[k] = f;
        }
    } else {
        #pragma unroll
        for (int kk = 0; kk < 10; ++kk) {
            int k = NPF + kk;
            float f = beta[b*10 + kk];
            At[frag_addr(rb, k)] = f2bf(f);
            pa[k] = f;
        }
        for (int k = KB; k < KP; ++k)
            At[frag_addr(rb, k)] = 0;
    }
}

// ============ K2a: Bfrag for 192-col tiles ============
__global__ __launch_bounds__(256) void k_convB192(const float* __restrict__ pd,
        const float* __restrict__ sd, short* __restrict__ Bf) {
    int nt = blockIdx.y;
    int id = blockIdx.x * 256 + threadIdx.x;       // (ks*12 + nf)*64 + lane
    int lane_ = id & 63;
    int fi = id >> 6;                              // 0..95
    int nf = fi % 12, ks = fi / 12;
    int q = lane_ >> 4, r16 = lane_ & 15;
    int rg = nt*192 + nf*16 + r16;
    int k0 = ks*32 + q*8;
    s16x8 v;
    if (rg < NR) {
        if (k0 + 7 < NPF) {
            const float* p = pd + (size_t)rg * NPF + k0;
            #pragma unroll
            for (int k = 0; k < 8; ++k) v[k] = f2bf(p[k]);
        } else {
            #pragma unroll
            for (int k = 0; k < 8; ++k) {
                int col = k0 + k;
                float f = 0.0f;
                if (col < NPF)     f = pd[(size_t)rg * NPF + col];
                else if (col < KB) f = sd[(size_t)rg * 10 + (col - NPF)];
                v[k] = f2bf(f);
            }
        }
    } else {
        #pragma unroll
        for (int k = 0; k < 8; ++k) v[k] = 0;
    }
    *(s16x8*)&Bf[((size_t)nt * FT2) + (size_t)id * 8] = v;
}

// ============ K2b: Bfrag for 128-col tiles (fallback) ============
__global__ __launch_bounds__(256) void k_convB128(const float* __restrict__ pd,
        const float* __restrict__ sd, short* __restrict__ Bf) {
    int cid = blockIdx.x * 256 + threadIdx.x;
    int lane_ = cid & 63;
    int nf = (cid >> 6) & 7;
    int ks = (cid >> 9) & 7;
    int nt = cid >> 12;
    int q = lane_ >> 4, r16 = lane_ & 15;
    int rg = nt*128 + nf*16 + r16;
    int k0 = ks*32 + q*8;
    s16x8 v;
    if (rg < NR) {
        if (k0 + 7 < NPF) {
            const float* p = pd + (size_t)rg * NPF + k0;
            #pragma unroll
            for (int k = 0; k < 8; ++k) v[k] = f2bf(p[k]);
        } else {
            #pragma unroll
            for (int k = 0; k < 8; ++k) {
                int col = k0 + k;
                float f = 0.0f;
                if (col < NPF)     f = pd[(size_t)rg * NPF + col];
                else if (col < KB) f = sd[(size_t)rg * 10 + (col - NPF)];
                v[k] = f2bf(f);
            }
        }
    } else {
        #pragma unroll
        for (int k = 0; k < 8; ++k) v[k] = 0;
    }
    *(s16x8*)&Bf[(size_t)cid * 8] = v;
}

// ============ K3: JD partials, part layout [bi][i(72)][k(224)] ============
__global__ __launch_bounds__(256) void k_jdirs(const float* __restrict__ pd,
        const float* __restrict__ sd, const float* __restrict__ vt,
        const float* __restrict__ Jreg, float* __restrict__ part) {
    __shared__ float wjs[24][VPB];
    int bi = blockIdx.x;
    int v0 = bi * VPB;
    int nv = NV - v0; if (nv > VPB) nv = VPB; if (nv < 0) nv = 0;
    for (int i = threadIdx.x; i < 24*VPB; i += 256) {
        int j = i / VPB, vv = i - j*VPB;
        wjs[j][vv] = (vv < nv) ? Jreg[(size_t)j * NV + v0 + vv] : 0.0f;
    }
    __syncthreads();
    int k = threadIdx.x;
    float acc[72];
    #pragma unroll
    for (int i = 0; i < 72; ++i) acc[i] = 0.0f;
    for (int vv = 0; vv < VPB; ++vv) {
        int v = v0 + vv;
        if (v >= NV) break;
        #pragma unroll
        for (int c = 0; c < 3; ++c) {
            int row = v*3 + c;
            float val = 0.0f;
            if (k < NPF)      val = pd[(size_t)row * NPF + k];
            else if (k < KB)  val = sd[(size_t)row * 10 + (k - NPF)];
            else if (k == KB) val = vt[row];
            #pragma unroll
            for (int j = 0; j < 24; ++j) acc[j*3 + c] += wjs[j][vv] * val;
        }
    }
    if (k < 224) {
        float* p = part + (size_t)bi * (72*224);
        #pragma unroll
        for (int i = 0; i < 72; ++i) p[i*224 + k] = acc[i];
    }
}

// ============ K4a: reduce 512 -> 8 partials, coalesced ============
__global__ __launch_bounds__(256) void k_jreduce1(const float* __restrict__ part,
        float* __restrict__ part2) {
    int i = blockIdx.x;            // 0..71
    int s = blockIdx.y;            // 0..7
    int k = threadIdx.x;
    if (k >= 224) return;
    float acc = 0.0f;
    #pragma unroll 4
    for (int bi = s*64; bi < s*64 + 64; ++bi)
        acc += part[(size_t)bi * (72*224) + i*224 + k];
    part2[((size_t)s * 72 + i) * 224 + k] = acc;
}

// ============ K4b: reduce 8 -> JDt[k][72] ============
__global__ __launch_bounds__(256) void k_jreduce2(const float* __restrict__ part2,
        float* __restrict__ JDt) {
    int e = blockIdx.x * 256 + threadIdx.x;    // e = i*224 + k
    if (e >= 72*224) return;
    int i = e / 224, k = e - i*224;
    float s = 0.0f;
    #pragma unroll
    for (int ss = 0; ss < 8; ++ss)
        s += part2[((size_t)ss * 72 + i) * 224 + k];
    if (k < 218) JDt[k*72 + i] = s;
}

// ============ K5: J[b][jc] = JDt[217][jc] + sum_k pfA[b][k]*JDt[k][jc] ============
__global__ __launch_bounds__(128) void k_J(const float* __restrict__ pfA,
        const float* __restrict__ JDt, float* __restrict__ Jout, int B) {
    int b = blockIdx.x, t = threadIdx.x;
    if (t >= 72) return;
    const float* pa = pfA + (size_t)b * 224;
    float acc = JDt[217*72 + t];
    #pragma unroll 7
    for (int k = 0; k < KB; ++k) acc += pa[k] * JDt[k*72 + t];
    Jout[(size_t)b * 72 + t] = acc;
}

// ============ K6: kinematic chain -> G_corr (B,24,12) ============
__global__ __launch_bounds__(32) void k_chain(const float* __restrict__ Rg,
        const float* __restrict__ Jg, float* __restrict__ Gc, int B) {
    __shared__ float Gs[32 * 289];
    int b = blockIdx.x * 32 + threadIdx.x;
    if (b >= B) return;
    float* G = &Gs[threadIdx.x * 289];
    float Jl[72];
    const float* Jb = Jg + (size_t)b * 72;
    #pragma unroll
    for (int i = 0; i < 72; ++i) Jl[i] = Jb[i];
    const float* Rb = Rg + (size_t)b * 216;
    G[0]=Rb[0]; G[1]=Rb[1]; G[2]=Rb[2];  G[3]=Jl[0];
    G[4]=Rb[3]; G[5]=Rb[4]; G[6]=Rb[5];  G[7]=Jl[1];
    G[8]=Rb[6]; G[9]=Rb[7]; G[10]=Rb[8]; G[11]=Jl[2];
    #pragma unroll
    for (int i = 1; i < NJ; ++i) {
        const int p = PAR[i];
        const float* Ri = Rb + i*9;
        float r00=Ri[0],r01=Ri[1],r02=Ri[2];
        float r10=Ri[3],r11=Ri[4],r12=Ri[5];
        float r20=Ri[6],r21=Ri[7],r22=Ri[8];
        float px=Jl[p*3+0], py=Jl[p*3+1], pz=Jl[p*3+2];
        float tx = Jl[i*3+0] - (r00*px + r01*py + r02*pz);
        float ty = Jl[i*3+1] - (r10*px + r11*py + r12*pz);
        float tz = Jl[i*3+2] - (r20*px + r21*py + r22*pz);
        const float* gp = &G[p*12];
        float* gi = &G[i*12];
        #pragma unroll
        for (int rr = 0; rr < 3; ++rr) {
            float a0=gp[rr*4+0], a1=gp[rr*4+1], a2=gp[rr*4+2], a3=gp[rr*4+3];
            gi[rr*4+0] = a0*r00 + a1*r10 + a2*r20;
            gi[rr*4+1] = a0*r01 + a1*r11 + a2*r21;
            gi[rr*4+2] = a0*r02 + a1*r12 + a2*r22;
            gi[rr*4+3] = a0*tx + a1*ty + a2*tz + a3;
        }
    }
    float* out = Gc + (size_t)b * 288;
    #pragma unroll
    for (int i = 0; i < NJ; ++i) {
        const float* gi = &G[i*12];
        float jx=Jl[i*3+0], jy=Jl[i*3+1], jz=Jl[i*3+2];
        #pragma unroll
        for (int rr = 0; rr < 3; ++rr) {
            out[i*12+rr*4+0] = gi[rr*4+0];
            out[i*12+rr*4+1] = gi[rr*4+1];
            out[i*12+rr*4+2] = gi[rr*4+2];
            out[i*12+rr*4+3] = gi[rr*4+3] - (gi[rr*4+0]*jx + gi[rr*4+1]*jy + gi[rr*4+2]*jz);
        }
    }
}

// ============ K6b: Gmf[b][lane][8] bf16 skin-A-fragments from G_corr ============
__global__ __launch_bounds__(256) void k_gmf(const float* __restrict__ Gc,
        short* __restrict__ Gmf, int B) {
    int idx = blockIdx.x * 256 + threadIdx.x;      // b*64 + lane
    if (idx >= B * 64) return;
    int lane_ = idx & 63, b = idx >> 6;
    int q = lane_ >> 4, c = lane_ & 15;
    s16x8 v;
    if (c < 12 && q < 3) {
        #pragma unroll
        for (int e = 0; e < 8; ++e)
            v[e] = f2bf(Gc[(size_t)b * 288 + (q*8 + e)*12 + c]);
    } else {
        #pragma unroll
        for (int e = 0; e < 8; ++e) v[e] = 0;
    }
    *(s16x8*)&Gmf[(size_t)idx * 8] = v;
}

// ============ K7: 128-col streaming GEMM, f32 out (fallback) ============
__global__ __launch_bounds__(256, 2) void k_gemm(const short* __restrict__ Af,
        const short* __restrict__ Bf, const float* __restrict__ vt,
        float* __restrict__ vout, int B) {
    __shared__ float eld[64 * 128];
    const int t = threadIdx.x;
    const int wgid = blockIdx.x;
    const int bt = wgid & 7, nt = wgid >> 3;
    const int wave = t >> 6, lane = t & 63;
    const int wn = (wave & 1) * 64;
    const int q = lane >> 4, r16 = lane & 15;
    const int mfb = (wave >> 1) * 4, nfb = (wave & 1) * 4;

    const s16x8* Ab = (const s16x8*)(Af + (size_t)bt * FTILE);
    const s16x8* Bb = (const s16x8*)(Bf + (size_t)nt * FTILE);

    f32x4 acc[4][4];
    #pragma unroll
    for (int m = 0; m < 4; ++m)
        #pragma unroll
        for (int n = 0; n < 4; ++n)
            #pragma unroll
            for (int i = 0; i < 4; ++i) acc[m][n][i] = 0.0f;

    #pragma unroll
    for (int ks = 0; ks < 8; ++ks) {
        s16x8 a[4], b[4];
        #pragma unroll
        for (int m = 0; m < 4; ++m) a[m] = Ab[(ks*8 + mfb + m)*64 + lane];
        #pragma unroll
        for (int n = 0; n < 4; ++n) b[n] = Bb[(ks*8 + nfb + n)*64 + lane];
        #pragma unroll
        for (int m = 0; m < 4; ++m)
            #pragma unroll
            for (int n = 0; n < 4; ++n)
                acc[m][n] = __builtin_amdgcn_mfma_f32_16x16x32_bf16(a[m], b[n], acc[m][n], 0, 0, 0);
    }

    #pragma unroll
    for (int half = 0; half < 2; ++half) {
        if ((wave >> 1) == half) {
            #pragma unroll
            for (int m = 0; m < 4; ++m)
                #pragma unroll
                for (int n = 0; n < 4; ++n)
                    #pragma unroll
                    for (int i = 0; i < 4; ++i) {
                        int row_l = m*16 + q*4 + i;
                        int col = wn + n*16 + r16;
                        eld[row_l * 128 + (col ^ ((row_l & 7) << 2))] = acc[m][n][i];
                    }
        }
        __syncthreads();
        {
            const int c32 = t & 31;
            const int col = c32 * 4;
            const int rsub = (t >> 5) & 1;
            #pragma unroll
            for (int it = 0; it < 8; ++it) {
                int row_l = it * 8 + wave * 2 + rsub;
                int bg = bt * 128 + half * 64 + row_l;
                int rg = nt * 128 + col;
                f32x4 v = *(const f32x4*)&eld[row_l * 128 + (col ^ ((row_l & 7) << 2))];
                if (bg < B) {
                    float* dst = vout + (size_t)bg * NR + rg;
                    if (rg + 3 < NR) {
                        float4 tv = *(const float4*)(vt + rg);
                        v[0] += tv.x; v[1] += tv.y; v[2] += tv.z; v[3] += tv.w;
                        *(f4u*)dst = v;
                    } else {
                        #pragma unroll
                        for (int e = 0; e < 4; ++e)
                            if (rg + e < NR) dst[e] = v[e] + vt[rg + e];
                    }
                }
            }
        }
        __syncthreads();
    }
}

// ============ K7b: 192-col streaming GEMM -> padded bf16 vpbf, slim bf16-LDS epilogue ============
__global__ __launch_bounds__(256, 2) void k_gemm_bf(const short* __restrict__ Af,
        const short* __restrict__ Bf, const float* __restrict__ vt,
        short* __restrict__ vpbf, int B) {
    __shared__ short elds[64 * ELDW];              // 33.8 KB, vertex-padded bf16
    const int t = threadIdx.x;
    const int wgid = blockIdx.x;
    const int bt = wgid & 7, nt = wgid >> 3;       // nt 0..107
    const int wave = t >> 6, lane = t & 63;
    const int wn = (wave & 1) * 96;
    const int q = lane >> 4, r16 = lane & 15;
    const int mfb = (wave >> 1) * 4, nfb = (wave & 1) * 6;

    const s16x8* Ab = (const s16x8*)(Af + (size_t)bt * FTILE);
    const s16x8* Bb = (const s16x8*)(Bf + (size_t)nt * FT2);

    f32x4 acc[4][6];
    #pragma unroll
    for (int m = 0; m < 4; ++m)
        #pragma unroll
        for (int n = 0; n < 6; ++n)
            #pragma unroll
            for (int i = 0; i < 4; ++i) acc[m][n][i] = 0.0f;

    #pragma unroll
    for (int ks = 0; ks < 8; ++ks) {
        s16x8 a[4], b[6];
        #pragma unroll
        for (int m = 0; m < 4; ++m) a[m] = Ab[(ks*8 + mfb + m)*64 + lane];
        #pragma unroll
        for (int n = 0; n < 6; ++n) b[n] = Bb[(ks*12 + nfb + n)*64 + lane];
        #pragma unroll
        for (int m = 0; m < 4; ++m)
            #pragma unroll
            for (int n = 0; n < 6; ++n)
                acc[m][n] = __builtin_amdgcn_mfma_f32_16x16x32_bf16(a[m], b[n], acc[m][n], 0, 0, 0);
    }

    // per-n: vt value and destination short-offset within a row (vert*4 + comp)
    float vtv[6];
    int sofs[6];
    #pragma unroll
    for (int n = 0; n < 6; ++n) {
        int col = wn + n*16 + r16;
        int rg = nt*192 + col;
        vtv[n] = (rg < NR) ? vt[rg] : 0.0f;
        int vert = col / 3;
        sofs[n] = vert*4 + (col - vert*3);
    }

    #pragma unroll
    for (int half = 0; half < 2; ++half) {
        // (a) owning wave-pair converts + writes bf16 into vertex-padded rows
        if ((wave >> 1) == half) {
            #pragma unroll
            for (int m = 0; m < 4; ++m)
                #pragma unroll
                for (int i = 0; i < 4; ++i) {
                    int row_l = m*16 + q*4 + i;              // 0..63
                    #pragma unroll
                    for (int n = 0; n < 6; ++n)
                        elds[row_l * ELDW + sofs[n]] = f2bf(acc[m][n][i] + vtv[n]);
                }
        }
        __syncthreads();
        // (b) all waves: 8 x (b128 LDS read = 2 verts -> 16B store, 512B/instr contiguous)
        {
            const int rsub = t >> 5;               // 0..7
            const int v2 = (t & 31) * 2;           // vertex pair base
            #pragma unroll
            for (int it = 0; it < 8; ++it) {
                int row_l = it * 8 + rsub;         // 0..63
                int bg = bt * 128 + half * 64 + row_l;
                s16x8 v = *(const s16x8*)&elds[row_l * ELDW + v2 * 4];
                *(s16x8*)&vpbf[(size_t)bg * (NVP*4) + (size_t)(nt*64 + v2) * 4] = v;
            }
        }
        __syncthreads();
    }
}

// ============ K8: MFMA skinning, f32 in-place (fallback) ============
__global__ __launch_bounds__(256) void k_skin(float* __restrict__ vio,
        const float* __restrict__ W, const float* __restrict__ Gc, int B) {
    __shared__ short Gm[16 * 40];
    const int t = threadIdx.x;
    const int wave = t >> 6, lane = t & 63;
    const int q = lane >> 4, c = lane & 15;
    const int vb = blockIdx.x * 256 + wave * 64;
    const int b0 = blockIdx.y * 16;

    if (t < 320) ((int*)Gm)[t] = 0;

    s16x8 wf[4];
    #pragma unroll
    for (int m = 0; m < 4; ++m) {
        int vert = vb + m*16 + c;
        if (q < 3 && vert < NV) {
            const float* wp = W + (size_t)vert * NJ + q*8;
            float4 f0 = *(const float4*)(wp);
            float4 f1 = *(const float4*)(wp + 4);
            wf[m][0]=f2bf(f0.x); wf[m][1]=f2bf(f0.y); wf[m][2]=f2bf(f0.z); wf[m][3]=f2bf(f0.w);
            wf[m][4]=f2bf(f1.x); wf[m][5]=f2bf(f1.y); wf[m][6]=f2bf(f1.z); wf[m][7]=f2bf(f1.w);
        } else {
            #pragma unroll
            for (int e = 0; e < 8; ++e) wf[m][e] = 0;
        }
    }
    __syncthreads();

    for (int bb = 0; bb < 16; ++bb) {
        int b = b0 + bb;
        if (b >= B) break;
        {
            int i0 = t;
            int j0 = i0 / 12, c0 = i0 - j0*12;
            if (i0 < 288) Gm[c0*40 + j0] = f2bf(Gc[(size_t)b*288 + i0]);
            int i1 = t + 256;
            if (i1 < 288) {
                int j1 = i1 / 12, c1 = i1 - j1*12;
                Gm[c1*40 + j1] = f2bf(Gc[(size_t)b*288 + i1]);
            }
        }
        __syncthreads();

        s16x8 af = *(const s16x8*)&Gm[c*40 + q*8];
        #pragma unroll
        for (int m = 0; m < 4; ++m) {
            f32x4 zz = {0.0f, 0.0f, 0.0f, 0.0f};
            f32x4 acc = __builtin_amdgcn_mfma_f32_16x16x32_bf16(af, wf[m], zz, 0, 0, 0);
            int vert = vb + m*16 + c;
            bool ok = (q < 3) && (vert < NV);
            if (ok) {
                float* vp = vio + (size_t)b * NR + (size_t)vert * 3;
                float x = vp[0], y = vp[1], z = vp[2];
                float o = acc[0]*x + acc[1]*y + acc[2]*z + acc[3];
                vp[q] = o;
            }
        }
        __syncthreads();
    }
}

// ============ K8b: pipelined barrier-free skinning, padded bf16 in (dwordx2/vert) ============
__global__ __launch_bounds__(256) void k_skin_bf(const short* __restrict__ vpbf,
        float* __restrict__ vout, const float* __restrict__ W,
        const short* __restrict__ Gmf, int B) {
    const int t = threadIdx.x;
    const int wave = t >> 6, lane = t & 63;
    const int q = lane >> 4, c = lane & 15;
    const int vb = blockIdx.x * 256 + wave * 64;
    const int b0 = blockIdx.y * NB;

    s16x8 wf[4];
    int vert[4];
    bool vok[4];
    #pragma unroll
    for (int m = 0; m < 4; ++m) {
        vert[m] = vb + m*16 + c;
        vok[m] = (q < 3) && (vert[m] < NV);
        if (vok[m]) {
            const float* wp = W + (size_t)vert[m] * NJ + q*8;
            float4 f0 = *(const float4*)(wp);
            float4 f1 = *(const float4*)(wp + 4);
            wf[m][0]=f2bf(f0.x); wf[m][1]=f2bf(f0.y); wf[m][2]=f2bf(f0.z); wf[m][3]=f2bf(f0.w);
            wf[m][4]=f2bf(f1.x); wf[m][5]=f2bf(f1.y); wf[m][6]=f2bf(f1.z); wf[m][7]=f2bf(f1.w);
        } else {
            #pragma unroll
            for (int e = 0; e < 8; ++e) wf[m][e] = 0;
        }
    }

#define LOADTO(bx, af_, v_)                                                        \
    {                                                                              \
        af_ = *(const s16x8*)&Gmf[((size_t)(bx) * 64 + lane) * 8];                 \
        const short* vbase_ = vpbf + (size_t)(bx) * (NVP*4);                       \
        _Pragma("unroll")                                                          \
        for (int m = 0; m < 4; ++m)                                                \
            v_[m] = *(const u32x2*)&vbase_[vert[m] * 4];                           \
    }

#define COMPUTE(bx, af_, v_)                                                       \
    {                                                                              \
        _Pragma("unroll")                                                          \
        for (int m = 0; m < 4; ++m) {                                              \
            f32x4 zz = {0.0f, 0.0f, 0.0f, 0.0f};                                   \
            f32x4 acc = __builtin_amdgcn_mfma_f32_16x16x32_bf16(af_, wf[m], zz, 0, 0, 0); \
            if (vok[m]) {                                                          \
                float x = bf2f(v_[m][0] & 0xffffu);                                \
                float y = bf2f(v_[m][0] >> 16);                                    \
                float z = bf2f(v_[m][1] & 0xffffu);                                \
                float o = acc[0]*x + acc[1]*y + acc[2]*z + acc[3];                 \
                vout[(size_t)(bx) * NR + (size_t)vert[m] * 3 + q] = o;             \
            }                                                                      \
        }                                                                          \
    }

    s16x8 afA, afB;
    u32x2 vA[4], vB[4];

    LOADTO(b0, afA, vA);
    #pragma unroll
    for (int bb = 0; bb < NB; bb += 2) {
        if (bb + 1 < NB) LOADTO(b0 + bb + 1, afB, vB);
        COMPUTE(b0 + bb, afA, vA);
        if (bb + 2 < NB) LOADTO(b0 + bb + 2, afA, vA);
        if (bb + 1 < NB) COMPUTE(b0 + bb + 1, afB, vB);
    }
#undef LOADTO
#undef COMPUTE
}

extern "C" void kernel_launch(void* const* d_in, const int* in_sizes, int n_in,
                              void* d_out, int out_size, void* d_ws, size_t ws_size,
                              hipStream_t stream) {
    const float* theta = (const float*)d_in[0];
    const float* beta  = (const float*)d_in[1];
    const float* sd    = (const float*)d_in[2];
    const float* pd    = (const float*)d_in[3];
    const float* Jreg  = (const float*)d_in[4];
    const float* vt    = (const float*)d_in[5];
    const float* W     = (const float*)d_in[6];
    float* out = (float*)d_out;

    const int B = in_sizes[0] / 72;

    float* vregion = out;
    float* Jout    = out + (size_t)B * NR;

    float* Rws   = (float*)d_ws;                          // B*216 f32
    float* Gcws  = Rws + (size_t)B * 216;                 // B*288 f32
    float* pfA   = Gcws + (size_t)B * 288;                // B*224 f32
    short* Afrag = (short*)(pfA + (size_t)B * 224);       // (B/128)*FTILE bf16
    short* Bfrag = Afrag + (size_t)(B/128) * FTILE;       // NT2*FT2 shorts (10.6 MB)
    short* vpbf  = Bfrag + (size_t)NT2 * FT2;             // B*NVP*4 bf16 (56.6 MB, optional)
    short* Gmf   = vpbf + (size_t)B * NVP * 4;            // B*512 bf16 (1 MB, optional)

    size_t base_bytes = (size_t)B * 2912 + (size_t)(B/128) * FTILE * 2 + (size_t)NT2 * FT2 * 2;
    size_t need_bf    = base_bytes + (size_t)B * NVP * 4 * 2 + (size_t)B * 512 * 2;
    const bool use_bf = (ws_size >= need_bf) && ((B & 127) == 0);

    float* part  = vregion;                               // d_out scratch pre-GEMM
    float* part2 = vregion + (size_t)NSPLIT * 72 * 224;
    float* JDt   = part2 + (size_t)8 * 72 * 224;

    k_rodrigues<<<(B*NJ + 255)/256, 256, 0, stream>>>(theta, beta, Rws, pfA, Afrag, B);
    if (use_bf) {
        dim3 grid(24, NT2);
        k_convB192<<<grid, 256, 0, stream>>>(pd, sd, Bfrag);
    } else {
        k_convB128<<<(NT*8*8*64)/256, 256, 0, stream>>>(pd, sd, Bfrag);
    }
    k_jdirs<<<NSPLIT, 256, 0, stream>>>(pd, sd, vt, Jreg, part);
    {
        dim3 grid(72, 8);
        k_jreduce1<<<grid, 256, 0, stream>>>(part, part2);
    }
    k_jreduce2<<<(72*224 + 255)/256, 256, 0, stream>>>(part2, JDt);
    k_J<<<B, 128, 0, stream>>>(pfA, JDt, Jout, B);
    k_chain<<<(B + 31)/32, 32, 0, stream>>>(Rws, Jout, Gcws, B);

    if (use_bf) {
        k_gmf<<<(B*64 + 255)/256, 256, 0, stream>>>(Gcws, Gmf, B);
        k_gemm_bf<<<NT2 * (B/128), 256, 0, stream>>>(Afrag, Bfrag, vt, vpbf, B);
        dim3 grid((NV + 255)/256, (B + NB - 1)/NB);
        k_skin_bf<<<grid, 256, 0, stream>>>(vpbf, vregion, W, Gmf, B);
    } else {
        k_gemm<<<NT * (B/128), 256, 0, stream>>>(Afrag, Bfrag, vt, vregion, B);
        dim3 grid((NV + 255)/256, (B + 15)/16);
        k_skin<<<grid, 256, 0, stream>>>(vregion, W, Gcws, B);
    }
}

// Round 19
// 126.425 us; speedup vs baseline: 1.5232x; 1.0818x over previous
//
#include <hip/hip_runtime.h>
#include <hip/hip_bf16.h>

#define NJ 24
#define NV 6890
#define NVP 6912
#define NR (NV*3)        // 20670 output rows per batch
#define NPF 207
#define KB 217           // 207 pf + 10 beta
#define KP 256           // padded K (8 x 32)
#define NT 162           // 128-col tiles (fallback path)
#define NT2 108          // 192-col tiles (64 whole verts each)
#define NSPLIT 512       // jdirs v-splits
#define VPB 14           // ceil(6890/512)
#define FTILE 32768      // A-tile shorts: 8 ks * 8 frag * 64 lane * 8
#define FT2   49152      // B-tile shorts (192-col)
#define ELDW 264         // elds row stride in shorts (64 verts*4 + 8 pad)

typedef short s16x8 __attribute__((ext_vector_type(8)));
typedef short s16x4 __attribute__((ext_vector_type(4)));
typedef float f32x4 __attribute__((ext_vector_type(4)));
typedef float f4u   __attribute__((ext_vector_type(4), aligned(4)));

__device__ constexpr int PAR[24] = {-1,0,0,0,1,2,3,4,5,6,7,8,9,9,9,12,13,14,16,17,18,19,20,21};

__device__ __forceinline__ short f2bf(float f) {
    __hip_bfloat16 h = __float2bfloat16(f);
    return *reinterpret_cast<short*>(&h);
}
__device__ __forceinline__ float bf2fs(unsigned short u) {
    unsigned int x = ((unsigned int)u) << 16;
    return __uint_as_float(x);
}

// A-fragment address for (row_in_tile, k)
__device__ __forceinline__ size_t frag_addr(int row128, int k) {
    int ks = k >> 5, q = (k >> 3) & 3, e = k & 7;
    int mf = row128 >> 4, r16 = row128 & 15;
    return ((size_t)(ks*8 + mf) * 64 + q*16 + r16) * 8 + e;
}

// ============ K1: Rodrigues -> Rws(f32), pfA(f32), Afrag(bf16 fragment layout) ============
__global__ __launch_bounds__(256) void k_rodrigues(const float* __restrict__ theta,
        const float* __restrict__ beta, float* __restrict__ Rws,
        float* __restrict__ pfA, short* __restrict__ Afrag, int B) {
    int idx = blockIdx.x * blockDim.x + threadIdx.x;   // b*24 + j
    if (idx >= B * NJ) return;
    int b = idx / NJ, j = idx % NJ;
    float x = theta[b*72 + j*3 + 0];
    float y = theta[b*72 + j*3 + 1];
    float z = theta[b*72 + j*3 + 2];
    float n = sqrtf(x*x + y*y + z*z);
    float a = fmaxf(n, 1e-8f);
    float inv = 1.0f / a;
    float ix = x*inv, iy = y*inv, iz = z*inv;
    float c = cosf(a), s = sinf(a), t = 1.0f - c;
    float r[9];
    r[0] = t*ix*ix + c;     r[1] = t*ix*iy - s*iz;  r[2] = t*ix*iz + s*iy;
    r[3] = t*ix*iy + s*iz;  r[4] = t*iy*iy + c;     r[5] = t*iy*iz - s*ix;
    r[6] = t*ix*iz - s*iy;  r[7] = t*iy*iz + s*ix;  r[8] = t*iz*iz + c;
    float* Rp = Rws + (size_t)idx * 9;
    #pragma unroll
    for (int k = 0; k < 9; ++k) Rp[k] = r[k];

    int rb = b & 127;
    short* At = Afrag + (size_t)(b >> 7) * FTILE;
    float* pa = pfA + (size_t)b * 224;
    if (j >= 1) {
        #pragma unroll
        for (int kk = 0; kk < 9; ++kk) {
            int k = (j-1)*9 + kk;
            float f = r[kk] - ((kk == 0 || kk == 4 || kk == 8) ? 1.0f : 0.0f);
            At[frag_addr(rb, k)] = f2bf(f);
            pa[k] = f;
        }
    } else {
        #pragma unroll
        for (int kk = 0; kk < 10; ++kk) {
            int k = NPF + kk;
            float f = beta[b*10 + kk];
            At[frag_addr(rb, k)] = f2bf(f);
            pa[k] = f;
        }
        for (int k = KB; k < KP; ++k)
            At[frag_addr(rb, k)] = 0;
    }
}

// ============ K2a: Bfrag for 192-col tiles ============
__global__ __launch_bounds__(256) void k_convB192(const float* __restrict__ pd,
        const float* __restrict__ sd, short* __restrict__ Bf) {
    int nt = blockIdx.y;
    int id = blockIdx.x * 256 + threadIdx.x;       // (ks*12 + nf)*64 + lane
    int lane_ = id & 63;
    int fi = id >> 6;
    int nf = fi % 12, ks = fi / 12;
    int q = lane_ >> 4, r16 = lane_ & 15;
    int rg = nt*192 + nf*16 + r16;
    int k0 = ks*32 + q*8;
    s16x8 v;
    if (rg < NR) {
        if (k0 + 7 < NPF) {
            const float* p = pd + (size_t)rg * NPF + k0;
            #pragma unroll
            for (int k = 0; k < 8; ++k) v[k] = f2bf(p[k]);
        } else {
            #pragma unroll
            for (int k = 0; k < 8; ++k) {
                int col = k0 + k;
                float f = 0.0f;
                if (col < NPF)     f = pd[(size_t)rg * NPF + col];
                else if (col < KB) f = sd[(size_t)rg * 10 + (col - NPF)];
                v[k] = f2bf(f);
            }
        }
    } else {
        #pragma unroll
        for (int k = 0; k < 8; ++k) v[k] = 0;
    }
    *(s16x8*)&Bf[((size_t)nt * FT2) + (size_t)id * 8] = v;
}

// ============ K2b: Bfrag for 128-col tiles (fallback) ============
__global__ __launch_bounds__(256) void k_convB128(const float* __restrict__ pd,
        const float* __restrict__ sd, short* __restrict__ Bf) {
    int cid = blockIdx.x * 256 + threadIdx.x;
    int lane_ = cid & 63;
    int nf = (cid >> 6) & 7;
    int ks = (cid >> 9) & 7;
    int nt = cid >> 12;
    int q = lane_ >> 4, r16 = lane_ & 15;
    int rg = nt*128 + nf*16 + r16;
    int k0 = ks*32 + q*8;
    s16x8 v;
    if (rg < NR) {
        if (k0 + 7 < NPF) {
            const float* p = pd + (size_t)rg * NPF + k0;
            #pragma unroll
            for (int k = 0; k < 8; ++k) v[k] = f2bf(p[k]);
        } else {
            #pragma unroll
            for (int k = 0; k < 8; ++k) {
                int col = k0 + k;
                float f = 0.0f;
                if (col < NPF)     f = pd[(size_t)rg * NPF + col];
                else if (col < KB) f = sd[(size_t)rg * 10 + (col - NPF)];
                v[k] = f2bf(f);
            }
        }
    } else {
        #pragma unroll
        for (int k = 0; k < 8; ++k) v[k] = 0;
    }
    *(s16x8*)&Bf[(size_t)cid * 8] = v;
}

// ============ K3: JD partials ============
__global__ __launch_bounds__(256) void k_jdirs(const float* __restrict__ pd,
        const float* __restrict__ sd, const float* __restrict__ vt,
        const float* __restrict__ Jreg, float* __restrict__ part) {
    __shared__ float wjs[24][VPB];
    int bi = blockIdx.x;
    int v0 = bi * VPB;
    int nv = NV - v0; if (nv > VPB) nv = VPB; if (nv < 0) nv = 0;
    for (int i = threadIdx.x; i < 24*VPB; i += 256) {
        int j = i / VPB, vv = i - j*VPB;
        wjs[j][vv] = (vv < nv) ? Jreg[(size_t)j * NV + v0 + vv] : 0.0f;
    }
    __syncthreads();
    int k = threadIdx.x;
    float acc[72];
    #pragma unroll
    for (int i = 0; i < 72; ++i) acc[i] = 0.0f;
    for (int vv = 0; vv < VPB; ++vv) {
        int v = v0 + vv;
        if (v >= NV) break;
        #pragma unroll
        for (int c = 0; c < 3; ++c) {
            int row = v*3 + c;
            float val = 0.0f;
            if (k < NPF)      val = pd[(size_t)row * NPF + k];
            else if (k < KB)  val = sd[(size_t)row * 10 + (k - NPF)];
            else if (k == KB) val = vt[row];
            #pragma unroll
            for (int j = 0; j < 24; ++j) acc[j*3 + c] += wjs[j][vv] * val;
        }
    }
    if (k < 224) {
        float* p = part + (size_t)bi * (72*224);
        #pragma unroll
        for (int i = 0; i < 72; ++i) p[i*224 + k] = acc[i];
    }
}

// ============ K4a: reduce 512 -> 8 partials ============
__global__ __launch_bounds__(256) void k_jreduce1(const float* __restrict__ part,
        float* __restrict__ part2) {
    int i = blockIdx.x;
    int s = blockIdx.y;
    int k = threadIdx.x;
    if (k >= 224) return;
    float acc = 0.0f;
    #pragma unroll 4
    for (int bi = s*64; bi < s*64 + 64; ++bi)
        acc += part[(size_t)bi * (72*224) + i*224 + k];
    part2[((size_t)s * 72 + i) * 224 + k] = acc;
}

// ============ K4b: reduce 8 -> JDt[k][72] ============
__global__ __launch_bounds__(256) void k_jreduce2(const float* __restrict__ part2,
        float* __restrict__ JDt) {
    int e = blockIdx.x * 256 + threadIdx.x;
    if (e >= 72*224) return;
    int i = e / 224, k = e - i*224;
    float s = 0.0f;
    #pragma unroll
    for (int ss = 0; ss < 8; ++ss)
        s += part2[((size_t)ss * 72 + i) * 224 + k];
    if (k < 218) JDt[k*72 + i] = s;
}

// ============ K5: J ============
__global__ __launch_bounds__(128) void k_J(const float* __restrict__ pfA,
        const float* __restrict__ JDt, float* __restrict__ Jout, int B) {
    int b = blockIdx.x, t = threadIdx.x;
    if (t >= 72) return;
    const float* pa = pfA + (size_t)b * 224;
    float acc = JDt[217*72 + t];
    #pragma unroll 7
    for (int k = 0; k < KB; ++k) acc += pa[k] * JDt[k*72 + t];
    Jout[(size_t)b * 72 + t] = acc;
}

// ============ K6: kinematic chain -> G_corr ============
__global__ __launch_bounds__(32) void k_chain(const float* __restrict__ Rg,
        const float* __restrict__ Jg, float* __restrict__ Gc, int B) {
    __shared__ float Gs[32 * 289];
    int b = blockIdx.x * 32 + threadIdx.x;
    if (b >= B) return;
    float* G = &Gs[threadIdx.x * 289];
    float Jl[72];
    const float* Jb = Jg + (size_t)b * 72;
    #pragma unroll
    for (int i = 0; i < 72; ++i) Jl[i] = Jb[i];
    const float* Rb = Rg + (size_t)b * 216;
    G[0]=Rb[0]; G[1]=Rb[1]; G[2]=Rb[2];  G[3]=Jl[0];
    G[4]=Rb[3]; G[5]=Rb[4]; G[6]=Rb[5];  G[7]=Jl[1];
    G[8]=Rb[6]; G[9]=Rb[7]; G[10]=Rb[8]; G[11]=Jl[2];
    #pragma unroll
    for (int i = 1; i < NJ; ++i) {
        const int p = PAR[i];
        const float* Ri = Rb + i*9;
        float r00=Ri[0],r01=Ri[1],r02=Ri[2];
        float r10=Ri[3],r11=Ri[4],r12=Ri[5];
        float r20=Ri[6],r21=Ri[7],r22=Ri[8];
        float px=Jl[p*3+0], py=Jl[p*3+1], pz=Jl[p*3+2];
        float tx = Jl[i*3+0] - (r00*px + r01*py + r02*pz);
        float ty = Jl[i*3+1] - (r10*px + r11*py + r12*pz);
        float tz = Jl[i*3+2] - (r20*px + r21*py + r22*pz);
        const float* gp = &G[p*12];
        float* gi = &G[i*12];
        #pragma unroll
        for (int rr = 0; rr < 3; ++rr) {
            float a0=gp[rr*4+0], a1=gp[rr*4+1], a2=gp[rr*4+2], a3=gp[rr*4+3];
            gi[rr*4+0] = a0*r00 + a1*r10 + a2*r20;
            gi[rr*4+1] = a0*r01 + a1*r11 + a2*r21;
            gi[rr*4+2] = a0*r02 + a1*r12 + a2*r22;
            gi[rr*4+3] = a0*tx + a1*ty + a2*tz + a3;
        }
    }
    float* out = Gc + (size_t)b * 288;
    #pragma unroll
    for (int i = 0; i < NJ; ++i) {
        const float* gi = &G[i*12];
        float jx=Jl[i*3+0], jy=Jl[i*3+1], jz=Jl[i*3+2];
        #pragma unroll
        for (int rr = 0; rr < 3; ++rr) {
            out[i*12+rr*4+0] = gi[rr*4+0];
            out[i*12+rr*4+1] = gi[rr*4+1];
            out[i*12+rr*4+2] = gi[rr*4+2];
            out[i*12+rr*4+3] = gi[rr*4+3] - (gi[rr*4+0]*jx + gi[rr*4+1]*jy + gi[rr*4+2]*jz);
        }
    }
}

// ============ K6b: Gmf[b][lane][8] bf16 skin-A-fragments ============
__global__ __launch_bounds__(256) void k_gmf(const float* __restrict__ Gc,
        short* __restrict__ Gmf, int B) {
    int idx = blockIdx.x * 256 + threadIdx.x;
    if (idx >= B * 64) return;
    int lane_ = idx & 63, b = idx >> 6;
    int q = lane_ >> 4, c = lane_ & 15;
    s16x8 v;
    if (c < 12 && q < 3) {
        #pragma unroll
        for (int e = 0; e < 8; ++e)
            v[e] = f2bf(Gc[(size_t)b * 288 + (q*8 + e)*12 + c]);
    } else {
        #pragma unroll
        for (int e = 0; e < 8; ++e) v[e] = 0;
    }
    *(s16x8*)&Gmf[(size_t)idx * 8] = v;
}

// ============ K7: 128-col streaming GEMM, f32 out (fallback) ============
__global__ __launch_bounds__(256, 2) void k_gemm(const short* __restrict__ Af,
        const short* __restrict__ Bf, const float* __restrict__ vt,
        float* __restrict__ vout, int B) {
    __shared__ float eld[64 * 128];
    const int t = threadIdx.x;
    const int wgid = blockIdx.x;
    const int bt = wgid & 7, nt = wgid >> 3;
    const int wave = t >> 6, lane = t & 63;
    const int wn = (wave & 1) * 64;
    const int q = lane >> 4, r16 = lane & 15;
    const int mfb = (wave >> 1) * 4, nfb = (wave & 1) * 4;

    const s16x8* Ab = (const s16x8*)(Af + (size_t)bt * FTILE);
    const s16x8* Bb = (const s16x8*)(Bf + (size_t)nt * FTILE);

    f32x4 acc[4][4];
    #pragma unroll
    for (int m = 0; m < 4; ++m)
        #pragma unroll
        for (int n = 0; n < 4; ++n)
            #pragma unroll
            for (int i = 0; i < 4; ++i) acc[m][n][i] = 0.0f;

    #pragma unroll
    for (int ks = 0; ks < 8; ++ks) {
        s16x8 a[4], b[4];
        #pragma unroll
        for (int m = 0; m < 4; ++m) a[m] = Ab[(ks*8 + mfb + m)*64 + lane];
        #pragma unroll
        for (int n = 0; n < 4; ++n) b[n] = Bb[(ks*8 + nfb + n)*64 + lane];
        #pragma unroll
        for (int m = 0; m < 4; ++m)
            #pragma unroll
            for (int n = 0; n < 4; ++n)
                acc[m][n] = __builtin_amdgcn_mfma_f32_16x16x32_bf16(a[m], b[n], acc[m][n], 0, 0, 0);
    }

    #pragma unroll
    for (int half = 0; half < 2; ++half) {
        if ((wave >> 1) == half) {
            #pragma unroll
            for (int m = 0; m < 4; ++m)
                #pragma unroll
                for (int n = 0; n < 4; ++n)
                    #pragma unroll
                    for (int i = 0; i < 4; ++i) {
                        int row_l = m*16 + q*4 + i;
                        int col = wn + n*16 + r16;
                        eld[row_l * 128 + (col ^ ((row_l & 7) << 2))] = acc[m][n][i];
                    }
        }
        __syncthreads();
        {
            const int c32 = t & 31;
            const int col = c32 * 4;
            const int rsub = (t >> 5) & 1;
            #pragma unroll
            for (int it = 0; it < 8; ++it) {
                int row_l = it * 8 + wave * 2 + rsub;
                int bg = bt * 128 + half * 64 + row_l;
                int rg = nt * 128 + col;
                f32x4 v = *(const f32x4*)&eld[row_l * 128 + (col ^ ((row_l & 7) << 2))];
                if (bg < B) {
                    float* dst = vout + (size_t)bg * NR + rg;
                    if (rg + 3 < NR) {
                        float4 tv = *(const float4*)(vt + rg);
                        v[0] += tv.x; v[1] += tv.y; v[2] += tv.z; v[3] += tv.w;
                        *(f4u*)dst = v;
                    } else {
                        #pragma unroll
                        for (int e = 0; e < 4; ++e)
                            if (rg + e < NR) dst[e] = v[e] + vt[rg + e];
                    }
                }
            }
        }
        __syncthreads();
    }
}

// ============ K7b: FUSED 192-col GEMM + MFMA skinning (no vpbf) ============
__global__ __launch_bounds__(256, 2) void k_gemm_skin(const short* __restrict__ Af,
        const short* __restrict__ Bf, const float* __restrict__ vt,
        const short* __restrict__ Gmf, const float* __restrict__ W,
        float* __restrict__ vout, int B) {
    __shared__ short elds[64 * ELDW];              // 33.8 KB bf16 v_posed (one half)
    const int t = threadIdx.x;
    const int wgid = blockIdx.x;
    const int bt = wgid & 7, nt = wgid >> 3;       // nt 0..107
    const int wave = t >> 6, lane = t & 63;
    const int wn = (wave & 1) * 96;
    const int q = lane >> 4, r16 = lane & 15;
    const int mfb = (wave >> 1) * 4, nfb = (wave & 1) * 6;

    const s16x8* Ab = (const s16x8*)(Af + (size_t)bt * FTILE);
    const s16x8* Bb = (const s16x8*)(Bf + (size_t)nt * FT2);

    f32x4 acc[4][6];
    #pragma unroll
    for (int m = 0; m < 4; ++m)
        #pragma unroll
        for (int n = 0; n < 6; ++n)
            #pragma unroll
            for (int i = 0; i < 4; ++i) acc[m][n][i] = 0.0f;

    #pragma unroll
    for (int ks = 0; ks < 8; ++ks) {
        s16x8 a[4], b[6];
        #pragma unroll
        for (int m = 0; m < 4; ++m) a[m] = Ab[(ks*8 + mfb + m)*64 + lane];
        #pragma unroll
        for (int n = 0; n < 6; ++n) b[n] = Bb[(ks*12 + nfb + n)*64 + lane];
        #pragma unroll
        for (int m = 0; m < 4; ++m)
            #pragma unroll
            for (int n = 0; n < 6; ++n)
                acc[m][n] = __builtin_amdgcn_mfma_f32_16x16x32_bf16(a[m], b[n], acc[m][n], 0, 0, 0);
    }

    // per-n vt value + LDS short-offset (vert*4 + comp)
    float vtv[6];
    int sofs[6];
    #pragma unroll
    for (int n = 0; n < 6; ++n) {
        int col = wn + n*16 + r16;
        int rg = nt*192 + col;
        vtv[n] = (rg < NR) ? vt[rg] : 0.0f;
        int vert = col / 3;
        sofs[n] = vert*4 + (col - vert*3);
    }

    // W fragments for this tile's 64 verts (built once, reused both halves)
    s16x8 wf[4];
    int vert[4];
    bool vok[4];
    const int c16 = lane & 15;
    #pragma unroll
    for (int m = 0; m < 4; ++m) {
        vert[m] = nt*64 + m*16 + c16;
        vok[m] = (q < 3) && (vert[m] < NV);
        if (vok[m]) {
            const float* wp = W + (size_t)vert[m] * NJ + q*8;
            float4 f0 = *(const float4*)(wp);
            float4 f1 = *(const float4*)(wp + 4);
            wf[m][0]=f2bf(f0.x); wf[m][1]=f2bf(f0.y); wf[m][2]=f2bf(f0.z); wf[m][3]=f2bf(f0.w);
            wf[m][4]=f2bf(f1.x); wf[m][5]=f2bf(f1.y); wf[m][6]=f2bf(f1.z); wf[m][7]=f2bf(f1.w);
        } else {
            #pragma unroll
            for (int e = 0; e < 8; ++e) wf[m][e] = 0;
        }
    }

    #pragma unroll
    for (int half = 0; half < 2; ++half) {
        // (a) owning wave-pair converts + writes bf16 v_posed into vertex-padded rows
        if ((wave >> 1) == half) {
            #pragma unroll
            for (int m = 0; m < 4; ++m)
                #pragma unroll
                for (int i = 0; i < 4; ++i) {
                    int row_l = m*16 + q*4 + i;              // 0..63 (batch-local)
                    #pragma unroll
                    for (int n = 0; n < 6; ++n)
                        elds[row_l * ELDW + sofs[n]] = f2bf(acc[m][n][i] + vtv[n]);
                }
        }
        __syncthreads();
        // (c) skin: each wave owns 16 batch rows; af ping-pong prefetched
        {
            s16x8 afA, afB;
            int bl0 = wave * 16;
            int bgbase = bt * 128 + half * 64;
            afA = *(const s16x8*)&Gmf[((size_t)(bgbase + bl0) * 64 + lane) * 8];
            #pragma unroll
            for (int bb = 0; bb < 16; ++bb) {
                if (bb + 1 < 16) {
                    const s16x8* nx = (const s16x8*)&Gmf[((size_t)(bgbase + bl0 + bb + 1) * 64 + lane) * 8];
                    if (bb & 1) afA = *nx; else afB = *nx;
                }
                s16x8 af = (bb & 1) ? afB : afA;
                int bl = bl0 + bb;
                int bg = bgbase + bl;
                #pragma unroll
                for (int m = 0; m < 4; ++m) {
                    s16x4 vd = *(const s16x4*)&elds[bl * ELDW + (m*16 + c16) * 4];
                    f32x4 zz = {0.0f, 0.0f, 0.0f, 0.0f};
                    f32x4 Tq = __builtin_amdgcn_mfma_f32_16x16x32_bf16(af, wf[m], zz, 0, 0, 0);
                    if (vok[m]) {
                        float x = bf2fs((unsigned short)vd[0]);
                        float y = bf2fs((unsigned short)vd[1]);
                        float z = bf2fs((unsigned short)vd[2]);
                        float o = Tq[0]*x + Tq[1]*y + Tq[2]*z + Tq[3];
                        vout[(size_t)bg * NR + (size_t)vert[m] * 3 + q] = o;
                    }
                }
            }
        }
        __syncthreads();
    }
}

// ============ K8: MFMA skinning, f32 in-place (fallback) ============
__global__ __launch_bounds__(256) void k_skin(float* __restrict__ vio,
        const float* __restrict__ W, const float* __restrict__ Gc, int B) {
    __shared__ short Gm[16 * 40];
    const int t = threadIdx.x;
    const int wave = t >> 6, lane = t & 63;
    const int q = lane >> 4, c = lane & 15;
    const int vb = blockIdx.x * 256 + wave * 64;
    const int b0 = blockIdx.y * 16;

    if (t < 320) ((int*)Gm)[t] = 0;

    s16x8 wf[4];
    #pragma unroll
    for (int m = 0; m < 4; ++m) {
        int vert = vb + m*16 + c;
        if (q < 3 && vert < NV) {
            const float* wp = W + (size_t)vert * NJ + q*8;
            float4 f0 = *(const float4*)(wp);
            float4 f1 = *(const float4*)(wp + 4);
            wf[m][0]=f2bf(f0.x); wf[m][1]=f2bf(f0.y); wf[m][2]=f2bf(f0.z); wf[m][3]=f2bf(f0.w);
            wf[m][4]=f2bf(f1.x); wf[m][5]=f2bf(f1.y); wf[m][6]=f2bf(f1.z); wf[m][7]=f2bf(f1.w);
        } else {
            #pragma unroll
            for (int e = 0; e < 8; ++e) wf[m][e] = 0;
        }
    }
    __syncthreads();

    for (int bb = 0; bb < 16; ++bb) {
        int b = b0 + bb;
        if (b >= B) break;
        {
            int i0 = t;
            int j0 = i0 / 12, c0 = i0 - j0*12;
            if (i0 < 288) Gm[c0*40 + j0] = f2bf(Gc[(size_t)b*288 + i0]);
            int i1 = t + 256;
            if (i1 < 288) {
                int j1 = i1 / 12, c1 = i1 - j1*12;
                Gm[c1*40 + j1] = f2bf(Gc[(size_t)b*288 + i1]);
            }
        }
        __syncthreads();

        s16x8 af = *(const s16x8*)&Gm[c*40 + q*8];
        #pragma unroll
        for (int m = 0; m < 4; ++m) {
            f32x4 zz = {0.0f, 0.0f, 0.0f, 0.0f};
            f32x4 acc = __builtin_amdgcn_mfma_f32_16x16x32_bf16(af, wf[m], zz, 0, 0, 0);
            int vert = vb + m*16 + c;
            bool ok = (q < 3) && (vert < NV);
            if (ok) {
                float* vp = vio + (size_t)b * NR + (size_t)vert * 3;
                float x = vp[0], y = vp[1], z = vp[2];
                float o = acc[0]*x + acc[1]*y + acc[2]*z + acc[3];
                vp[q] = o;
            }
        }
        __syncthreads();
    }
}

extern "C" void kernel_launch(void* const* d_in, const int* in_sizes, int n_in,
                              void* d_out, int out_size, void* d_ws, size_t ws_size,
                              hipStream_t stream) {
    const float* theta = (const float*)d_in[0];
    const float* beta  = (const float*)d_in[1];
    const float* sd    = (const float*)d_in[2];
    const float* pd    = (const float*)d_in[3];
    const float* Jreg  = (const float*)d_in[4];
    const float* vt    = (const float*)d_in[5];
    const float* W     = (const float*)d_in[6];
    float* out = (float*)d_out;

    const int B = in_sizes[0] / 72;

    float* vregion = out;
    float* Jout    = out + (size_t)B * NR;

    float* Rws   = (float*)d_ws;                          // B*216 f32
    float* Gcws  = Rws + (size_t)B * 216;                 // B*288 f32
    float* pfA   = Gcws + (size_t)B * 288;                // B*224 f32
    short* Afrag = (short*)(pfA + (size_t)B * 224);       // (B/128)*FTILE bf16
    short* Bfrag = Afrag + (size_t)(B/128) * FTILE;       // NT2*FT2 shorts (10.6 MB)
    short* Gmf   = Bfrag + (size_t)NT2 * FT2;             // B*512 bf16 (1 MB)

    size_t need_fuse = (size_t)B * 2912 + (size_t)(B/128) * FTILE * 2
                     + (size_t)NT2 * FT2 * 2 + (size_t)B * 512 * 2;
    const bool use_fuse = (ws_size >= need_fuse) && ((B & 127) == 0);

    float* part  = vregion;                               // d_out scratch pre-GEMM
    float* part2 = vregion + (size_t)NSPLIT * 72 * 224;
    float* JDt   = part2 + (size_t)8 * 72 * 224;

    k_rodrigues<<<(B*NJ + 255)/256, 256, 0, stream>>>(theta, beta, Rws, pfA, Afrag, B);
    if (use_fuse) {
        dim3 grid(24, NT2);
        k_convB192<<<grid, 256, 0, stream>>>(pd, sd, Bfrag);
    } else {
        k_convB128<<<(NT*8*8*64)/256, 256, 0, stream>>>(pd, sd, Bfrag);
    }
    k_jdirs<<<NSPLIT, 256, 0, stream>>>(pd, sd, vt, Jreg, part);
    {
        dim3 grid(72, 8);
        k_jreduce1<<<grid, 256, 0, stream>>>(part, part2);
    }
    k_jreduce2<<<(72*224 + 255)/256, 256, 0, stream>>>(part2, JDt);
    k_J<<<B, 128, 0, stream>>>(pfA, JDt, Jout, B);
    k_chain<<<(B + 31)/32, 32, 0, stream>>>(Rws, Jout, Gcws, B);

    if (use_fuse) {
        k_gmf<<<(B*64 + 255)/256, 256, 0, stream>>>(Gcws, Gmf, B);
        k_gemm_skin<<<NT2 * (B/128), 256, 0, stream>>>(Afrag, Bfrag, vt, Gmf, W, vregion, B);
    } else {
        k_gemm<<<NT * (B/128), 256, 0, stream>>>(Afrag, Bfrag, vt, vregion, B);
        dim3 grid((NV + 255)/256, (B + 15)/16);
        k_skin<<<grid, 256, 0, stream>>>(vregion, W, Gcws, B);
    }
}

// Round 20
// 125.563 us; speedup vs baseline: 1.5337x; 1.0069x over previous
//
#include <hip/hip_runtime.h>
#include <hip/hip_bf16.h>

#define NJ 24
#define NV 6890
#define NVP 6912
#define NR (NV*3)        // 20670 output rows per batch
#define NPF 207
#define KB 217           // 207 pf + 10 beta
#define KP 256           // padded K (8 x 32)
#define NT 162           // 128-col tiles (fallback path)
#define NT2 108          // 192-col tiles (64 whole verts each)
#define NSPLIT 512       // jdirs v-splits
#define VPB 14           // ceil(6890/512)
#define FTILE 32768      // A-tile shorts: 8 ks * 8 frag * 64 lane * 8
#define FT2   49152      // B-tile shorts (192-col)
#define ELDW 264         // elds row stride in shorts (64 verts*4 + 8 pad)

typedef short s16x8 __attribute__((ext_vector_type(8)));
typedef short s16x4 __attribute__((ext_vector_type(4)));
typedef float f32x4 __attribute__((ext_vector_type(4)));
typedef float f4u   __attribute__((ext_vector_type(4), aligned(4)));

__device__ constexpr int PAR[24] = {-1,0,0,0,1,2,3,4,5,6,7,8,9,9,9,12,13,14,16,17,18,19,20,21};

__device__ __forceinline__ short f2bf(float f) {
    __hip_bfloat16 h = __float2bfloat16(f);
    return *reinterpret_cast<short*>(&h);
}
__device__ __forceinline__ float bf2fs(unsigned short u) {
    unsigned int x = ((unsigned int)u) << 16;
    return __uint_as_float(x);
}

// A-fragment address for (row_in_tile, k)
__device__ __forceinline__ size_t frag_addr(int row128, int k) {
    int ks = k >> 5, q = (k >> 3) & 3, e = k & 7;
    int mf = row128 >> 4, r16 = row128 & 15;
    return ((size_t)(ks*8 + mf) * 64 + q*16 + r16) * 8 + e;
}

// ============ K1: Rodrigues -> Rws(f32), pfA(f32), Afrag(bf16 fragment layout) ============
__global__ __launch_bounds__(256) void k_rodrigues(const float* __restrict__ theta,
        const float* __restrict__ beta, float* __restrict__ Rws,
        float* __restrict__ pfA, short* __restrict__ Afrag, int B) {
    int idx = blockIdx.x * blockDim.x + threadIdx.x;   // b*24 + j
    if (idx >= B * NJ) return;
    int b = idx / NJ, j = idx % NJ;
    float x = theta[b*72 + j*3 + 0];
    float y = theta[b*72 + j*3 + 1];
    float z = theta[b*72 + j*3 + 2];
    float n = sqrtf(x*x + y*y + z*z);
    float a = fmaxf(n, 1e-8f);
    float inv = 1.0f / a;
    float ix = x*inv, iy = y*inv, iz = z*inv;
    float c = cosf(a), s = sinf(a), t = 1.0f - c;
    float r[9];
    r[0] = t*ix*ix + c;     r[1] = t*ix*iy - s*iz;  r[2] = t*ix*iz + s*iy;
    r[3] = t*ix*iy + s*iz;  r[4] = t*iy*iy + c;     r[5] = t*iy*iz - s*ix;
    r[6] = t*ix*iz - s*iy;  r[7] = t*iy*iz + s*ix;  r[8] = t*iz*iz + c;
    float* Rp = Rws + (size_t)idx * 9;
    #pragma unroll
    for (int k = 0; k < 9; ++k) Rp[k] = r[k];

    int rb = b & 127;
    short* At = Afrag + (size_t)(b >> 7) * FTILE;
    float* pa = pfA + (size_t)b * 224;
    if (j >= 1) {
        #pragma unroll
        for (int kk = 0; kk < 9; ++kk) {
            int k = (j-1)*9 + kk;
            float f = r[kk] - ((kk == 0 || kk == 4 || kk == 8) ? 1.0f : 0.0f);
            At[frag_addr(rb, k)] = f2bf(f);
            pa[k] = f;
        }
    } else {
        #pragma unroll
        for (int kk = 0; kk < 10; ++kk) {
            int k = NPF + kk;
            float f = beta[b*10 + kk];
            At[frag_addr(rb, k)] = f2bf(f);
            pa[k] = f;
        }
        for (int k = KB; k < KP; ++k)
            At[frag_addr(rb, k)] = 0;
    }
}

// ============ K2a: Bfrag for 192-col tiles ============
__global__ __launch_bounds__(256) void k_convB192(const float* __restrict__ pd,
        const float* __restrict__ sd, short* __restrict__ Bf) {
    int nt = blockIdx.y;
    int id = blockIdx.x * 256 + threadIdx.x;       // (ks*12 + nf)*64 + lane
    int lane_ = id & 63;
    int fi = id >> 6;
    int nf = fi % 12, ks = fi / 12;
    int q = lane_ >> 4, r16 = lane_ & 15;
    int rg = nt*192 + nf*16 + r16;
    int k0 = ks*32 + q*8;
    s16x8 v;
    if (rg < NR) {
        if (k0 + 7 < NPF) {
            const float* p = pd + (size_t)rg * NPF + k0;
            #pragma unroll
            for (int k = 0; k < 8; ++k) v[k] = f2bf(p[k]);
        } else {
            #pragma unroll
            for (int k = 0; k < 8; ++k) {
                int col = k0 + k;
                float f = 0.0f;
                if (col < NPF)     f = pd[(size_t)rg * NPF + col];
                else if (col < KB) f = sd[(size_t)rg * 10 + (col - NPF)];
                v[k] = f2bf(f);
            }
        }
    } else {
        #pragma unroll
        for (int k = 0; k < 8; ++k) v[k] = 0;
    }
    *(s16x8*)&Bf[((size_t)nt * FT2) + (size_t)id * 8] = v;
}

// ============ K2b: Bfrag for 128-col tiles (fallback) ============
__global__ __launch_bounds__(256) void k_convB128(const float* __restrict__ pd,
        const float* __restrict__ sd, short* __restrict__ Bf) {
    int cid = blockIdx.x * 256 + threadIdx.x;
    int lane_ = cid & 63;
    int nf = (cid >> 6) & 7;
    int ks = (cid >> 9) & 7;
    int nt = cid >> 12;
    int q = lane_ >> 4, r16 = lane_ & 15;
    int rg = nt*128 + nf*16 + r16;
    int k0 = ks*32 + q*8;
    s16x8 v;
    if (rg < NR) {
        if (k0 + 7 < NPF) {
            const float* p = pd + (size_t)rg * NPF + k0;
            #pragma unroll
            for (int k = 0; k < 8; ++k) v[k] = f2bf(p[k]);
        } else {
            #pragma unroll
            for (int k = 0; k < 8; ++k) {
                int col = k0 + k;
                float f = 0.0f;
                if (col < NPF)     f = pd[(size_t)rg * NPF + col];
                else if (col < KB) f = sd[(size_t)rg * 10 + (col - NPF)];
                v[k] = f2bf(f);
            }
        }
    } else {
        #pragma unroll
        for (int k = 0; k < 8; ++k) v[k] = 0;
    }
    *(s16x8*)&Bf[(size_t)cid * 8] = v;
}

// ============ K3: JD partials ============
__global__ __launch_bounds__(256) void k_jdirs(const float* __restrict__ pd,
        const float* __restrict__ sd, const float* __restrict__ vt,
        const float* __restrict__ Jreg, float* __restrict__ part) {
    __shared__ float wjs[24][VPB];
    int bi = blockIdx.x;
    int v0 = bi * VPB;
    int nv = NV - v0; if (nv > VPB) nv = VPB; if (nv < 0) nv = 0;
    for (int i = threadIdx.x; i < 24*VPB; i += 256) {
        int j = i / VPB, vv = i - j*VPB;
        wjs[j][vv] = (vv < nv) ? Jreg[(size_t)j * NV + v0 + vv] : 0.0f;
    }
    __syncthreads();
    int k = threadIdx.x;
    float acc[72];
    #pragma unroll
    for (int i = 0; i < 72; ++i) acc[i] = 0.0f;
    for (int vv = 0; vv < VPB; ++vv) {
        int v = v0 + vv;
        if (v >= NV) break;
        #pragma unroll
        for (int c = 0; c < 3; ++c) {
            int row = v*3 + c;
            float val = 0.0f;
            if (k < NPF)      val = pd[(size_t)row * NPF + k];
            else if (k < KB)  val = sd[(size_t)row * 10 + (k - NPF)];
            else if (k == KB) val = vt[row];
            #pragma unroll
            for (int j = 0; j < 24; ++j) acc[j*3 + c] += wjs[j][vv] * val;
        }
    }
    if (k < 224) {
        float* p = part + (size_t)bi * (72*224);
        #pragma unroll
        for (int i = 0; i < 72; ++i) p[i*224 + k] = acc[i];
    }
}

// ============ K4a: reduce 512 -> 8 partials ============
__global__ __launch_bounds__(256) void k_jreduce1(const float* __restrict__ part,
        float* __restrict__ part2) {
    int i = blockIdx.x;
    int s = blockIdx.y;
    int k = threadIdx.x;
    if (k >= 224) return;
    float acc = 0.0f;
    #pragma unroll 4
    for (int bi = s*64; bi < s*64 + 64; ++bi)
        acc += part[(size_t)bi * (72*224) + i*224 + k];
    part2[((size_t)s * 72 + i) * 224 + k] = acc;
}

// ============ K4b: reduce 8 -> JDt[k][72] ============
__global__ __launch_bounds__(256) void k_jreduce2(const float* __restrict__ part2,
        float* __restrict__ JDt) {
    int e = blockIdx.x * 256 + threadIdx.x;
    if (e >= 72*224) return;
    int i = e / 224, k = e - i*224;
    float s = 0.0f;
    #pragma unroll
    for (int ss = 0; ss < 8; ++ss)
        s += part2[((size_t)ss * 72 + i) * 224 + k];
    if (k < 218) JDt[k*72 + i] = s;
}

// ============ K5: J ============
__global__ __launch_bounds__(128) void k_J(const float* __restrict__ pfA,
        const float* __restrict__ JDt, float* __restrict__ Jout, int B) {
    int b = blockIdx.x, t = threadIdx.x;
    if (t >= 72) return;
    const float* pa = pfA + (size_t)b * 224;
    float acc = JDt[217*72 + t];
    #pragma unroll 7
    for (int k = 0; k < KB; ++k) acc += pa[k] * JDt[k*72 + t];
    Jout[(size_t)b * 72 + t] = acc;
}

// ============ K6: kinematic chain -> G_corr ============
__global__ __launch_bounds__(32) void k_chain(const float* __restrict__ Rg,
        const float* __restrict__ Jg, float* __restrict__ Gc, int B) {
    __shared__ float Gs[32 * 289];
    int b = blockIdx.x * 32 + threadIdx.x;
    if (b >= B) return;
    float* G = &Gs[threadIdx.x * 289];
    float Jl[72];
    const float* Jb = Jg + (size_t)b * 72;
    #pragma unroll
    for (int i = 0; i < 72; ++i) Jl[i] = Jb[i];
    const float* Rb = Rg + (size_t)b * 216;
    G[0]=Rb[0]; G[1]=Rb[1]; G[2]=Rb[2];  G[3]=Jl[0];
    G[4]=Rb[3]; G[5]=Rb[4]; G[6]=Rb[5];  G[7]=Jl[1];
    G[8]=Rb[6]; G[9]=Rb[7]; G[10]=Rb[8]; G[11]=Jl[2];
    #pragma unroll
    for (int i = 1; i < NJ; ++i) {
        const int p = PAR[i];
        const float* Ri = Rb + i*9;
        float r00=Ri[0],r01=Ri[1],r02=Ri[2];
        float r10=Ri[3],r11=Ri[4],r12=Ri[5];
        float r20=Ri[6],r21=Ri[7],r22=Ri[8];
        float px=Jl[p*3+0], py=Jl[p*3+1], pz=Jl[p*3+2];
        float tx = Jl[i*3+0] - (r00*px + r01*py + r02*pz);
        float ty = Jl[i*3+1] - (r10*px + r11*py + r12*pz);
        float tz = Jl[i*3+2] - (r20*px + r21*py + r22*pz);
        const float* gp = &G[p*12];
        float* gi = &G[i*12];
        #pragma unroll
        for (int rr = 0; rr < 3; ++rr) {
            float a0=gp[rr*4+0], a1=gp[rr*4+1], a2=gp[rr*4+2], a3=gp[rr*4+3];
            gi[rr*4+0] = a0*r00 + a1*r10 + a2*r20;
            gi[rr*4+1] = a0*r01 + a1*r11 + a2*r21;
            gi[rr*4+2] = a0*r02 + a1*r12 + a2*r22;
            gi[rr*4+3] = a0*tx + a1*ty + a2*tz + a3;
        }
    }
    float* out = Gc + (size_t)b * 288;
    #pragma unroll
    for (int i = 0; i < NJ; ++i) {
        const float* gi = &G[i*12];
        float jx=Jl[i*3+0], jy=Jl[i*3+1], jz=Jl[i*3+2];
        #pragma unroll
        for (int rr = 0; rr < 3; ++rr) {
            out[i*12+rr*4+0] = gi[rr*4+0];
            out[i*12+rr*4+1] = gi[rr*4+1];
            out[i*12+rr*4+2] = gi[rr*4+2];
            out[i*12+rr*4+3] = gi[rr*4+3] - (gi[rr*4+0]*jx + gi[rr*4+1]*jy + gi[rr*4+2]*jz);
        }
    }
}

// ============ K6b: Gmf[b][lane][8] bf16 skin-A-fragments ============
__global__ __launch_bounds__(256) void k_gmf(const float* __restrict__ Gc,
        short* __restrict__ Gmf, int B) {
    int idx = blockIdx.x * 256 + threadIdx.x;
    if (idx >= B * 64) return;
    int lane_ = idx & 63, b = idx >> 6;
    int q = lane_ >> 4, c = lane_ & 15;
    s16x8 v;
    if (c < 12 && q < 3) {
        #pragma unroll
        for (int e = 0; e < 8; ++e)
            v[e] = f2bf(Gc[(size_t)b * 288 + (q*8 + e)*12 + c]);
    } else {
        #pragma unroll
        for (int e = 0; e < 8; ++e) v[e] = 0;
    }
    *(s16x8*)&Gmf[(size_t)idx * 8] = v;
}

// ============ K7: 128-col streaming GEMM, f32 out (fallback) ============
__global__ __launch_bounds__(256, 2) void k_gemm(const short* __restrict__ Af,
        const short* __restrict__ Bf, const float* __restrict__ vt,
        float* __restrict__ vout, int B) {
    __shared__ float eld[64 * 128];
    const int t = threadIdx.x;
    const int wgid = blockIdx.x;
    const int bt = wgid & 7, nt = wgid >> 3;
    const int wave = t >> 6, lane = t & 63;
    const int wn = (wave & 1) * 64;
    const int q = lane >> 4, r16 = lane & 15;
    const int mfb = (wave >> 1) * 4, nfb = (wave & 1) * 4;

    const s16x8* Ab = (const s16x8*)(Af + (size_t)bt * FTILE);
    const s16x8* Bb = (const s16x8*)(Bf + (size_t)nt * FTILE);

    f32x4 acc[4][4];
    #pragma unroll
    for (int m = 0; m < 4; ++m)
        #pragma unroll
        for (int n = 0; n < 4; ++n)
            #pragma unroll
            for (int i = 0; i < 4; ++i) acc[m][n][i] = 0.0f;

    #pragma unroll
    for (int ks = 0; ks < 8; ++ks) {
        s16x8 a[4], b[4];
        #pragma unroll
        for (int m = 0; m < 4; ++m) a[m] = Ab[(ks*8 + mfb + m)*64 + lane];
        #pragma unroll
        for (int n = 0; n < 4; ++n) b[n] = Bb[(ks*8 + nfb + n)*64 + lane];
        #pragma unroll
        for (int m = 0; m < 4; ++m)
            #pragma unroll
            for (int n = 0; n < 4; ++n)
                acc[m][n] = __builtin_amdgcn_mfma_f32_16x16x32_bf16(a[m], b[n], acc[m][n], 0, 0, 0);
    }

    #pragma unroll
    for (int half = 0; half < 2; ++half) {
        if ((wave >> 1) == half) {
            #pragma unroll
            for (int m = 0; m < 4; ++m)
                #pragma unroll
                for (int n = 0; n < 4; ++n)
                    #pragma unroll
                    for (int i = 0; i < 4; ++i) {
                        int row_l = m*16 + q*4 + i;
                        int col = wn + n*16 + r16;
                        eld[row_l * 128 + (col ^ ((row_l & 7) << 2))] = acc[m][n][i];
                    }
        }
        __syncthreads();
        {
            const int c32 = t & 31;
            const int col = c32 * 4;
            const int rsub = (t >> 5) & 1;
            #pragma unroll
            for (int it = 0; it < 8; ++it) {
                int row_l = it * 8 + wave * 2 + rsub;
                int bg = bt * 128 + half * 64 + row_l;
                int rg = nt * 128 + col;
                f32x4 v = *(const f32x4*)&eld[row_l * 128 + (col ^ ((row_l & 7) << 2))];
                if (bg < B) {
                    float* dst = vout + (size_t)bg * NR + rg;
                    if (rg + 3 < NR) {
                        float4 tv = *(const float4*)(vt + rg);
                        v[0] += tv.x; v[1] += tv.y; v[2] += tv.z; v[3] += tv.w;
                        *(f4u*)dst = v;
                    } else {
                        #pragma unroll
                        for (int e = 0; e < 4; ++e)
                            if (rg + e < NR) dst[e] = v[e] + vt[rg + e];
                    }
                }
            }
        }
        __syncthreads();
    }
}

// ============ K7b: FUSED 192-col GEMM + MFMA skinning, single-pass 128-row epilogue ============
__global__ __launch_bounds__(256, 2) void k_gemm_skin(const short* __restrict__ Af,
        const short* __restrict__ Bf, const float* __restrict__ vt,
        const short* __restrict__ Gmf, const float* __restrict__ W,
        float* __restrict__ vout, int B) {
    __shared__ short elds[128 * ELDW];             // 67.6 KB bf16 v_posed (full tile)
    const int t = threadIdx.x;
    const int wgid = blockIdx.x;
    const int bt = wgid & 7, nt = wgid >> 3;       // nt 0..107
    const int wave = t >> 6, lane = t & 63;
    const int wn = (wave & 1) * 96;
    const int q = lane >> 4, r16 = lane & 15;
    const int mfb = (wave >> 1) * 4, nfb = (wave & 1) * 6;
    const int rowbase = (wave >> 1) * 64;          // rows this wave's acc covers

    const s16x8* Ab = (const s16x8*)(Af + (size_t)bt * FTILE);
    const s16x8* Bb = (const s16x8*)(Bf + (size_t)nt * FT2);

    f32x4 acc[4][6];
    #pragma unroll
    for (int m = 0; m < 4; ++m)
        #pragma unroll
        for (int n = 0; n < 6; ++n)
            #pragma unroll
            for (int i = 0; i < 4; ++i) acc[m][n][i] = 0.0f;

    #pragma unroll
    for (int ks = 0; ks < 8; ++ks) {
        s16x8 a[4], b[6];
        #pragma unroll
        for (int m = 0; m < 4; ++m) a[m] = Ab[(ks*8 + mfb + m)*64 + lane];
        #pragma unroll
        for (int n = 0; n < 6; ++n) b[n] = Bb[(ks*12 + nfb + n)*64 + lane];
        #pragma unroll
        for (int m = 0; m < 4; ++m)
            #pragma unroll
            for (int n = 0; n < 6; ++n)
                acc[m][n] = __builtin_amdgcn_mfma_f32_16x16x32_bf16(a[m], b[n], acc[m][n], 0, 0, 0);
    }

    // per-n vt value + LDS short-offset (vert*4 + comp)
    float vtv[6];
    int sofs[6];
    #pragma unroll
    for (int n = 0; n < 6; ++n) {
        int col = wn + n*16 + r16;
        int rg = nt*192 + col;
        vtv[n] = (rg < NR) ? vt[rg] : 0.0f;
        int vert = col / 3;
        sofs[n] = vert*4 + (col - vert*3);
    }

    // W fragments for this tile's 64 verts
    s16x8 wf[4];
    int vert[4];
    bool vok[4];
    const int c16 = lane & 15;
    #pragma unroll
    for (int m = 0; m < 4; ++m) {
        vert[m] = nt*64 + m*16 + c16;
        vok[m] = (q < 3) && (vert[m] < NV);
        if (vok[m]) {
            const float* wp = W + (size_t)vert[m] * NJ + q*8;
            float4 f0 = *(const float4*)(wp);
            float4 f1 = *(const float4*)(wp + 4);
            wf[m][0]=f2bf(f0.x); wf[m][1]=f2bf(f0.y); wf[m][2]=f2bf(f0.z); wf[m][3]=f2bf(f0.w);
            wf[m][4]=f2bf(f1.x); wf[m][5]=f2bf(f1.y); wf[m][6]=f2bf(f1.z); wf[m][7]=f2bf(f1.w);
        } else {
            #pragma unroll
            for (int e = 0; e < 8; ++e) wf[m][e] = 0;
        }
    }

    // (a) ALL waves write their acc into the full 128-row elds (disjoint regions)
    #pragma unroll
    for (int m = 0; m < 4; ++m)
        #pragma unroll
        for (int i = 0; i < 4; ++i) {
            int row_l = rowbase + m*16 + q*4 + i;          // 0..127
            #pragma unroll
            for (int n = 0; n < 6; ++n)
                elds[row_l * ELDW + sofs[n]] = f2bf(acc[m][n][i] + vtv[n]);
        }
    __syncthreads();

    // (c) skin: each wave owns 32 batch rows; Gmf ping-pong prefetched
    {
        s16x8 afA, afB;
        int bl0 = wave * 32;
        int bgbase = bt * 128;
        afA = *(const s16x8*)&Gmf[((size_t)(bgbase + bl0) * 64 + lane) * 8];
        #pragma unroll 8
        for (int bb = 0; bb < 32; ++bb) {
            if (bb + 1 < 32) {
                const s16x8* nx = (const s16x8*)&Gmf[((size_t)(bgbase + bl0 + bb + 1) * 64 + lane) * 8];
                if (bb & 1) afA = *nx; else afB = *nx;
            }
            s16x8 af = (bb & 1) ? afB : afA;
            int bl = bl0 + bb;
            int bg = bgbase + bl;
            #pragma unroll
            for (int m = 0; m < 4; ++m) {
                s16x4 vd = *(const s16x4*)&elds[bl * ELDW + (m*16 + c16) * 4];
                f32x4 zz = {0.0f, 0.0f, 0.0f, 0.0f};
                f32x4 Tq = __builtin_amdgcn_mfma_f32_16x16x32_bf16(af, wf[m], zz, 0, 0, 0);
                if (vok[m]) {
                    float x = bf2fs((unsigned short)vd[0]);
                    float y = bf2fs((unsigned short)vd[1]);
                    float z = bf2fs((unsigned short)vd[2]);
                    float o = Tq[0]*x + Tq[1]*y + Tq[2]*z + Tq[3];
                    vout[(size_t)bg * NR + (size_t)vert[m] * 3 + q] = o;
                }
            }
        }
    }
}

// ============ K8: MFMA skinning, f32 in-place (fallback) ============
__global__ __launch_bounds__(256) void k_skin(float* __restrict__ vio,
        const float* __restrict__ W, const float* __restrict__ Gc, int B) {
    __shared__ short Gm[16 * 40];
    const int t = threadIdx.x;
    const int wave = t >> 6, lane = t & 63;
    const int q = lane >> 4, c = lane & 15;
    const int vb = blockIdx.x * 256 + wave * 64;
    const int b0 = blockIdx.y * 16;

    if (t < 320) ((int*)Gm)[t] = 0;

    s16x8 wf[4];
    #pragma unroll
    for (int m = 0; m < 4; ++m) {
        int vert = vb + m*16 + c;
        if (q < 3 && vert < NV) {
            const float* wp = W + (size_t)vert * NJ + q*8;
            float4 f0 = *(const float4*)(wp);
            float4 f1 = *(const float4*)(wp + 4);
            wf[m][0]=f2bf(f0.x); wf[m][1]=f2bf(f0.y); wf[m][2]=f2bf(f0.z); wf[m][3]=f2bf(f0.w);
            wf[m][4]=f2bf(f1.x); wf[m][5]=f2bf(f1.y); wf[m][6]=f2bf(f1.z); wf[m][7]=f2bf(f1.w);
        } else {
            #pragma unroll
            for (int e = 0; e < 8; ++e) wf[m][e] = 0;
        }
    }
    __syncthreads();

    for (int bb = 0; bb < 16; ++bb) {
        int b = b0 + bb;
        if (b >= B) break;
        {
            int i0 = t;
            int j0 = i0 / 12, c0 = i0 - j0*12;
            if (i0 < 288) Gm[c0*40 + j0] = f2bf(Gc[(size_t)b*288 + i0]);
            int i1 = t + 256;
            if (i1 < 288) {
                int j1 = i1 / 12, c1 = i1 - j1*12;
                Gm[c1*40 + j1] = f2bf(Gc[(size_t)b*288 + i1]);
            }
        }
        __syncthreads();

        s16x8 af = *(const s16x8*)&Gm[c*40 + q*8];
        #pragma unroll
        for (int m = 0; m < 4; ++m) {
            f32x4 zz = {0.0f, 0.0f, 0.0f, 0.0f};
            f32x4 acc = __builtin_amdgcn_mfma_f32_16x16x32_bf16(af, wf[m], zz, 0, 0, 0);
            int vert = vb + m*16 + c;
            bool ok = (q < 3) && (vert < NV);
            if (ok) {
                float* vp = vio + (size_t)b * NR + (size_t)vert * 3;
                float x = vp[0], y = vp[1], z = vp[2];
                float o = acc[0]*x + acc[1]*y + acc[2]*z + acc[3];
                vp[q] = o;
            }
        }
        __syncthreads();
    }
}

extern "C" void kernel_launch(void* const* d_in, const int* in_sizes, int n_in,
                              void* d_out, int out_size, void* d_ws, size_t ws_size,
                              hipStream_t stream) {
    const float* theta = (const float*)d_in[0];
    const float* beta  = (const float*)d_in[1];
    const float* sd    = (const float*)d_in[2];
    const float* pd    = (const float*)d_in[3];
    const float* Jreg  = (const float*)d_in[4];
    const float* vt    = (const float*)d_in[5];
    const float* W     = (const float*)d_in[6];
    float* out = (float*)d_out;

    const int B = in_sizes[0] / 72;

    float* vregion = out;
    float* Jout    = out + (size_t)B * NR;

    float* Rws   = (float*)d_ws;                          // B*216 f32
    float* Gcws  = Rws + (size_t)B * 216;                 // B*288 f32
    float* pfA   = Gcws + (size_t)B * 288;                // B*224 f32
    short* Afrag = (short*)(pfA + (size_t)B * 224);       // (B/128)*FTILE bf16
    short* Bfrag = Afrag + (size_t)(B/128) * FTILE;       // NT2*FT2 shorts (10.6 MB)
    short* Gmf   = Bfrag + (size_t)NT2 * FT2;             // B*512 bf16 (1 MB)

    size_t need_fuse = (size_t)B * 2912 + (size_t)(B/128) * FTILE * 2
                     + (size_t)NT2 * FT2 * 2 + (size_t)B * 512 * 2;
    const bool use_fuse = (ws_size >= need_fuse) && ((B & 127) == 0);

    float* part  = vregion;                               // d_out scratch pre-GEMM
    float* part2 = vregion + (size_t)NSPLIT * 72 * 224;
    float* JDt   = part2 + (size_t)8 * 72 * 224;

    k_rodrigues<<<(B*NJ + 255)/256, 256, 0, stream>>>(theta, beta, Rws, pfA, Afrag, B);
    if (use_fuse) {
        dim3 grid(24, NT2);
        k_convB192<<<grid, 256, 0, stream>>>(pd, sd, Bfrag);
    } else {
        k_convB128<<<(NT*8*8*64)/256, 256, 0, stream>>>(pd, sd, Bfrag);
    }
    k_jdirs<<<NSPLIT, 256, 0, stream>>>(pd, sd, vt, Jreg, part);
    {
        dim3 grid(72, 8);
        k_jreduce1<<<grid, 256, 0, stream>>>(part, part2);
    }
    k_jreduce2<<<(72*224 + 255)/256, 256, 0, stream>>>(part2, JDt);
    k_J<<<B, 128, 0, stream>>>(pfA, JDt, Jout, B);
    k_chain<<<(B + 31)/32, 32, 0, stream>>>(Rws, Jout, Gcws, B);

    if (use_fuse) {
        k_gmf<<<(B*64 + 255)/256, 256, 0, stream>>>(Gcws, Gmf, B);
        k_gemm_skin<<<NT2 * (B/128), 256, 0, stream>>>(Afrag, Bfrag, vt, Gmf, W, vregion, B);
    } else {
        k_gemm<<<NT * (B/128), 256, 0, stream>>>(Afrag, Bfrag, vt, vregion, B);
        dim3 grid((NV + 255)/256, (B + 15)/16);
        k_skin<<<grid, 256, 0, stream>>>(vregion, W, Gcws, B);
    }
}

// Round 21
// 114.386 us; speedup vs baseline: 1.6835x; 1.0977x over previous
//
#include <hip/hip_runtime.h>
#include <hip/hip_bf16.h>

#define NJ 24
#define NV 6890
#define NVP 6912
#define NR (NV*3)        // 20670 output rows per batch
#define NPF 207
#define KB 217           // 207 pf + 10 beta
#define KP 256           // padded K (8 x 32)
#define NT 162           // 128-col tiles (fallback path)
#define NT2 108          // 192-col tiles (64 whole verts each)
#define NSPLIT 512       // jdirs v-splits
#define VPB 14           // ceil(6890/512)
#define FTILE 32768      // A-tile shorts: 8 ks * 8 frag * 64 lane * 8
#define FT2   49152      // B-tile shorts (192-col)
#define ELDW 264         // elds row stride in shorts (64 verts*4 + 8 pad)

typedef short s16x8 __attribute__((ext_vector_type(8)));
typedef short s16x4 __attribute__((ext_vector_type(4)));
typedef float f32x4 __attribute__((ext_vector_type(4)));
typedef float f4u   __attribute__((ext_vector_type(4), aligned(4)));

__device__ constexpr int PAR[24] = {-1,0,0,0,1,2,3,4,5,6,7,8,9,9,9,12,13,14,16,17,18,19,20,21};

__device__ __forceinline__ short f2bf(float f) {
    __hip_bfloat16 h = __float2bfloat16(f);
    return *reinterpret_cast<short*>(&h);
}
__device__ __forceinline__ float bf2fs(unsigned short u) {
    unsigned int x = ((unsigned int)u) << 16;
    return __uint_as_float(x);
}

// A-fragment address for (row_in_tile, k)
__device__ __forceinline__ size_t frag_addr(int row128, int k) {
    int ks = k >> 5, q = (k >> 3) & 3, e = k & 7;
    int mf = row128 >> 4, r16 = row128 & 15;
    return ((size_t)(ks*8 + mf) * 64 + q*16 + r16) * 8 + e;
}

// -------- device bodies shared by fat kernel and fallbacks --------
__device__ __forceinline__ void rodrigues_body(int idx, const float* __restrict__ theta,
        const float* __restrict__ beta, float* __restrict__ Rws,
        float* __restrict__ pfA, short* __restrict__ Afrag, int B) {
    if (idx >= B * NJ) return;
    int b = idx / NJ, j = idx % NJ;
    float x = theta[b*72 + j*3 + 0];
    float y = theta[b*72 + j*3 + 1];
    float z = theta[b*72 + j*3 + 2];
    float n = sqrtf(x*x + y*y + z*z);
    float a = fmaxf(n, 1e-8f);
    float inv = 1.0f / a;
    float ix = x*inv, iy = y*inv, iz = z*inv;
    float c = cosf(a), s = sinf(a), t = 1.0f - c;
    float r[9];
    r[0] = t*ix*ix + c;     r[1] = t*ix*iy - s*iz;  r[2] = t*ix*iz + s*iy;
    r[3] = t*ix*iy + s*iz;  r[4] = t*iy*iy + c;     r[5] = t*iy*iz - s*ix;
    r[6] = t*ix*iz - s*iy;  r[7] = t*iy*iz + s*ix;  r[8] = t*iz*iz + c;
    float* Rp = Rws + (size_t)idx * 9;
    #pragma unroll
    for (int k = 0; k < 9; ++k) Rp[k] = r[k];

    int rb = b & 127;
    short* At = Afrag + (size_t)(b >> 7) * FTILE;
    float* pa = pfA + (size_t)b * 224;
    if (j >= 1) {
        #pragma unroll
        for (int kk = 0; kk < 9; ++kk) {
            int k = (j-1)*9 + kk;
            float f = r[kk] - ((kk == 0 || kk == 4 || kk == 8) ? 1.0f : 0.0f);
            At[frag_addr(rb, k)] = f2bf(f);
            pa[k] = f;
        }
    } else {
        #pragma unroll
        for (int kk = 0; kk < 10; ++kk) {
            int k = NPF + kk;
            float f = beta[b*10 + kk];
            At[frag_addr(rb, k)] = f2bf(f);
            pa[k] = f;
        }
        for (int k = KB; k < KP; ++k)
            At[frag_addr(rb, k)] = 0;
    }
}

__device__ __forceinline__ void convB192_body(int nt, int id,
        const float* __restrict__ pd, const float* __restrict__ sd,
        short* __restrict__ Bf) {
    int lane_ = id & 63;
    int fi = id >> 6;
    int nf = fi % 12, ks = fi / 12;
    int q = lane_ >> 4, r16 = lane_ & 15;
    int rg = nt*192 + nf*16 + r16;
    int k0 = ks*32 + q*8;
    s16x8 v;
    if (rg < NR) {
        if (k0 + 7 < NPF) {
            const float* p = pd + (size_t)rg * NPF + k0;
            #pragma unroll
            for (int k = 0; k < 8; ++k) v[k] = f2bf(p[k]);
        } else {
            #pragma unroll
            for (int k = 0; k < 8; ++k) {
                int col = k0 + k;
                float f = 0.0f;
                if (col < NPF)     f = pd[(size_t)rg * NPF + col];
                else if (col < KB) f = sd[(size_t)rg * 10 + (col - NPF)];
                v[k] = f2bf(f);
            }
        }
    } else {
        #pragma unroll
        for (int k = 0; k < 8; ++k) v[k] = 0;
    }
    *(s16x8*)&Bf[((size_t)nt * FT2) + (size_t)id * 8] = v;
}

// ============ K0: fat prep kernel — jdirs | convB192 | rodrigues ============
__global__ __launch_bounds__(256) void k_prep(const float* __restrict__ theta,
        const float* __restrict__ beta, const float* __restrict__ pd,
        const float* __restrict__ sd, const float* __restrict__ vt,
        const float* __restrict__ Jreg,
        float* __restrict__ Rws, float* __restrict__ pfA, short* __restrict__ Afrag,
        short* __restrict__ Bf, float* __restrict__ part, int B) {
    __shared__ float wjs[24][VPB];
    const int bid = blockIdx.x;
    const int t = threadIdx.x;
    if (bid < NSPLIT) {
        // ---- jdirs ----
        int bi = bid;
        int v0 = bi * VPB;
        int nv = NV - v0; if (nv > VPB) nv = VPB; if (nv < 0) nv = 0;
        for (int i = t; i < 24*VPB; i += 256) {
            int j = i / VPB, vv = i - j*VPB;
            wjs[j][vv] = (vv < nv) ? Jreg[(size_t)j * NV + v0 + vv] : 0.0f;
        }
        __syncthreads();
        int k = t;
        float acc[72];
        #pragma unroll
        for (int i = 0; i < 72; ++i) acc[i] = 0.0f;
        for (int vv = 0; vv < VPB; ++vv) {
            int v = v0 + vv;
            if (v >= NV) break;
            #pragma unroll
            for (int c = 0; c < 3; ++c) {
                int row = v*3 + c;
                float val = 0.0f;
                if (k < NPF)      val = pd[(size_t)row * NPF + k];
                else if (k < KB)  val = sd[(size_t)row * 10 + (k - NPF)];
                else if (k == KB) val = vt[row];
                #pragma unroll
                for (int j = 0; j < 24; ++j) acc[j*3 + c] += wjs[j][vv] * val;
            }
        }
        if (k < 224) {
            float* p = part + (size_t)bi * (72*224);
            #pragma unroll
            for (int i = 0; i < 72; ++i) p[i*224 + k] = acc[i];
        }
    } else if (bid < NSPLIT + 24*NT2) {
        // ---- convB192 ----
        int cb = bid - NSPLIT;
        int nt = cb / 24;
        int id = (cb % 24) * 256 + t;
        convB192_body(nt, id, pd, sd, Bf);
    } else {
        // ---- rodrigues ----
        int idx = (bid - NSPLIT - 24*NT2) * 256 + t;
        rodrigues_body(idx, theta, beta, Rws, pfA, Afrag, B);
    }
}

// ============ standalone kernels for fallback path ============
__global__ __launch_bounds__(256) void k_rodrigues(const float* __restrict__ theta,
        const float* __restrict__ beta, float* __restrict__ Rws,
        float* __restrict__ pfA, short* __restrict__ Afrag, int B) {
    rodrigues_body(blockIdx.x * blockDim.x + threadIdx.x, theta, beta, Rws, pfA, Afrag, B);
}

__global__ __launch_bounds__(256) void k_convB128(const float* __restrict__ pd,
        const float* __restrict__ sd, short* __restrict__ Bf) {
    int cid = blockIdx.x * 256 + threadIdx.x;
    int lane_ = cid & 63;
    int nf = (cid >> 6) & 7;
    int ks = (cid >> 9) & 7;
    int nt = cid >> 12;
    int q = lane_ >> 4, r16 = lane_ & 15;
    int rg = nt*128 + nf*16 + r16;
    int k0 = ks*32 + q*8;
    s16x8 v;
    if (rg < NR) {
        if (k0 + 7 < NPF) {
            const float* p = pd + (size_t)rg * NPF + k0;
            #pragma unroll
            for (int k = 0; k < 8; ++k) v[k] = f2bf(p[k]);
        } else {
            #pragma unroll
            for (int k = 0; k < 8; ++k) {
                int col = k0 + k;
                float f = 0.0f;
                if (col < NPF)     f = pd[(size_t)rg * NPF + col];
                else if (col < KB) f = sd[(size_t)rg * 10 + (col - NPF)];
                v[k] = f2bf(f);
            }
        }
    } else {
        #pragma unroll
        for (int k = 0; k < 8; ++k) v[k] = 0;
    }
    *(s16x8*)&Bf[(size_t)cid * 8] = v;
}

__global__ __launch_bounds__(256) void k_jdirs(const float* __restrict__ pd,
        const float* __restrict__ sd, const float* __restrict__ vt,
        const float* __restrict__ Jreg, float* __restrict__ part) {
    __shared__ float wjs[24][VPB];
    int bi = blockIdx.x;
    int v0 = bi * VPB;
    int nv = NV - v0; if (nv > VPB) nv = VPB; if (nv < 0) nv = 0;
    for (int i = threadIdx.x; i < 24*VPB; i += 256) {
        int j = i / VPB, vv = i - j*VPB;
        wjs[j][vv] = (vv < nv) ? Jreg[(size_t)j * NV + v0 + vv] : 0.0f;
    }
    __syncthreads();
    int k = threadIdx.x;
    float acc[72];
    #pragma unroll
    for (int i = 0; i < 72; ++i) acc[i] = 0.0f;
    for (int vv = 0; vv < VPB; ++vv) {
        int v = v0 + vv;
        if (v >= NV) break;
        #pragma unroll
        for (int c = 0; c < 3; ++c) {
            int row = v*3 + c;
            float val = 0.0f;
            if (k < NPF)      val = pd[(size_t)row * NPF + k];
            else if (k < KB)  val = sd[(size_t)row * 10 + (k - NPF)];
            else if (k == KB) val = vt[row];
            #pragma unroll
            for (int j = 0; j < 24; ++j) acc[j*3 + c] += wjs[j][vv] * val;
        }
    }
    if (k < 224) {
        float* p = part + (size_t)bi * (72*224);
        #pragma unroll
        for (int i = 0; i < 72; ++i) p[i*224 + k] = acc[i];
    }
}

// ============ K4a: reduce 512 -> 8 partials ============
__global__ __launch_bounds__(256) void k_jreduce1(const float* __restrict__ part,
        float* __restrict__ part2) {
    int i = blockIdx.x;
    int s = blockIdx.y;
    int k = threadIdx.x;
    if (k >= 224) return;
    float acc = 0.0f;
    #pragma unroll 4
    for (int bi = s*64; bi < s*64 + 64; ++bi)
        acc += part[(size_t)bi * (72*224) + i*224 + k];
    part2[((size_t)s * 72 + i) * 224 + k] = acc;
}

// ============ K4b: reduce 8 -> JDt[k][72] ============
__global__ __launch_bounds__(256) void k_jreduce2(const float* __restrict__ part2,
        float* __restrict__ JDt) {
    int e = blockIdx.x * 256 + threadIdx.x;
    if (e >= 72*224) return;
    int i = e / 224, k = e - i*224;
    float s = 0.0f;
    #pragma unroll
    for (int ss = 0; ss < 8; ++ss)
        s += part2[((size_t)ss * 72 + i) * 224 + k];
    if (k < 218) JDt[k*72 + i] = s;
}

// ============ K5: J ============
__global__ __launch_bounds__(128) void k_J(const float* __restrict__ pfA,
        const float* __restrict__ JDt, float* __restrict__ Jout, int B) {
    int b = blockIdx.x, t = threadIdx.x;
    if (t >= 72) return;
    const float* pa = pfA + (size_t)b * 224;
    float acc = JDt[217*72 + t];
    #pragma unroll 7
    for (int k = 0; k < KB; ++k) acc += pa[k] * JDt[k*72 + t];
    Jout[(size_t)b * 72 + t] = acc;
}

// ============ K6: kinematic chain -> G_corr (+ optional Gmf fragments) ============
__global__ __launch_bounds__(32) void k_chain(const float* __restrict__ Rg,
        const float* __restrict__ Jg, float* __restrict__ Gc,
        short* __restrict__ Gmf, int doGmf, int B) {
    __shared__ float Gs[32 * 289];
    int b = blockIdx.x * 32 + threadIdx.x;
    if (b >= B) return;
    float* G = &Gs[threadIdx.x * 289];
    float Jl[72];
    const float* Jb = Jg + (size_t)b * 72;
    #pragma unroll
    for (int i = 0; i < 72; ++i) Jl[i] = Jb[i];
    const float* Rb = Rg + (size_t)b * 216;
    G[0]=Rb[0]; G[1]=Rb[1]; G[2]=Rb[2];  G[3]=Jl[0];
    G[4]=Rb[3]; G[5]=Rb[4]; G[6]=Rb[5];  G[7]=Jl[1];
    G[8]=Rb[6]; G[9]=Rb[7]; G[10]=Rb[8]; G[11]=Jl[2];
    #pragma unroll
    for (int i = 1; i < NJ; ++i) {
        const int p = PAR[i];
        const float* Ri = Rb + i*9;
        float r00=Ri[0],r01=Ri[1],r02=Ri[2];
        float r10=Ri[3],r11=Ri[4],r12=Ri[5];
        float r20=Ri[6],r21=Ri[7],r22=Ri[8];
        float px=Jl[p*3+0], py=Jl[p*3+1], pz=Jl[p*3+2];
        float tx = Jl[i*3+0] - (r00*px + r01*py + r02*pz);
        float ty = Jl[i*3+1] - (r10*px + r11*py + r12*pz);
        float tz = Jl[i*3+2] - (r20*px + r21*py + r22*pz);
        const float* gp = &G[p*12];
        float* gi = &G[i*12];
        #pragma unroll
        for (int rr = 0; rr < 3; ++rr) {
            float a0=gp[rr*4+0], a1=gp[rr*4+1], a2=gp[rr*4+2], a3=gp[rr*4+3];
            gi[rr*4+0] = a0*r00 + a1*r10 + a2*r20;
            gi[rr*4+1] = a0*r01 + a1*r11 + a2*r21;
            gi[rr*4+2] = a0*r02 + a1*r12 + a2*r22;
            gi[rr*4+3] = a0*tx + a1*ty + a2*tz + a3;
        }
    }
    // apply -G*J correction in place, then write Gc (and Gmf fragments if requested)
    #pragma unroll
    for (int i = 0; i < NJ; ++i) {
        float* gi = &G[i*12];
        float jx=Jl[i*3+0], jy=Jl[i*3+1], jz=Jl[i*3+2];
        #pragma unroll
        for (int rr = 0; rr < 3; ++rr)
            gi[rr*4+3] = gi[rr*4+3] - (gi[rr*4+0]*jx + gi[rr*4+1]*jy + gi[rr*4+2]*jz);
    }
    float* out = Gc + (size_t)b * 288;
    #pragma unroll
    for (int i = 0; i < 288; ++i) out[i] = G[i];
    if (doGmf) {
        short* gm = Gmf + (size_t)b * 512;
        // real fragments: lane = q*16 + c (q<3, c<12), elems e=0..7 -> joint j=q*8+e
        #pragma unroll
        for (int q = 0; q < 3; ++q)
            for (int c = 0; c < 12; ++c) {
                #pragma unroll
                for (int e = 0; e < 8; ++e)
                    gm[(q*16 + c)*8 + e] = f2bf(G[(q*8 + e)*12 + c]);
            }
        // zero pads: c in 12..15 for q<3, and all of q==3
        #pragma unroll
        for (int q = 0; q < 3; ++q)
            for (int c = 12; c < 16; ++c)
                #pragma unroll
                for (int e = 0; e < 8; ++e) gm[(q*16 + c)*8 + e] = 0;
        #pragma unroll
        for (int c = 0; c < 16; ++c)
            #pragma unroll
            for (int e = 0; e < 8; ++e) gm[(48 + c)*8 + e] = 0;
    }
}

// ============ K7: 128-col streaming GEMM, f32 out (fallback) ============
__global__ __launch_bounds__(256, 2) void k_gemm(const short* __restrict__ Af,
        const short* __restrict__ Bf, const float* __restrict__ vt,
        float* __restrict__ vout, int B) {
    __shared__ float eld[64 * 128];
    const int t = threadIdx.x;
    const int wgid = blockIdx.x;
    const int bt = wgid & 7, nt = wgid >> 3;
    const int wave = t >> 6, lane = t & 63;
    const int wn = (wave & 1) * 64;
    const int q = lane >> 4, r16 = lane & 15;
    const int mfb = (wave >> 1) * 4, nfb = (wave & 1) * 4;

    const s16x8* Ab = (const s16x8*)(Af + (size_t)bt * FTILE);
    const s16x8* Bb = (const s16x8*)(Bf + (size_t)nt * FTILE);

    f32x4 acc[4][4];
    #pragma unroll
    for (int m = 0; m < 4; ++m)
        #pragma unroll
        for (int n = 0; n < 4; ++n)
            #pragma unroll
            for (int i = 0; i < 4; ++i) acc[m][n][i] = 0.0f;

    #pragma unroll
    for (int ks = 0; ks < 8; ++ks) {
        s16x8 a[4], b[4];
        #pragma unroll
        for (int m = 0; m < 4; ++m) a[m] = Ab[(ks*8 + mfb + m)*64 + lane];
        #pragma unroll
        for (int n = 0; n < 4; ++n) b[n] = Bb[(ks*8 + nfb + n)*64 + lane];
        #pragma unroll
        for (int m = 0; m < 4; ++m)
            #pragma unroll
            for (int n = 0; n < 4; ++n)
                acc[m][n] = __builtin_amdgcn_mfma_f32_16x16x32_bf16(a[m], b[n], acc[m][n], 0, 0, 0);
    }

    #pragma unroll
    for (int half = 0; half < 2; ++half) {
        if ((wave >> 1) == half) {
            #pragma unroll
            for (int m = 0; m < 4; ++m)
                #pragma unroll
                for (int n = 0; n < 4; ++n)
                    #pragma unroll
                    for (int i = 0; i < 4; ++i) {
                        int row_l = m*16 + q*4 + i;
                        int col = wn + n*16 + r16;
                        eld[row_l * 128 + (col ^ ((row_l & 7) << 2))] = acc[m][n][i];
                    }
        }
        __syncthreads();
        {
            const int c32 = t & 31;
            const int col = c32 * 4;
            const int rsub = (t >> 5) & 1;
            #pragma unroll
            for (int it = 0; it < 8; ++it) {
                int row_l = it * 8 + wave * 2 + rsub;
                int bg = bt * 128 + half * 64 + row_l;
                int rg = nt * 128 + col;
                f32x4 v = *(const f32x4*)&eld[row_l * 128 + (col ^ ((row_l & 7) << 2))];
                if (bg < B) {
                    float* dst = vout + (size_t)bg * NR + rg;
                    if (rg + 3 < NR) {
                        float4 tv = *(const float4*)(vt + rg);
                        v[0] += tv.x; v[1] += tv.y; v[2] += tv.z; v[3] += tv.w;
                        *(f4u*)dst = v;
                    } else {
                        #pragma unroll
                        for (int e = 0; e < 4; ++e)
                            if (rg + e < NR) dst[e] = v[e] + vt[rg + e];
                    }
                }
            }
        }
        __syncthreads();
    }
}

// ============ K7b: FUSED 192-col GEMM + MFMA skinning, single-pass 128-row epilogue ============
__global__ __launch_bounds__(256, 2) void k_gemm_skin(const short* __restrict__ Af,
        const short* __restrict__ Bf, const float* __restrict__ vt,
        const short* __restrict__ Gmf, const float* __restrict__ W,
        float* __restrict__ vout, int B) {
    __shared__ short elds[128 * ELDW];             // 67.6 KB bf16 v_posed (full tile)
    const int t = threadIdx.x;
    const int wgid = blockIdx.x;
    const int bt = wgid & 7, nt = wgid >> 3;       // nt 0..107
    const int wave = t >> 6, lane = t & 63;
    const int wn = (wave & 1) * 96;
    const int q = lane >> 4, r16 = lane & 15;
    const int mfb = (wave >> 1) * 4, nfb = (wave & 1) * 6;
    const int rowbase = (wave >> 1) * 64;

    const s16x8* Ab = (const s16x8*)(Af + (size_t)bt * FTILE);
    const s16x8* Bb = (const s16x8*)(Bf + (size_t)nt * FT2);

    f32x4 acc[4][6];
    #pragma unroll
    for (int m = 0; m < 4; ++m)
        #pragma unroll
        for (int n = 0; n < 6; ++n)
            #pragma unroll
            for (int i = 0; i < 4; ++i) acc[m][n][i] = 0.0f;

    #pragma unroll
    for (int ks = 0; ks < 8; ++ks) {
        s16x8 a[4], b[6];
        #pragma unroll
        for (int m = 0; m < 4; ++m) a[m] = Ab[(ks*8 + mfb + m)*64 + lane];
        #pragma unroll
        for (int n = 0; n < 6; ++n) b[n] = Bb[(ks*12 + nfb + n)*64 + lane];
        #pragma unroll
        for (int m = 0; m < 4; ++m)
            #pragma unroll
            for (int n = 0; n < 6; ++n)
                acc[m][n] = __builtin_amdgcn_mfma_f32_16x16x32_bf16(a[m], b[n], acc[m][n], 0, 0, 0);
    }

    float vtv[6];
    int sofs[6];
    #pragma unroll
    for (int n = 0; n < 6; ++n) {
        int col = wn + n*16 + r16;
        int rg = nt*192 + col;
        vtv[n] = (rg < NR) ? vt[rg] : 0.0f;
        int vert = col / 3;
        sofs[n] = vert*4 + (col - vert*3);
    }

    s16x8 wf[4];
    int vert[4];
    bool vok[4];
    const int c16 = lane & 15;
    #pragma unroll
    for (int m = 0; m < 4; ++m) {
        vert[m] = nt*64 + m*16 + c16;
        vok[m] = (q < 3) && (vert[m] < NV);
        if (vok[m]) {
            const float* wp = W + (size_t)vert[m] * NJ + q*8;
            float4 f0 = *(const float4*)(wp);
            float4 f1 = *(const float4*)(wp + 4);
            wf[m][0]=f2bf(f0.x); wf[m][1]=f2bf(f0.y); wf[m][2]=f2bf(f0.z); wf[m][3]=f2bf(f0.w);
            wf[m][4]=f2bf(f1.x); wf[m][5]=f2bf(f1.y); wf[m][6]=f2bf(f1.z); wf[m][7]=f2bf(f1.w);
        } else {
            #pragma unroll
            for (int e = 0; e < 8; ++e) wf[m][e] = 0;
        }
    }

    // (a) ALL waves write their acc into the full 128-row elds (disjoint regions)
    #pragma unroll
    for (int m = 0; m < 4; ++m)
        #pragma unroll
        for (int i = 0; i < 4; ++i) {
            int row_l = rowbase + m*16 + q*4 + i;
            #pragma unroll
            for (int n = 0; n < 6; ++n)
                elds[row_l * ELDW + sofs[n]] = f2bf(acc[m][n][i] + vtv[n]);
        }
    __syncthreads();

    // (c) skin: each wave owns 32 batch rows; Gmf ping-pong prefetched
    {
        s16x8 afA, afB;
        int bl0 = wave * 32;
        int bgbase = bt * 128;
        afA = *(const s16x8*)&Gmf[((size_t)(bgbase + bl0) * 64 + lane) * 8];
        #pragma unroll 8
        for (int bb = 0; bb < 32; ++bb) {
            if (bb + 1 < 32) {
                const s16x8* nx = (const s16x8*)&Gmf[((size_t)(bgbase + bl0 + bb + 1) * 64 + lane) * 8];
                if (bb & 1) afA = *nx; else afB = *nx;
            }
            s16x8 af = (bb & 1) ? afB : afA;
            int bl = bl0 + bb;
            int bg = bgbase + bl;
            #pragma unroll
            for (int m = 0; m < 4; ++m) {
                s16x4 vd = *(const s16x4*)&elds[bl * ELDW + (m*16 + c16) * 4];
                f32x4 zz = {0.0f, 0.0f, 0.0f, 0.0f};
                f32x4 Tq = __builtin_amdgcn_mfma_f32_16x16x32_bf16(af, wf[m], zz, 0, 0, 0);
                if (vok[m]) {
                    float x = bf2fs((unsigned short)vd[0]);
                    float y = bf2fs((unsigned short)vd[1]);
                    float z = bf2fs((unsigned short)vd[2]);
                    float o = Tq[0]*x + Tq[1]*y + Tq[2]*z + Tq[3];
                    vout[(size_t)bg * NR + (size_t)vert[m] * 3 + q] = o;
                }
            }
        }
    }
}

// ============ K8: MFMA skinning, f32 in-place (fallback) ============
__global__ __launch_bounds__(256) void k_skin(float* __restrict__ vio,
        const float* __restrict__ W, const float* __restrict__ Gc, int B) {
    __shared__ short Gm[16 * 40];
    const int t = threadIdx.x;
    const int wave = t >> 6, lane = t & 63;
    const int q = lane >> 4, c = lane & 15;
    const int vb = blockIdx.x * 256 + wave * 64;
    const int b0 = blockIdx.y * 16;

    if (t < 320) ((int*)Gm)[t] = 0;

    s16x8 wf[4];
    #pragma unroll
    for (int m = 0; m < 4; ++m) {
        int vert = vb + m*16 + c;
        if (q < 3 && vert < NV) {
            const float* wp = W + (size_t)vert * NJ + q*8;
            float4 f0 = *(const float4*)(wp);
            float4 f1 = *(const float4*)(wp + 4);
            wf[m][0]=f2bf(f0.x); wf[m][1]=f2bf(f0.y); wf[m][2]=f2bf(f0.z); wf[m][3]=f2bf(f0.w);
            wf[m][4]=f2bf(f1.x); wf[m][5]=f2bf(f1.y); wf[m][6]=f2bf(f1.z); wf[m][7]=f2bf(f1.w);
        } else {
            #pragma unroll
            for (int e = 0; e < 8; ++e) wf[m][e] = 0;
        }
    }
    __syncthreads();

    for (int bb = 0; bb < 16; ++bb) {
        int b = b0 + bb;
        if (b >= B) break;
        {
            int i0 = t;
            int j0 = i0 / 12, c0 = i0 - j0*12;
            if (i0 < 288) Gm[c0*40 + j0] = f2bf(Gc[(size_t)b*288 + i0]);
            int i1 = t + 256;
            if (i1 < 288) {
                int j1 = i1 / 12, c1 = i1 - j1*12;
                Gm[c1*40 + j1] = f2bf(Gc[(size_t)b*288 + i1]);
            }
        }
        __syncthreads();

        s16x8 af = *(const s16x8*)&Gm[c*40 + q*8];
        #pragma unroll
        for (int m = 0; m < 4; ++m) {
            f32x4 zz = {0.0f, 0.0f, 0.0f, 0.0f};
            f32x4 acc = __builtin_amdgcn_mfma_f32_16x16x32_bf16(af, wf[m], zz, 0, 0, 0);
            int vert = vb + m*16 + c;
            bool ok = (q < 3) && (vert < NV);
            if (ok) {
                float* vp = vio + (size_t)b * NR + (size_t)vert * 3;
                float x = vp[0], y = vp[1], z = vp[2];
                float o = acc[0]*x + acc[1]*y + acc[2]*z + acc[3];
                vp[q] = o;
            }
        }
        __syncthreads();
    }
}

extern "C" void kernel_launch(void* const* d_in, const int* in_sizes, int n_in,
                              void* d_out, int out_size, void* d_ws, size_t ws_size,
                              hipStream_t stream) {
    const float* theta = (const float*)d_in[0];
    const float* beta  = (const float*)d_in[1];
    const float* sd    = (const float*)d_in[2];
    const float* pd    = (const float*)d_in[3];
    const float* Jreg  = (const float*)d_in[4];
    const float* vt    = (const float*)d_in[5];
    const float* W     = (const float*)d_in[6];
    float* out = (float*)d_out;

    const int B = in_sizes[0] / 72;

    float* vregion = out;
    float* Jout    = out + (size_t)B * NR;

    float* Rws   = (float*)d_ws;                          // B*216 f32
    float* Gcws  = Rws + (size_t)B * 216;                 // B*288 f32
    float* pfA   = Gcws + (size_t)B * 288;                // B*224 f32
    short* Afrag = (short*)(pfA + (size_t)B * 224);       // (B/128)*FTILE bf16
    short* Bfrag = Afrag + (size_t)(B/128) * FTILE;       // NT2*FT2 shorts (10.6 MB)
    short* Gmf   = Bfrag + (size_t)NT2 * FT2;             // B*512 bf16 (1 MB)

    size_t need_fuse = (size_t)B * 2912 + (size_t)(B/128) * FTILE * 2
                     + (size_t)NT2 * FT2 * 2 + (size_t)B * 512 * 2;
    const bool use_fuse = (ws_size >= need_fuse) && ((B & 127) == 0);

    float* part  = vregion;                               // d_out scratch pre-GEMM
    float* part2 = vregion + (size_t)NSPLIT * 72 * 224;
    float* JDt   = part2 + (size_t)8 * 72 * 224;

    const int rodblocks = (B*NJ + 255)/256;

    if (use_fuse) {
        // fat prep: jdirs (512) | convB192 (2592) | rodrigues (rodblocks)
        k_prep<<<NSPLIT + 24*NT2 + rodblocks, 256, 0, stream>>>(
            theta, beta, pd, sd, vt, Jreg, Rws, pfA, Afrag, Bfrag, part, B);
    } else {
        k_rodrigues<<<rodblocks, 256, 0, stream>>>(theta, beta, Rws, pfA, Afrag, B);
        k_convB128<<<(NT*8*8*64)/256, 256, 0, stream>>>(pd, sd, Bfrag);
        k_jdirs<<<NSPLIT, 256, 0, stream>>>(pd, sd, vt, Jreg, part);
    }
    {
        dim3 grid(72, 8);
        k_jreduce1<<<grid, 256, 0, stream>>>(part, part2);
    }
    k_jreduce2<<<(72*224 + 255)/256, 256, 0, stream>>>(part2, JDt);
    k_J<<<B, 128, 0, stream>>>(pfA, JDt, Jout, B);
    k_chain<<<(B + 31)/32, 32, 0, stream>>>(Rws, Jout, Gcws, Gmf, use_fuse ? 1 : 0, B);

    if (use_fuse) {
        k_gemm_skin<<<NT2 * (B/128), 256, 0, stream>>>(Afrag, Bfrag, vt, Gmf, W, vregion, B);
    } else {
        k_gemm<<<NT * (B/128), 256, 0, stream>>>(Afrag, Bfrag, vt, vregion, B);
        dim3 grid((NV + 255)/256, (B + 15)/16);
        k_skin<<<grid, 256, 0, stream>>>(vregion, W, Gcws, B);
    }
}

// Round 22
// 103.973 us; speedup vs baseline: 1.8521x; 1.1001x over previous
//
#include <hip/hip_runtime.h>
#include <hip/hip_bf16.h>

#define NJ 24
#define NV 6890
#define NVP 6912
#define NR (NV*3)        // 20670 output rows per batch
#define NPF 207
#define KB 217           // 207 pf + 10 beta
#define KP 256           // padded K (8 x 32)
#define NT 162           // 128-col tiles (fallback path)
#define NT2 108          // 192-col tiles (64 whole verts each)
#define NSPLIT 512       // jdirs v-splits
#define VPB 14           // ceil(6890/512)
#define FTILE 32768      // A-tile shorts: 8 ks * 8 frag * 64 lane * 8
#define FT2   49152      // B-tile shorts (192-col)
#define ELDW 264         // elds row stride in shorts (64 verts*4 + 8 pad)

typedef short s16x8 __attribute__((ext_vector_type(8)));
typedef short s16x4 __attribute__((ext_vector_type(4)));
typedef float f32x4 __attribute__((ext_vector_type(4)));
typedef float f4u   __attribute__((ext_vector_type(4), aligned(4)));

__device__ constexpr int PAR[24] = {-1,0,0,0,1,2,3,4,5,6,7,8,9,9,9,12,13,14,16,17,18,19,20,21};

__device__ __forceinline__ short f2bf(float f) {
    __hip_bfloat16 h = __float2bfloat16(f);
    return *reinterpret_cast<short*>(&h);
}
__device__ __forceinline__ float bf2fs(unsigned short u) {
    unsigned int x = ((unsigned int)u) << 16;
    return __uint_as_float(x);
}

// A-fragment address for (row_in_tile, k)
__device__ __forceinline__ size_t frag_addr(int row128, int k) {
    int ks = k >> 5, q = (k >> 3) & 3, e = k & 7;
    int mf = row128 >> 4, r16 = row128 & 15;
    return ((size_t)(ks*8 + mf) * 64 + q*16 + r16) * 8 + e;
}

// -------- device bodies shared by fat kernel and fallbacks --------
__device__ __forceinline__ void rodrigues_body(int idx, const float* __restrict__ theta,
        const float* __restrict__ beta, float* __restrict__ Rws,
        float* __restrict__ pfA, short* __restrict__ Afrag, int B) {
    if (idx >= B * NJ) return;
    int b = idx / NJ, j = idx % NJ;
    float x = theta[b*72 + j*3 + 0];
    float y = theta[b*72 + j*3 + 1];
    float z = theta[b*72 + j*3 + 2];
    float n = sqrtf(x*x + y*y + z*z);
    float a = fmaxf(n, 1e-8f);
    float inv = 1.0f / a;
    float ix = x*inv, iy = y*inv, iz = z*inv;
    float c = cosf(a), s = sinf(a), t = 1.0f - c;
    float r[9];
    r[0] = t*ix*ix + c;     r[1] = t*ix*iy - s*iz;  r[2] = t*ix*iz + s*iy;
    r[3] = t*ix*iy + s*iz;  r[4] = t*iy*iy + c;     r[5] = t*iy*iz - s*ix;
    r[6] = t*ix*iz - s*iy;  r[7] = t*iy*iz + s*ix;  r[8] = t*iz*iz + c;
    float* Rp = Rws + (size_t)idx * 9;
    #pragma unroll
    for (int k = 0; k < 9; ++k) Rp[k] = r[k];

    int rb = b & 127;
    short* At = Afrag + (size_t)(b >> 7) * FTILE;
    float* pa = pfA + (size_t)b * 224;
    if (j >= 1) {
        #pragma unroll
        for (int kk = 0; kk < 9; ++kk) {
            int k = (j-1)*9 + kk;
            float f = r[kk] - ((kk == 0 || kk == 4 || kk == 8) ? 1.0f : 0.0f);
            At[frag_addr(rb, k)] = f2bf(f);
            pa[k] = f;
        }
    } else {
        #pragma unroll
        for (int kk = 0; kk < 10; ++kk) {
            int k = NPF + kk;
            float f = beta[b*10 + kk];
            At[frag_addr(rb, k)] = f2bf(f);
            pa[k] = f;
        }
        for (int k = KB; k < KP; ++k)
            At[frag_addr(rb, k)] = 0;
    }
}

__device__ __forceinline__ void convB192_body(int nt, int id,
        const float* __restrict__ pd, const float* __restrict__ sd,
        short* __restrict__ Bf) {
    int lane_ = id & 63;
    int fi = id >> 6;
    int nf = fi % 12, ks = fi / 12;
    int q = lane_ >> 4, r16 = lane_ & 15;
    int rg = nt*192 + nf*16 + r16;
    int k0 = ks*32 + q*8;
    s16x8 v;
    if (rg < NR) {
        if (k0 + 7 < NPF) {
            const float* p = pd + (size_t)rg * NPF + k0;
            #pragma unroll
            for (int k = 0; k < 8; ++k) v[k] = f2bf(p[k]);
        } else {
            #pragma unroll
            for (int k = 0; k < 8; ++k) {
                int col = k0 + k;
                float f = 0.0f;
                if (col < NPF)     f = pd[(size_t)rg * NPF + col];
                else if (col < KB) f = sd[(size_t)rg * 10 + (col - NPF)];
                v[k] = f2bf(f);
            }
        }
    } else {
        #pragma unroll
        for (int k = 0; k < 8; ++k) v[k] = 0;
    }
    *(s16x8*)&Bf[((size_t)nt * FT2) + (size_t)id * 8] = v;
}

// ============ K0: fat prep kernel — jdirs | convB192 | rodrigues ============
__global__ __launch_bounds__(256) void k_prep(const float* __restrict__ theta,
        const float* __restrict__ beta, const float* __restrict__ pd,
        const float* __restrict__ sd, const float* __restrict__ vt,
        const float* __restrict__ Jreg,
        float* __restrict__ Rws, float* __restrict__ pfA, short* __restrict__ Afrag,
        short* __restrict__ Bf, float* __restrict__ part, int B) {
    __shared__ float wjs[24][VPB];
    const int bid = blockIdx.x;
    const int t = threadIdx.x;
    if (bid < NSPLIT) {
        // ---- jdirs ----
        int bi = bid;
        int v0 = bi * VPB;
        int nv = NV - v0; if (nv > VPB) nv = VPB; if (nv < 0) nv = 0;
        for (int i = t; i < 24*VPB; i += 256) {
            int j = i / VPB, vv = i - j*VPB;
            wjs[j][vv] = (vv < nv) ? Jreg[(size_t)j * NV + v0 + vv] : 0.0f;
        }
        __syncthreads();
        int k = t;
        float acc[72];
        #pragma unroll
        for (int i = 0; i < 72; ++i) acc[i] = 0.0f;
        for (int vv = 0; vv < VPB; ++vv) {
            int v = v0 + vv;
            if (v >= NV) break;
            #pragma unroll
            for (int c = 0; c < 3; ++c) {
                int row = v*3 + c;
                float val = 0.0f;
                if (k < NPF)      val = pd[(size_t)row * NPF + k];
                else if (k < KB)  val = sd[(size_t)row * 10 + (k - NPF)];
                else if (k == KB) val = vt[row];
                #pragma unroll
                for (int j = 0; j < 24; ++j) acc[j*3 + c] += wjs[j][vv] * val;
            }
        }
        if (k < 224) {
            float* p = part + (size_t)bi * (72*224);
            #pragma unroll
            for (int i = 0; i < 72; ++i) p[i*224 + k] = acc[i];
        }
    } else if (bid < NSPLIT + 24*NT2) {
        // ---- convB192 ----
        int cb = bid - NSPLIT;
        int nt = cb / 24;
        int id = (cb % 24) * 256 + t;
        convB192_body(nt, id, pd, sd, Bf);
    } else {
        // ---- rodrigues ----
        int idx = (bid - NSPLIT - 24*NT2) * 256 + t;
        rodrigues_body(idx, theta, beta, Rws, pfA, Afrag, B);
    }
}

// ============ standalone kernels for fallback path ============
__global__ __launch_bounds__(256) void k_rodrigues(const float* __restrict__ theta,
        const float* __restrict__ beta, float* __restrict__ Rws,
        float* __restrict__ pfA, short* __restrict__ Afrag, int B) {
    rodrigues_body(blockIdx.x * blockDim.x + threadIdx.x, theta, beta, Rws, pfA, Afrag, B);
}

__global__ __launch_bounds__(256) void k_convB128(const float* __restrict__ pd,
        const float* __restrict__ sd, short* __restrict__ Bf) {
    int cid = blockIdx.x * 256 + threadIdx.x;
    int lane_ = cid & 63;
    int nf = (cid >> 6) & 7;
    int ks = (cid >> 9) & 7;
    int nt = cid >> 12;
    int q = lane_ >> 4, r16 = lane_ & 15;
    int rg = nt*128 + nf*16 + r16;
    int k0 = ks*32 + q*8;
    s16x8 v;
    if (rg < NR) {
        if (k0 + 7 < NPF) {
            const float* p = pd + (size_t)rg * NPF + k0;
            #pragma unroll
            for (int k = 0; k < 8; ++k) v[k] = f2bf(p[k]);
        } else {
            #pragma unroll
            for (int k = 0; k < 8; ++k) {
                int col = k0 + k;
                float f = 0.0f;
                if (col < NPF)     f = pd[(size_t)rg * NPF + col];
                else if (col < KB) f = sd[(size_t)rg * 10 + (col - NPF)];
                v[k] = f2bf(f);
            }
        }
    } else {
        #pragma unroll
        for (int k = 0; k < 8; ++k) v[k] = 0;
    }
    *(s16x8*)&Bf[(size_t)cid * 8] = v;
}

__global__ __launch_bounds__(256) void k_jdirs(const float* __restrict__ pd,
        const float* __restrict__ sd, const float* __restrict__ vt,
        const float* __restrict__ Jreg, float* __restrict__ part) {
    __shared__ float wjs[24][VPB];
    int bi = blockIdx.x;
    int v0 = bi * VPB;
    int nv = NV - v0; if (nv > VPB) nv = VPB; if (nv < 0) nv = 0;
    for (int i = threadIdx.x; i < 24*VPB; i += 256) {
        int j = i / VPB, vv = i - j*VPB;
        wjs[j][vv] = (vv < nv) ? Jreg[(size_t)j * NV + v0 + vv] : 0.0f;
    }
    __syncthreads();
    int k = threadIdx.x;
    float acc[72];
    #pragma unroll
    for (int i = 0; i < 72; ++i) acc[i] = 0.0f;
    for (int vv = 0; vv < VPB; ++vv) {
        int v = v0 + vv;
        if (v >= NV) break;
        #pragma unroll
        for (int c = 0; c < 3; ++c) {
            int row = v*3 + c;
            float val = 0.0f;
            if (k < NPF)      val = pd[(size_t)row * NPF + k];
            else if (k < KB)  val = sd[(size_t)row * 10 + (k - NPF)];
            else if (k == KB) val = vt[row];
            #pragma unroll
            for (int j = 0; j < 24; ++j) acc[j*3 + c] += wjs[j][vv] * val;
        }
    }
    if (k < 224) {
        float* p = part + (size_t)bi * (72*224);
        #pragma unroll
        for (int i = 0; i < 72; ++i) p[i*224 + k] = acc[i];
    }
}

// ============ K4a: reduce 512 -> 8 partials ============
__global__ __launch_bounds__(256) void k_jreduce1(const float* __restrict__ part,
        float* __restrict__ part2) {
    int i = blockIdx.x;
    int s = blockIdx.y;
    int k = threadIdx.x;
    if (k >= 224) return;
    float acc = 0.0f;
    #pragma unroll 4
    for (int bi = s*64; bi < s*64 + 64; ++bi)
        acc += part[(size_t)bi * (72*224) + i*224 + k];
    part2[((size_t)s * 72 + i) * 224 + k] = acc;
}

// ============ K4b: reduce 8 -> JDt[k][72] ============
__global__ __launch_bounds__(256) void k_jreduce2(const float* __restrict__ part2,
        float* __restrict__ JDt) {
    int e = blockIdx.x * 256 + threadIdx.x;
    if (e >= 72*224) return;
    int i = e / 224, k = e - i*224;
    float s = 0.0f;
    #pragma unroll
    for (int ss = 0; ss < 8; ++ss)
        s += part2[((size_t)ss * 72 + i) * 224 + k];
    if (k < 218) JDt[k*72 + i] = s;
}

// ============ K5: J ============
__global__ __launch_bounds__(128) void k_J(const float* __restrict__ pfA,
        const float* __restrict__ JDt, float* __restrict__ Jout, int B) {
    int b = blockIdx.x, t = threadIdx.x;
    if (t >= 72) return;
    const float* pa = pfA + (size_t)b * 224;
    float acc = JDt[217*72 + t];
    #pragma unroll 7
    for (int k = 0; k < KB; ++k) acc += pa[k] * JDt[k*72 + t];
    Jout[(size_t)b * 72 + t] = acc;
}

// ============ K6: kinematic chain -> G_corr (+ optional Gmf fragments) ============
__global__ __launch_bounds__(32) void k_chain(const float* __restrict__ Rg,
        const float* __restrict__ Jg, float* __restrict__ Gc,
        short* __restrict__ Gmf, int doGmf, int B) {
    __shared__ float Gs[32 * 289];
    int b = blockIdx.x * 32 + threadIdx.x;
    if (b >= B) return;
    float* G = &Gs[threadIdx.x * 289];
    float Jl[72];
    const float* Jb = Jg + (size_t)b * 72;
    #pragma unroll
    for (int i = 0; i < 72; ++i) Jl[i] = Jb[i];
    const float* Rb = Rg + (size_t)b * 216;
    G[0]=Rb[0]; G[1]=Rb[1]; G[2]=Rb[2];  G[3]=Jl[0];
    G[4]=Rb[3]; G[5]=Rb[4]; G[6]=Rb[5];  G[7]=Jl[1];
    G[8]=Rb[6]; G[9]=Rb[7]; G[10]=Rb[8]; G[11]=Jl[2];
    #pragma unroll
    for (int i = 1; i < NJ; ++i) {
        const int p = PAR[i];
        const float* Ri = Rb + i*9;
        float r00=Ri[0],r01=Ri[1],r02=Ri[2];
        float r10=Ri[3],r11=Ri[4],r12=Ri[5];
        float r20=Ri[6],r21=Ri[7],r22=Ri[8];
        float px=Jl[p*3+0], py=Jl[p*3+1], pz=Jl[p*3+2];
        float tx = Jl[i*3+0] - (r00*px + r01*py + r02*pz);
        float ty = Jl[i*3+1] - (r10*px + r11*py + r12*pz);
        float tz = Jl[i*3+2] - (r20*px + r21*py + r22*pz);
        const float* gp = &G[p*12];
        float* gi = &G[i*12];
        #pragma unroll
        for (int rr = 0; rr < 3; ++rr) {
            float a0=gp[rr*4+0], a1=gp[rr*4+1], a2=gp[rr*4+2], a3=gp[rr*4+3];
            gi[rr*4+0] = a0*r00 + a1*r10 + a2*r20;
            gi[rr*4+1] = a0*r01 + a1*r11 + a2*r21;
            gi[rr*4+2] = a0*r02 + a1*r12 + a2*r22;
            gi[rr*4+3] = a0*tx + a1*ty + a2*tz + a3;
        }
    }
    #pragma unroll
    for (int i = 0; i < NJ; ++i) {
        float* gi = &G[i*12];
        float jx=Jl[i*3+0], jy=Jl[i*3+1], jz=Jl[i*3+2];
        #pragma unroll
        for (int rr = 0; rr < 3; ++rr)
            gi[rr*4+3] = gi[rr*4+3] - (gi[rr*4+0]*jx + gi[rr*4+1]*jy + gi[rr*4+2]*jz);
    }
    float* out = Gc + (size_t)b * 288;
    #pragma unroll
    for (int i = 0; i < 288; ++i) out[i] = G[i];
    if (doGmf) {
        short* gm = Gmf + (size_t)b * 512;
        #pragma unroll
        for (int q = 0; q < 3; ++q)
            for (int c = 0; c < 12; ++c) {
                #pragma unroll
                for (int e = 0; e < 8; ++e)
                    gm[(q*16 + c)*8 + e] = f2bf(G[(q*8 + e)*12 + c]);
            }
        #pragma unroll
        for (int q = 0; q < 3; ++q)
            for (int c = 12; c < 16; ++c)
                #pragma unroll
                for (int e = 0; e < 8; ++e) gm[(q*16 + c)*8 + e] = 0;
        #pragma unroll
        for (int c = 0; c < 16; ++c)
            #pragma unroll
            for (int e = 0; e < 8; ++e) gm[(48 + c)*8 + e] = 0;
    }
}

// ============ K7: 128-col streaming GEMM, f32 out (fallback) ============
__global__ __launch_bounds__(256, 2) void k_gemm(const short* __restrict__ Af,
        const short* __restrict__ Bf, const float* __restrict__ vt,
        float* __restrict__ vout, int B) {
    __shared__ float eld[64 * 128];
    const int t = threadIdx.x;
    const int wgid = blockIdx.x;
    const int bt = wgid & 7, nt = wgid >> 3;
    const int wave = t >> 6, lane = t & 63;
    const int wn = (wave & 1) * 64;
    const int q = lane >> 4, r16 = lane & 15;
    const int mfb = (wave >> 1) * 4, nfb = (wave & 1) * 4;

    const s16x8* Ab = (const s16x8*)(Af + (size_t)bt * FTILE);
    const s16x8* Bb = (const s16x8*)(Bf + (size_t)nt * FTILE);

    f32x4 acc[4][4];
    #pragma unroll
    for (int m = 0; m < 4; ++m)
        #pragma unroll
        for (int n = 0; n < 4; ++n)
            #pragma unroll
            for (int i = 0; i < 4; ++i) acc[m][n][i] = 0.0f;

    #pragma unroll
    for (int ks = 0; ks < 8; ++ks) {
        s16x8 a[4], b[4];
        #pragma unroll
        for (int m = 0; m < 4; ++m) a[m] = Ab[(ks*8 + mfb + m)*64 + lane];
        #pragma unroll
        for (int n = 0; n < 4; ++n) b[n] = Bb[(ks*8 + nfb + n)*64 + lane];
        #pragma unroll
        for (int m = 0; m < 4; ++m)
            #pragma unroll
            for (int n = 0; n < 4; ++n)
                acc[m][n] = __builtin_amdgcn_mfma_f32_16x16x32_bf16(a[m], b[n], acc[m][n], 0, 0, 0);
    }

    #pragma unroll
    for (int half = 0; half < 2; ++half) {
        if ((wave >> 1) == half) {
            #pragma unroll
            for (int m = 0; m < 4; ++m)
                #pragma unroll
                for (int n = 0; n < 4; ++n)
                    #pragma unroll
                    for (int i = 0; i < 4; ++i) {
                        int row_l = m*16 + q*4 + i;
                        int col = wn + n*16 + r16;
                        eld[row_l * 128 + (col ^ ((row_l & 7) << 2))] = acc[m][n][i];
                    }
        }
        __syncthreads();
        {
            const int c32 = t & 31;
            const int col = c32 * 4;
            const int rsub = (t >> 5) & 1;
            #pragma unroll
            for (int it = 0; it < 8; ++it) {
                int row_l = it * 8 + wave * 2 + rsub;
                int bg = bt * 128 + half * 64 + row_l;
                int rg = nt * 128 + col;
                f32x4 v = *(const f32x4*)&eld[row_l * 128 + (col ^ ((row_l & 7) << 2))];
                if (bg < B) {
                    float* dst = vout + (size_t)bg * NR + rg;
                    if (rg + 3 < NR) {
                        float4 tv = *(const float4*)(vt + rg);
                        v[0] += tv.x; v[1] += tv.y; v[2] += tv.z; v[3] += tv.w;
                        *(f4u*)dst = v;
                    } else {
                        #pragma unroll
                        for (int e = 0; e < 4; ++e)
                            if (rg + e < NR) dst[e] = v[e] + vt[rg + e];
                    }
                }
            }
        }
        __syncthreads();
    }
}

// ============ K7b: FUSED 64-batch x 192-col GEMM + MFMA skinning ============
__global__ __launch_bounds__(256, 4) void k_gemm_skin(const short* __restrict__ Af,
        const short* __restrict__ Bf, const float* __restrict__ vt,
        const short* __restrict__ Gmf, const float* __restrict__ W,
        float* __restrict__ vout, int B) {
    __shared__ short elds[64 * ELDW];              // 33.8 KB bf16 v_posed (64 batches)
    const int t = threadIdx.x;
    const int wgid = blockIdx.x;
    const int nbt = B >> 6;                        // batch tiles of 64
    const int bt64 = wgid % nbt, nt = wgid / nbt;  // nt 0..107
    const int wave = t >> 6, lane = t & 63;
    const int q = lane >> 4, r16 = lane & 15;
    const int mfbase = (bt64 & 1) * 4;             // half of the 128-row A-frag tile
    const int nfb = wave * 3;                      // 3 n-frags per wave
    const int wn = wave * 48;

    const s16x8* Ab = (const s16x8*)(Af + (size_t)(bt64 >> 1) * FTILE);
    const s16x8* Bb = (const s16x8*)(Bf + (size_t)nt * FT2);

    f32x4 acc[4][3];
    #pragma unroll
    for (int m = 0; m < 4; ++m)
        #pragma unroll
        for (int n = 0; n < 3; ++n)
            #pragma unroll
            for (int i = 0; i < 4; ++i) acc[m][n][i] = 0.0f;

    #pragma unroll
    for (int ks = 0; ks < 8; ++ks) {
        s16x8 a[4], b[3];
        #pragma unroll
        for (int m = 0; m < 4; ++m) a[m] = Ab[(ks*8 + mfbase + m)*64 + lane];
        #pragma unroll
        for (int n = 0; n < 3; ++n) b[n] = Bb[(ks*12 + nfb + n)*64 + lane];
        #pragma unroll
        for (int m = 0; m < 4; ++m)
            #pragma unroll
            for (int n = 0; n < 3; ++n)
                acc[m][n] = __builtin_amdgcn_mfma_f32_16x16x32_bf16(a[m], b[n], acc[m][n], 0, 0, 0);
    }

    // per-n vt value + LDS short-offset (vert*4 + comp)
    float vtv[3];
    int sofs[3];
    #pragma unroll
    for (int n = 0; n < 3; ++n) {
        int col = wn + n*16 + r16;
        int rg = nt*192 + col;
        vtv[n] = (rg < NR) ? vt[rg] : 0.0f;
        int vert = col / 3;
        sofs[n] = vert*4 + (col - vert*3);
    }

    // W fragments for this tile's 64 verts
    s16x8 wf[4];
    int vert[4];
    bool vok[4];
    const int c16 = lane & 15;
    #pragma unroll
    for (int m = 0; m < 4; ++m) {
        vert[m] = nt*64 + m*16 + c16;
        vok[m] = (q < 3) && (vert[m] < NV);
        if (vok[m]) {
            const float* wp = W + (size_t)vert[m] * NJ + q*8;
            float4 f0 = *(const float4*)(wp);
            float4 f1 = *(const float4*)(wp + 4);
            wf[m][0]=f2bf(f0.x); wf[m][1]=f2bf(f0.y); wf[m][2]=f2bf(f0.z); wf[m][3]=f2bf(f0.w);
            wf[m][4]=f2bf(f1.x); wf[m][5]=f2bf(f1.y); wf[m][6]=f2bf(f1.z); wf[m][7]=f2bf(f1.w);
        } else {
            #pragma unroll
            for (int e = 0; e < 8; ++e) wf[m][e] = 0;
        }
    }

    // (a) all 4 waves write their acc into elds (disjoint column ranges)
    #pragma unroll
    for (int m = 0; m < 4; ++m)
        #pragma unroll
        for (int i = 0; i < 4; ++i) {
            int row_l = m*16 + q*4 + i;                // 0..63
            #pragma unroll
            for (int n = 0; n < 3; ++n)
                elds[row_l * ELDW + sofs[n]] = f2bf(acc[m][n][i] + vtv[n]);
        }
    __syncthreads();

    // (c) skin: each wave owns 16 batch rows; Gmf ping-pong prefetched
    {
        s16x8 afA, afB;
        int bl0 = wave * 16;
        int bgbase = bt64 * 64;
        afA = *(const s16x8*)&Gmf[((size_t)(bgbase + bl0) * 64 + lane) * 8];
        #pragma unroll 8
        for (int bb = 0; bb < 16; ++bb) {
            if (bb + 1 < 16) {
                const s16x8* nx = (const s16x8*)&Gmf[((size_t)(bgbase + bl0 + bb + 1) * 64 + lane) * 8];
                if (bb & 1) afA = *nx; else afB = *nx;
            }
            s16x8 af = (bb & 1) ? afB : afA;
            int bl = bl0 + bb;
            int bg = bgbase + bl;
            #pragma unroll
            for (int m = 0; m < 4; ++m) {
                s16x4 vd = *(const s16x4*)&elds[bl * ELDW + (m*16 + c16) * 4];
                f32x4 zz = {0.0f, 0.0f, 0.0f, 0.0f};
                f32x4 Tq = __builtin_amdgcn_mfma_f32_16x16x32_bf16(af, wf[m], zz, 0, 0, 0);
                if (vok[m]) {
                    float x = bf2fs((unsigned short)vd[0]);
                    float y = bf2fs((unsigned short)vd[1]);
                    float z = bf2fs((unsigned short)vd[2]);
                    float o = Tq[0]*x + Tq[1]*y + Tq[2]*z + Tq[3];
                    vout[(size_t)bg * NR + (size_t)vert[m] * 3 + q] = o;
                }
            }
        }
    }
}

// ============ K8: MFMA skinning, f32 in-place (fallback) ============
__global__ __launch_bounds__(256) void k_skin(float* __restrict__ vio,
        const float* __restrict__ W, const float* __restrict__ Gc, int B) {
    __shared__ short Gm[16 * 40];
    const int t = threadIdx.x;
    const int wave = t >> 6, lane = t & 63;
    const int q = lane >> 4, c = lane & 15;
    const int vb = blockIdx.x * 256 + wave * 64;
    const int b0 = blockIdx.y * 16;

    if (t < 320) ((int*)Gm)[t] = 0;

    s16x8 wf[4];
    #pragma unroll
    for (int m = 0; m < 4; ++m) {
        int vert = vb + m*16 + c;
        if (q < 3 && vert < NV) {
            const float* wp = W + (size_t)vert * NJ + q*8;
            float4 f0 = *(const float4*)(wp);
            float4 f1 = *(const float4*)(wp + 4);
            wf[m][0]=f2bf(f0.x); wf[m][1]=f2bf(f0.y); wf[m][2]=f2bf(f0.z); wf[m][3]=f2bf(f0.w);
            wf[m][4]=f2bf(f1.x); wf[m][5]=f2bf(f1.y); wf[m][6]=f2bf(f1.z); wf[m][7]=f2bf(f1.w);
        } else {
            #pragma unroll
            for (int e = 0; e < 8; ++e) wf[m][e] = 0;
        }
    }
    __syncthreads();

    for (int bb = 0; bb < 16; ++bb) {
        int b = b0 + bb;
        if (b >= B) break;
        {
            int i0 = t;
            int j0 = i0 / 12, c0 = i0 - j0*12;
            if (i0 < 288) Gm[c0*40 + j0] = f2bf(Gc[(size_t)b*288 + i0]);
            int i1 = t + 256;
            if (i1 < 288) {
                int j1 = i1 / 12, c1 = i1 - j1*12;
                Gm[c1*40 + j1] = f2bf(Gc[(size_t)b*288 + i1]);
            }
        }
        __syncthreads();

        s16x8 af = *(const s16x8*)&Gm[c*40 + q*8];
        #pragma unroll
        for (int m = 0; m < 4; ++m) {
            f32x4 zz = {0.0f, 0.0f, 0.0f, 0.0f};
            f32x4 acc = __builtin_amdgcn_mfma_f32_16x16x32_bf16(af, wf[m], zz, 0, 0, 0);
            int vert = vb + m*16 + c;
            bool ok = (q < 3) && (vert < NV);
            if (ok) {
                float* vp = vio + (size_t)b * NR + (size_t)vert * 3;
                float x = vp[0], y = vp[1], z = vp[2];
                float o = acc[0]*x + acc[1]*y + acc[2]*z + acc[3];
                vp[q] = o;
            }
        }
        __syncthreads();
    }
}

extern "C" void kernel_launch(void* const* d_in, const int* in_sizes, int n_in,
                              void* d_out, int out_size, void* d_ws, size_t ws_size,
                              hipStream_t stream) {
    const float* theta = (const float*)d_in[0];
    const float* beta  = (const float*)d_in[1];
    const float* sd    = (const float*)d_in[2];
    const float* pd    = (const float*)d_in[3];
    const float* Jreg  = (const float*)d_in[4];
    const float* vt    = (const float*)d_in[5];
    const float* W     = (const float*)d_in[6];
    float* out = (float*)d_out;

    const int B = in_sizes[0] / 72;

    float* vregion = out;
    float* Jout    = out + (size_t)B * NR;

    float* Rws   = (float*)d_ws;                          // B*216 f32
    float* Gcws  = Rws + (size_t)B * 216;                 // B*288 f32
    float* pfA   = Gcws + (size_t)B * 288;                // B*224 f32
    short* Afrag = (short*)(pfA + (size_t)B * 224);       // (B/128)*FTILE bf16
    short* Bfrag = Afrag + (size_t)(B/128) * FTILE;       // NT2*FT2 shorts (10.6 MB)
    short* Gmf   = Bfrag + (size_t)NT2 * FT2;             // B*512 bf16 (1 MB)

    size_t need_fuse = (size_t)B * 2912 + (size_t)(B/128) * FTILE * 2
                     + (size_t)NT2 * FT2 * 2 + (size_t)B * 512 * 2;
    const bool use_fuse = (ws_size >= need_fuse) && ((B & 127) == 0);

    float* part  = vregion;                               // d_out scratch pre-GEMM
    float* part2 = vregion + (size_t)NSPLIT * 72 * 224;
    float* JDt   = part2 + (size_t)8 * 72 * 224;

    const int rodblocks = (B*NJ + 255)/256;

    if (use_fuse) {
        k_prep<<<NSPLIT + 24*NT2 + rodblocks, 256, 0, stream>>>(
            theta, beta, pd, sd, vt, Jreg, Rws, pfA, Afrag, Bfrag, part, B);
    } else {
        k_rodrigues<<<rodblocks, 256, 0, stream>>>(theta, beta, Rws, pfA, Afrag, B);
        k_convB128<<<(NT*8*8*64)/256, 256, 0, stream>>>(pd, sd, Bfrag);
        k_jdirs<<<NSPLIT, 256, 0, stream>>>(pd, sd, vt, Jreg, part);
    }
    {
        dim3 grid(72, 8);
        k_jreduce1<<<grid, 256, 0, stream>>>(part, part2);
    }
    k_jreduce2<<<(72*224 + 255)/256, 256, 0, stream>>>(part2, JDt);
    k_J<<<B, 128, 0, stream>>>(pfA, JDt, Jout, B);
    k_chain<<<(B + 31)/32, 32, 0, stream>>>(Rws, Jout, Gcws, Gmf, use_fuse ? 1 : 0, B);

    if (use_fuse) {
        k_gemm_skin<<<NT2 * (B/64), 256, 0, stream>>>(Afrag, Bfrag, vt, Gmf, W, vregion, B);
    } else {
        k_gemm<<<NT * (B/128), 256, 0, stream>>>(Afrag, Bfrag, vt, vregion, B);
        dim3 grid((NV + 255)/256, (B + 15)/16);
        k_skin<<<grid, 256, 0, stream>>>(vregion, W, Gcws, B);
    }
}